// Round 4
// baseline (230.428 us; speedup 1.0000x reference)
//
#include <hip/hip_runtime.h>
#include <math.h>

#define RR 512
#define RR2 (RR*RR)
#define PP 256
#define PP2 (PP*PP)

__constant__ double d_wls[3] = {4.6e-7, 5.4e-7, 6.2e-7};
__constant__ double d_dn[3]  = {0.52, 0.515, 0.51};

__device__ inline float2 cadd(float2 a, float2 b){ return make_float2(a.x+b.x, a.y+b.y); }
__device__ inline float2 csub(float2 a, float2 b){ return make_float2(a.x-b.x, a.y-b.y); }
__device__ inline float2 cmulf(float2 a, float2 b){ return make_float2(a.x*b.x-a.y*b.y, a.x*b.y+a.y*b.x); }

template<bool INV>
__device__ inline float2 cjrot(float2 z){ return INV ? make_float2(-z.y, z.x) : make_float2(z.y, -z.x); }

// One radix-4 DIF-Stockham butterfly. Element i lives at buf[i*STR + off].
template<int N, int STR, bool INV>
__device__ inline void bfly4(const float2* __restrict__ in, float2* __restrict__ out,
                             int t, int m, int off) {
  int j = t & ~(m-1);
  float2 a0 = in[t*STR + off];
  float2 a1 = in[(t + N/4)*STR + off];
  float2 a2 = in[(t + N/2)*STR + off];
  float2 a3 = in[(t + 3*(N/4))*STR + off];
  float2 e0 = cadd(a0,a2), o0 = cadd(a1,a3);
  float2 e1 = csub(a0,a2), o1 = csub(a1,a3);
  float2 c0 = cadd(e0,o0), c2 = csub(e0,o0);
  float2 r1 = cjrot<INV>(o1);
  float2 c1 = cadd(e1,r1), c3 = csub(e1,r1);
  float ang = (INV ? 6.2831853071795865f : -6.2831853071795865f) * (float)j * (1.0f/(float)N);
  float sn, cs; __sincosf(ang, &sn, &cs);
  float2 w1 = make_float2(cs, sn);
  float2 w2 = make_float2(cs*cs - sn*sn, 2.f*cs*sn);
  float2 w3 = cmulf(w2, w1);
  int base = 4*j + (t - j);
  out[base*STR + off]       = c0;
  out[(base+m)*STR + off]   = cmulf(c1, w1);
  out[(base+2*m)*STR + off] = cmulf(c2, w2);
  out[(base+3*m)*STR + off] = cmulf(c3, w3);
}

// 512-pt rows: 128 threads, 4 radix-4 stages + twiddle-free radix-2. Result in b1.
template<bool INV>
__device__ inline void fft512_core(float2* __restrict__ b0, float2* __restrict__ b1, int t) {
  __syncthreads(); bfly4<512,1,INV>(b0,b1,t,1,0);
  __syncthreads(); bfly4<512,1,INV>(b1,b0,t,4,0);
  __syncthreads(); bfly4<512,1,INV>(b0,b1,t,16,0);
  __syncthreads(); bfly4<512,1,INV>(b1,b0,t,64,0);
  __syncthreads();
  #pragma unroll
  for (int k = 0; k < 2; ++k) {
    int tt = t + k*128;
    float2 a = b0[tt], b = b0[tt+256];
    b1[tt] = cadd(a,b); b1[tt+256] = csub(a,b);
  }
  __syncthreads();
}

// 256-pt rows: 64 threads (per row slice), 4 radix-4 stages. Result in b0.
template<bool INV>
__device__ inline void fft256_core(float2* __restrict__ b0, float2* __restrict__ b1, int t) {
  __syncthreads(); bfly4<256,1,INV>(b0,b1,t,1,0);
  __syncthreads(); bfly4<256,1,INV>(b1,b0,t,4,0);
  __syncthreads(); bfly4<256,1,INV>(b0,b1,t,16,0);
  __syncthreads(); bfly4<256,1,INV>(b1,b0,t,64,0);
  __syncthreads();
}

// 512-pt cols: CB=8 (pad 9), W=32 workers. Result in b1.
template<bool INV>
__device__ inline void fft512_core_col(float2* __restrict__ b0, float2* __restrict__ b1,
                                       int w, int c) {
  __syncthreads();
  #pragma unroll
  for (int k=0;k<4;++k) bfly4<512,9,INV>(b0,b1,w+32*k,1,c);
  __syncthreads();
  #pragma unroll
  for (int k=0;k<4;++k) bfly4<512,9,INV>(b1,b0,w+32*k,4,c);
  __syncthreads();
  #pragma unroll
  for (int k=0;k<4;++k) bfly4<512,9,INV>(b0,b1,w+32*k,16,c);
  __syncthreads();
  #pragma unroll
  for (int k=0;k<4;++k) bfly4<512,9,INV>(b1,b0,w+32*k,64,c);
  __syncthreads();
  #pragma unroll
  for (int k=0;k<8;++k) {
    int tt = w + 32*k;
    float2 a = b0[tt*9+c], b = b0[(tt+256)*9+c];
    b1[tt*9+c] = cadd(a,b); b1[(tt+256)*9+c] = csub(a,b);
  }
  __syncthreads();
}

// 256-pt cols: CB=8 (pad 9), W=32 workers. Result in b0.
template<bool INV>
__device__ inline void fft256_core_col(float2* __restrict__ b0, float2* __restrict__ b1,
                                       int w, int c) {
  __syncthreads();
  #pragma unroll
  for (int k=0;k<2;++k) bfly4<256,9,INV>(b0,b1,w+32*k,1,c);
  __syncthreads();
  #pragma unroll
  for (int k=0;k<2;++k) bfly4<256,9,INV>(b1,b0,w+32*k,4,c);
  __syncthreads();
  #pragma unroll
  for (int k=0;k<2;++k) bfly4<256,9,INV>(b0,b1,w+32*k,16,c);
  __syncthreads();
  #pragma unroll
  for (int k=0;k<2;++k) bfly4<256,9,INV>(b1,b0,w+32*k,64,c);
  __syncthreads();
}

// ---------------- height map (float4 vectorized) ----------------
__global__ void k_height4(const float* __restrict__ zc, const float4* __restrict__ zv,
                          float4* __restrict__ hm) {
  int idx = blockIdx.x * 256 + threadIdx.x;   // RR2/4
  float4 s = make_float4(0.f,0.f,0.f,0.f);
  #pragma unroll 8
  for (int t = 0; t < 64; ++t) {
    float c = zc[t];
    float4 v = zv[(size_t)t * (RR2/4) + idx];
    s.x += c*v.x; s.y += c*v.y; s.z += c*v.z; s.w += c*v.w;
  }
  hm[idx] = s;
}

// ---------------- aux 8x8x3 tile + PSUM zero ----------------
__global__ void k_aux(const float* __restrict__ mp, const float* __restrict__ cf,
                      float* __restrict__ aux8, float* __restrict__ PSUM) {
  int idx = threadIdx.x;           // 256 threads
  if (idx < 12) PSUM[idx] = 0.f;
  if (idx >= 192) return;
  int l = idx % 3, j = (idx / 3) & 7, i = idx / 24;
  int i4 = (i < 4) ? i : 7 - i;
  int j4 = (j < 4) ? j : 7 - j;
  float s = 0.f;
  for (int f = 0; f < 4; ++f) s += cf[f*3 + l] * mp[f*16 + i4*4 + j4];
  aux8[idx] = s;
}

// ---------------- transfer functions, 6 planes = 3 bands x {dc, d-dc} --------
__global__ void k_transfer(float2* __restrict__ HB) {
  int gid = blockIdx.x * 256 + threadIdx.x;   // 6 * RR2
  int p = gid >> 18, idx = gid & (RR2 - 1);
  int band = p >> 1;
  double wl = d_wls[band];
  double dist = (p & 1) ? (0.05 - 0.047) : 0.047;
  int u = idx >> 9, v = idx & 511;
  double inv_nd = 1.0 / (512.0 * 3.69e-6);
  double fu = (double)((u < 256) ? u : u - 512) * inv_nd;
  double fv = (double)((v < 256) ? v : v - 512) * inv_nd;
  double au = wl * fu, av = wl * fv;
  double argd = 1.0 - au*au - av*av;
  float2 h = make_float2(0.f, 0.f);
  if (argd > 0.0) {
    double kz = (6.283185307179586 / wl) * sqrt(argd);
    double ph = fmod(dist * kz, 6.283185307179586);
    float s, c;
    __sincosf((float)ph, &s, &c);
    h = make_float2(c, s);
  }
  HB[gid] = h;
}

// ---------------- fwd 512 rows fused with pupil-field build ----------------
__global__ __launch_bounds__(128) void k_r512f_field(
    const float* __restrict__ hm, float2* __restrict__ A) {
  __shared__ float2 b0[512], b1[512];
  int t = threadIdx.x;
  int g = blockIdx.x;            // band*512 + r
  int band = g >> 9, r = g & 511;
  float K = (float)(6.283185307179586 / d_wls[band] * d_dn[band]);
  const float* hrow = hm + (size_t)r * 512;
  int dx = r - 256;
  #pragma unroll
  for (int k = 0; k < 4; ++k) {
    int i = t + k*128;
    int dy = i - 256;
    float2 v = make_float2(0.f, 0.f);
    if (dx*dx + dy*dy < 65025) {
      float ph = K * hrow[i];
      float s, c;
      sincosf(ph, &s, &c);
      v = make_float2(c, s);
    }
    b0[i] = v;
  }
  fft512_core<false>(b0, b1, t);
  float2* row = A + (size_t)g * 512;
  #pragma unroll
  for (int k = 0; k < 4; ++k) { int i = t + k*128; row[i] = b1[i]; }
}

// ---------------- 512 cols: fwd + xH + inv, fused ----------------
__global__ __launch_bounds__(256) void k_c512_H(
    float2* __restrict__ data, const float2* __restrict__ HB, int pshift, int hodd) {
  __shared__ float2 b0[512*9], b1[512*9];
  int c = threadIdx.x, w = threadIdx.y;          // (8,32)
  int p = blockIdx.y;
  int band = p >> pshift;
  int col = blockIdx.x * 8 + c;
  float2* img = data + ((size_t)p << 18) + col;
  const float2* Hcol = HB + (((size_t)(band*2 + hodd)) << 18) + col;
  #pragma unroll
  for (int r = w; r < 512; r += 32) b0[r*9 + c] = img[(size_t)r * 512];
  fft512_core_col<false>(b0, b1, w, c);
  #pragma unroll
  for (int r = w; r < 512; r += 32) b0[r*9 + c] = cmulf(b1[r*9 + c], Hcol[(size_t)r * 512]);
  fft512_core_col<true>(b0, b1, w, c);
  const float sc = 1.f/512.f;
  #pragma unroll
  for (int r = w; r < 512; r += 32) {
    float2 v = b1[r*9 + c];
    img[(size_t)r * 512] = make_float2(v.x*sc, v.y*sc);
  }
}

// ------- rows-inv(u1) + mask expand + rows-fwd x4, all row-local -------
__global__ __launch_bounds__(128) void k_r512_invexpand(
    const float2* __restrict__ A, const float* __restrict__ aux8,
    float2* __restrict__ U) {
  __shared__ float2 b0[512], b1[512];
  __shared__ float2 u1row[512];
  int t = threadIdx.x;
  int g = blockIdx.x;            // band*512 + r
  int band = g >> 9, r = g & 511;
  const float2* row = A + (size_t)g * 512;
  #pragma unroll
  for (int k = 0; k < 4; ++k) { int i = t + k*128; b0[i] = row[i]; }
  fft512_core<true>(b0, b1, t);
  const float sc = 1.f/512.f;
  #pragma unroll
  for (int k = 0; k < 4; ++k) {
    int i = t + k*128;
    float2 v = b1[i];
    u1row[i] = make_float2(v.x*sc, v.y*sc);
  }
  for (int p = 0; p < 4; ++p) {
    int i8 = (r + (p >> 1)) & 7;
    const float* arow = aux8 + i8*24 + band;
    #pragma unroll
    for (int k = 0; k < 4; ++k) {
      int i = t + k*128;
      float m = arow[((i + (p & 1)) & 7) * 3];
      float2 v = u1row[i];
      b0[i] = make_float2(v.x*m, v.y*m);
    }
    fft512_core<false>(b0, b1, t);
    float2* orow = U + (((size_t)(band*4 + p)) << 18) + (size_t)r * 512;
    #pragma unroll
    for (int k = 0; k < 4; ++k) { int i = t + k*128; orow[i] = b1[i]; }
  }
}

// ------- rows-inv (2 rows/block) + |.|^2 + 2x2 downsample + PSF sum -------
__global__ __launch_bounds__(256) void k_r512_inv_psf(
    const float2* __restrict__ U, float* __restrict__ PSF, float* __restrict__ PSUM) {
  __shared__ float2 b0[2][512], b1[2][512];
  __shared__ float sq[2][512];
  __shared__ float red[256];
  int t = threadIdx.x, ty = threadIdx.y;         // (128,2)
  int g = blockIdx.x;            // p*256 + i
  int p = g >> 8, i = g & 255;
  const float2* row = U + ((size_t)p << 18) + (size_t)(2*i + ty) * 512;
  #pragma unroll
  for (int k = 0; k < 4; ++k) { int idx = t + k*128; b0[ty][idx] = row[idx]; }
  fft512_core<true>(b0[ty], b1[ty], t);
  #pragma unroll
  for (int k = 0; k < 4; ++k) {
    int idx = t + k*128;
    float2 v = b1[ty][idx];
    sq[ty][idx] = v.x*v.x + v.y*v.y;
  }
  __syncthreads();
  int j = ty*128 + t;            // output col 0..255
  const float sc2 = 0.25f / (512.f * 512.f);
  float val = sc2 * (sq[0][2*j] + sq[0][2*j+1] + sq[1][2*j] + sq[1][2*j+1]);
  PSF[((size_t)p << 16) | (i << 8) | j] = val;
  red[j] = val;
  __syncthreads();
  for (int o = 128; o > 0; o >>= 1) { if (j < o) red[j] += red[j+o]; __syncthreads(); }
  if (j == 0) atomicAdd(PSUM + p, red[0]);
}

// ---------------- fwd 256 rows fused with OTF load (shift+normalize) --------
__global__ __launch_bounds__(128) void k_r256f_otf(
    const float* __restrict__ PSF, const float* __restrict__ PSUM,
    float2* __restrict__ OTF) {
  __shared__ float2 s0[2][256], s1[2][256];
  int t = threadIdx.x, ty = threadIdx.y;
  int g = blockIdx.x * 2 + ty;         // p*256 + i
  int p = g >> 8, i = g & 255;
  float inv = 1.0f / PSUM[p];
  int si = (i + 128) & 255;
  const float* prow = PSF + ((size_t)p << 16) + (si << 8);
  #pragma unroll
  for (int k = 0; k < 4; ++k) {
    int idx = t + k*64;
    s0[ty][idx] = make_float2(prow[(idx + 128) & 255] * inv, 0.f);
  }
  fft256_core<false>(s0[ty], s1[ty], t);
  float2* row = OTF + (size_t)g * 256;
  #pragma unroll
  for (int k = 0; k < 4; ++k) { int idx = t + k*64; row[idx] = s0[ty][idx]; }
}

// ------- OTF cols-fwd (4 planes of one band) fused with parity S build ------
__global__ __launch_bounds__(256) void k_c256w(
    const float2* __restrict__ OTF, float2* __restrict__ Sb) {
  __shared__ float2 b0[256*9], b1[256*9];
  int c = threadIdx.x, w = threadIdx.y;          // (8,32)
  int band = blockIdx.y;
  int col = blockIdx.x * 8 + c;
  float2 S0[8], S1[8], S2[8], S3[8];
  #pragma unroll
  for (int k = 0; k < 8; ++k) {
    S0[k] = make_float2(0.f,0.f); S1[k] = make_float2(0.f,0.f);
    S2[k] = make_float2(0.f,0.f); S3[k] = make_float2(0.f,0.f);
  }
  for (int q = 0; q < 4; ++q) {
    const float2* img = OTF + (((size_t)(band*4 + q)) << 16) + col;
    #pragma unroll
    for (int r = w; r < 256; r += 32) b0[r*9 + c] = img[(size_t)r * 256];
    fft256_core_col<false>(b0, b1, w, c);
    float sg1 = (q & 1) ? -1.f : 1.f;
    float sg2 = (q & 2) ? -1.f : 1.f;
    float sg3 = sg1 * sg2;
    #pragma unroll
    for (int k = 0; k < 8; ++k) {
      int r = w + 32*k;
      float2 z = b0[r*9 + c];
      S0[k] = cadd(S0[k], z);
      S1[k] = make_float2(S1[k].x + sg1*z.x, S1[k].y + sg1*z.y);
      S2[k] = make_float2(S2[k].x + sg2*z.x, S2[k].y + sg2*z.y);
      S3[k] = make_float2(S3[k].x + sg3*z.x, S3[k].y + sg3*z.y);
    }
    __syncthreads();
  }
  float2* S = Sb + (((size_t)(band*4)) << 16);
  #pragma unroll
  for (int k = 0; k < 8; ++k) {
    int r = w + 32*k;
    int uv = (r << 8) | col;
    S[uv] = S0[k];
    S[(1<<16) | uv] = S1[k];
    S[(2<<16) | uv] = S2[k];
    S[(3<<16) | uv] = S3[k];
  }
}

// ---------------- fwd 256 rows fused with input load ----------------
__global__ __launch_bounds__(128) void k_r256f_x(
    const float* __restrict__ in, float2* __restrict__ X) {
  __shared__ float2 s0[2][256], s1[2][256];
  int t = threadIdx.x, ty = threadIdx.y;
  int g = blockIdx.x * 2 + ty;         // p*256 + i, p = band*8 + img
  int p = g >> 8, i = g & 255;
  int band = p >> 3, img = p & 7;
  const float* src = in + (((size_t)img * 256 + i) * 256) * 3 + band;
  #pragma unroll
  for (int k = 0; k < 4; ++k) {
    int idx = t + k*64;
    s0[ty][idx] = make_float2(src[idx*3], 0.f);
  }
  fft256_core<false>(s0[ty], s1[ty], t);
  float2* row = X + (size_t)g * 256;
  #pragma unroll
  for (int k = 0; k < 4; ++k) { int idx = t + k*64; row[idx] = s0[ty][idx]; }
}

// ---------------- 256 cols fwd (X) ----------------
__global__ __launch_bounds__(256) void k_c256_fwd(float2* __restrict__ data) {
  __shared__ float2 b0[256*9], b1[256*9];
  int c = threadIdx.x, w = threadIdx.y;          // (8,32)
  float2* img = data + ((size_t)blockIdx.y << 16) + (size_t)blockIdx.x * 8 + c;
  #pragma unroll
  for (int r = w; r < 256; r += 32) b0[r*9 + c] = img[(size_t)r * 256];
  fft256_core_col<false>(b0, b1, w, c);
  #pragma unroll
  for (int r = w; r < 256; r += 32) img[(size_t)r * 256] = b0[r*9 + c];
}

// ------- ybuild (4-term S combine over closed column quads) + cols-inv ------
__global__ __launch_bounds__(256) void k_ybuild_cinv(
    const float2* __restrict__ X, const float2* __restrict__ Sb,
    float2* __restrict__ Y) {
  __shared__ float2 Xl[256*9];
  __shared__ float2 b0[256*9], b1[256*9];
  int c = threadIdx.x, w = threadIdx.y;          // (8,32)
  int n = blockIdx.y;
  int band = n >> 3;
  // column for slot c: quad base v0 in [0,64), member m in [0,4)
  int v0 = blockIdx.x * 2 + (c >> 2);
  int col = v0 + 64 * (c & 3);
  const float2* Xn = X + ((size_t)n << 16);
  #pragma unroll
  for (int r = w; r < 256; r += 32) Xl[r*9 + c] = Xn[(r << 8) | col];
  __syncthreads();
  const float2* S = Sb + (((size_t)(band*4)) << 16);
  int cA = (c & 4) | (((c & 3) + 3) & 3);   // column (col+192)&255
  int cB = (c & 4) | (((c & 3) + 1) & 3);   // column (col+64)&255
  #pragma unroll
  for (int k = 0; k < 8; ++k) {
    int u = w + 32*k;
    int ua = (u + 192) & 255, ub = (u + 64) & 255;
    float2 X00 = Xl[u*9 + c];
    float2 X01 = Xl[u*9 + cA], X03 = Xl[u*9 + cB];
    float2 X10 = Xl[ua*9 + c], X30 = Xl[ub*9 + c];
    float2 X11 = Xl[ua*9 + cA], X13 = Xl[ua*9 + cB];
    float2 X31 = Xl[ub*9 + cA], X33 = Xl[ub*9 + cB];
    float2 t00 = make_float2(0.25f*X00.x, 0.25f*X00.y);
    float2 t01 = make_float2(0.125f*(X01.x + X03.x - (X03.y - X01.y)),
                             0.125f*(X01.y + X03.y + (X03.x - X01.x)));
    float2 t10 = make_float2(0.125f*(X10.x + X30.x - (X30.y - X10.y)),
                             0.125f*(X10.y + X30.y + (X30.x - X10.x)));
    float2 t11 = make_float2(0.125f*(X13.x + X31.x - (X33.y - X11.y)),
                             0.125f*(X13.y + X31.y + (X33.x - X11.x)));
    int uv = (u << 8) | col;
    float2 acc = cmulf(S[uv], t00);
    acc = cadd(acc, cmulf(S[(1<<16) | uv], t01));
    acc = cadd(acc, cmulf(S[(2<<16) | uv], t10));
    acc = cadd(acc, cmulf(S[(3<<16) | uv], t11));
    b0[u*9 + c] = acc;
  }
  fft256_core_col<true>(b0, b1, w, c);
  const float sc = 1.f/256.f;
  float2* Yp = Y + ((size_t)n << 16) + col;
  #pragma unroll
  for (int r = w; r < 256; r += 32) {
    float2 v = b0[r*9 + c];
    Yp[(size_t)r * 256] = make_float2(v.x*sc, v.y*sc);
  }
}

// ---------------- inv 256 rows over 3 bands fused with color accumulate -----
__global__ __launch_bounds__(128) void k_r256_inv_accum3(
    const float2* __restrict__ Y, float* __restrict__ out,
    const float* __restrict__ cf) {
  __shared__ float2 s0[2][256], s1[2][256];
  int t = threadIdx.x, ty = threadIdx.y;
  int g = blockIdx.x * 2 + ty;         // img*256 + i
  int img = g >> 8, i = g & 255;
  float accR[4] = {0.f,0.f,0.f,0.f};
  float accG[4] = {0.f,0.f,0.f,0.f};
  float accB[4] = {0.f,0.f,0.f,0.f};
  for (int band = 0; band < 3; ++band) {
    const float2* row = Y + (((size_t)(band*8 + img)) << 16) + ((size_t)i << 8);
    #pragma unroll
    for (int k = 0; k < 4; ++k) s0[ty][t + k*64] = row[t + k*64];
    fft256_core<true>(s0[ty], s1[ty], t);
    float c0 = cf[band], c1 = cf[3 + band], c2 = cf[9 + band];
    const float sc = 1.f/256.f;
    #pragma unroll
    for (int k = 0; k < 4; ++k) {
      float re = s0[ty][t + k*64].x * sc;
      accR[k] += c0*re; accG[k] += c1*re; accB[k] += c2*re;
    }
  }
  #pragma unroll
  for (int k = 0; k < 4; ++k) {
    int col = t + k*64;
    float* o = out + (((size_t)img * 256 + i) * 256 + col) * 3;
    o[0] = accR[k]; o[1] = accG[k]; o[2] = accB[k];
  }
}

// ================= host-side dispatch =================

extern "C" void kernel_launch(void* const* d_in, const int* in_sizes, int n_in,
                              void* d_out, int out_size, void* d_ws, size_t ws_size,
                              hipStream_t stream) {
  const float* inp = (const float*)d_in[0];   // (8,256,256,3)
  const float* zc  = (const float*)d_in[1];   // (64,1,1)
  const float* zv  = (const float*)d_in[2];   // (64,512,512)
  const float* mp  = (const float*)d_in[3];   // (4,4,4)
  const float* cf  = (const float*)d_in[4];   // (4,3)
  float* out = (float*)d_out;                 // (8,256,256,3)

  char* ws = (char*)d_ws;
  size_t off = 0;
  auto alloc = [&](size_t bytes) -> void* {
    void* p = ws + off;
    off = (off + bytes + 255) & ~(size_t)255;
    return p;
  };
  float*  hm   = (float*) alloc((size_t)RR2 * 4);            // 1 MB
  float*  aux8 = (float*) alloc(256 * 4);
  float*  PSUM = (float*) alloc(64 * 4);
  float2* A    = (float2*)alloc((size_t)3 * RR2 * 8);        // 6 MB
  float2* HB   = (float2*)alloc((size_t)6 * RR2 * 8);        // 12 MB
  float2* U    = (float2*)alloc((size_t)12 * RR2 * 8);       // 24 MB
  float*  PSF  = (float*) alloc((size_t)12 * PP2 * 4);       // 3 MB
  float2* OTF  = (float2*)alloc((size_t)12 * PP2 * 8);       // 6 MB
  float2* Sb   = (float2*)alloc((size_t)12 * PP2 * 8);       // 6 MB
  float2* X    = (float2*)alloc((size_t)24 * PP2 * 8);       // 12 MB
  float2* Y    = (float2*)alloc((size_t)24 * PP2 * 8);       // 12 MB

  // ---- setup ----
  k_height4<<<RR2/4/256, 256, 0, stream>>>(zc, (const float4*)zv, (float4*)hm);
  k_aux<<<1, 256, 0, stream>>>(mp, cf, aux8, PSUM);
  k_transfer<<<6*RR2/256, 256, 0, stream>>>(HB);

  // ---- u1 for all 3 bands: rows-fwd -> (cols-fwd + xH + cols-inv) ----
  k_r512f_field<<<3*512, 128, 0, stream>>>(hm, A);
  k_c512_H<<<dim3(64, 3), dim3(8, 32), 0, stream>>>(A, HB, 0, 0);

  // ---- rows-inv(u1) + expand + rows-fwd -> U (12 planes) ----
  k_r512_invexpand<<<3*512, 128, 0, stream>>>(A, aux8, U);
  k_c512_H<<<dim3(64, 12), dim3(8, 32), 0, stream>>>(U, HB, 2, 1);
  k_r512_inv_psf<<<12*256, dim3(128, 2), 0, stream>>>(U, PSF, PSUM);

  // ---- OTFs + parity S build ----
  k_r256f_otf<<<12*256/2, dim3(64, 2), 0, stream>>>(PSF, PSUM, OTF);
  k_c256w<<<dim3(32, 3), dim3(8, 32), 0, stream>>>(OTF, Sb);

  // ---- convolution: FFT(X), fused 4-term combine + cols-inv, rows-inv ----
  k_r256f_x<<<24*256/2, dim3(64, 2), 0, stream>>>(inp, X);
  k_c256_fwd<<<dim3(32, 24), dim3(8, 32), 0, stream>>>(X);
  k_ybuild_cinv<<<dim3(32, 24), dim3(8, 32), 0, stream>>>(X, Sb, Y);
  k_r256_inv_accum3<<<8*256/2, dim3(64, 2), 0, stream>>>(Y, out, cf);
}

// Round 5
// 228.418 us; speedup vs baseline: 1.0088x; 1.0088x over previous
//
#include <hip/hip_runtime.h>
#include <math.h>

#define RR 512
#define RR2 (RR*RR)
#define PP 256
#define PP2 (PP*PP)

__constant__ double d_wls[3] = {4.6e-7, 5.4e-7, 6.2e-7};
__constant__ double d_dn[3]  = {0.52, 0.515, 0.51};

__device__ __forceinline__ float2 cadd(float2 a, float2 b){ return make_float2(a.x+b.x, a.y+b.y); }
__device__ __forceinline__ float2 csub(float2 a, float2 b){ return make_float2(a.x-b.x, a.y-b.y); }
__device__ __forceinline__ float2 cmulf(float2 a, float2 b){ return make_float2(a.x*b.x-a.y*b.y, a.x*b.y+a.y*b.x); }

// ======================================================================
// Wave-level FFT: N = 64 lanes x R regs, element n = lane + 64*reg.
// fwd: reg-DFT (R-pt) -> twiddle W_N^{lane*m} -> cross-lane 64 DIF (shfl).
//      output: lane holds q bit-reversed, reg pos p holds m = brR(p).
//      storage: out[lane + 64*m] = v[brR(m)]  ->  f(s) = (s>>6) + R_hi*bitrev6(s&63)
// inv: exact mirror; output pos p = x[lane + 64*brR(p)] (unscaled).
// ======================================================================

// cross-lane 64-pt DIF fwd (natural lanes in -> bitrev lanes out)
template<int R>
__device__ __forceinline__ void xf64_fwd(float2* v, int lane) {
  #pragma unroll
  for (int h = 32; h >= 1; h >>= 1) {
    float ang = -6.2831853071795865f * (float)(lane & (h-1)) / (float)(2*h);
    float sn, cs;
    __sincosf(ang, &sn, &cs);
    bool odd = (lane & h) != 0;
    float wc = odd ? cs : 1.f;
    float ws = odd ? sn : 0.f;
    #pragma unroll
    for (int r = 0; r < R; ++r) {
      float2 t;
      t.x = __shfl_xor(v[r].x, h);
      t.y = __shfl_xor(v[r].y, h);
      float2 d = odd ? csub(t, v[r]) : cadd(v[r], t);
      v[r] = make_float2(d.x*wc - d.y*ws, d.x*ws + d.y*wc);
    }
  }
}

// cross-lane 64-pt DIT inverse (bitrev lanes in -> natural lanes out), unscaled
template<int R>
__device__ __forceinline__ void xf64_inv(float2* v, int lane) {
  #pragma unroll
  for (int h = 1; h <= 32; h <<= 1) {
    float ang = 6.2831853071795865f * (float)(lane & (h-1)) / (float)(2*h);
    float sn, cs;
    __sincosf(ang, &sn, &cs);
    bool odd = (lane & h) != 0;
    #pragma unroll
    for (int r = 0; r < R; ++r) {
      float2 t;
      t.x = __shfl_xor(v[r].x, h);
      t.y = __shfl_xor(v[r].y, h);
      float2 s = odd ? v[r] : t;
      float2 ws = make_float2(s.x*cs - s.y*sn, s.x*sn + s.y*cs);
      v[r] = odd ? csub(t, ws) : cadd(v[r], ws);
    }
  }
}

// 8-pt DIF over regs, natural in, bitrev3 positions out
template<bool INV>
__device__ __forceinline__ void reg_fft8(float2* a) {
  const float C = 0.70710678118654752f;
  // h = 4
  {
    float2 t0 = csub(a[0], a[4]); a[0] = cadd(a[0], a[4]); a[4] = t0;
    float2 t1 = csub(a[1], a[5]); a[1] = cadd(a[1], a[5]);
    a[5] = INV ? make_float2(C*(t1.x - t1.y), C*(t1.x + t1.y))
               : make_float2(C*(t1.x + t1.y), C*(t1.y - t1.x));
    float2 t2 = csub(a[2], a[6]); a[2] = cadd(a[2], a[6]);
    a[6] = INV ? make_float2(-t2.y, t2.x) : make_float2(t2.y, -t2.x);
    float2 t3 = csub(a[3], a[7]); a[3] = cadd(a[3], a[7]);
    a[7] = INV ? make_float2(-C*(t3.x + t3.y), C*(t3.x - t3.y))
               : make_float2(C*(t3.y - t3.x), -C*(t3.x + t3.y));
  }
  // h = 2
  #pragma unroll
  for (int g = 0; g < 2; ++g) {
    int b = g*4;
    float2 t0 = csub(a[b], a[b+2]); a[b] = cadd(a[b], a[b+2]); a[b+2] = t0;
    float2 t1 = csub(a[b+1], a[b+3]); a[b+1] = cadd(a[b+1], a[b+3]);
    a[b+3] = INV ? make_float2(-t1.y, t1.x) : make_float2(t1.y, -t1.x);
  }
  // h = 1
  #pragma unroll
  for (int g = 0; g < 4; ++g) {
    int b = g*2;
    float2 t = csub(a[b], a[b+1]); a[b] = cadd(a[b], a[b+1]); a[b+1] = t;
  }
}

// 4-pt DIF over regs, natural in, bitrev2 positions out
template<bool INV>
__device__ __forceinline__ void reg_fft4(float2* a) {
  float2 t0 = csub(a[0], a[2]); a[0] = cadd(a[0], a[2]); a[2] = t0;
  float2 t1 = csub(a[1], a[3]); a[1] = cadd(a[1], a[3]);
  a[3] = INV ? make_float2(-t1.y, t1.x) : make_float2(t1.y, -t1.x);
  t0 = csub(a[0], a[1]); a[0] = cadd(a[0], a[1]); a[1] = t0;
  t1 = csub(a[2], a[3]); a[2] = cadd(a[2], a[3]); a[3] = t1;
}

__device__ __forceinline__ void wfft512_fwd(float2* v, int lane) {
  const int BR3[8] = {0,4,2,6,1,5,3,7};
  reg_fft8<false>(v);                          // pos p holds m = br3(p)
  float ang = -6.2831853071795865f * (float)lane * (1.f/512.f);
  float sn, cs; __sincosf(ang, &sn, &cs);
  float2 w1 = make_float2(cs, sn), w = w1;
  #pragma unroll
  for (int m = 1; m < 8; ++m) {
    v[BR3[m]] = cmulf(v[BR3[m]], w);
    if (m < 7) w = cmulf(w, w1);
  }
  xf64_fwd<8>(v, lane);
}

__device__ __forceinline__ void wfft512_inv(float2* v, int lane) {
  xf64_inv<8>(v, lane);
  float ang = 6.2831853071795865f * (float)lane * (1.f/512.f);
  float sn, cs; __sincosf(ang, &sn, &cs);
  float2 w1 = make_float2(cs, sn), w = w1;
  #pragma unroll
  for (int m = 1; m < 8; ++m) {
    v[m] = cmulf(v[m], w);
    if (m < 7) w = cmulf(w, w1);
  }
  reg_fft8<true>(v);                           // pos p holds n2 = br3(p)
}

__device__ __forceinline__ void wfft256_fwd(float2* v, int lane) {
  const int BR2[4] = {0,2,1,3};
  reg_fft4<false>(v);
  float ang = -6.2831853071795865f * (float)lane * (1.f/256.f);
  float sn, cs; __sincosf(ang, &sn, &cs);
  float2 w1 = make_float2(cs, sn), w = w1;
  #pragma unroll
  for (int m = 1; m < 4; ++m) {
    v[BR2[m]] = cmulf(v[BR2[m]], w);
    if (m < 3) w = cmulf(w, w1);
  }
  xf64_fwd<4>(v, lane);
}

__device__ __forceinline__ void wfft256_inv(float2* v, int lane) {
  xf64_inv<4>(v, lane);
  float ang = 6.2831853071795865f * (float)lane * (1.f/256.f);
  float sn, cs; __sincosf(ang, &sn, &cs);
  float2 w1 = make_float2(cs, sn), w = w1;
  #pragma unroll
  for (int m = 1; m < 4; ++m) {
    v[m] = cmulf(v[m], w);
    if (m < 3) w = cmulf(w, w1);
  }
  reg_fft4<true>(v);
}

// ================= LDS column-FFT cores (unchanged structure) =================

template<bool INV>
__device__ __forceinline__ float2 cjrot(float2 z){ return INV ? make_float2(-z.y, z.x) : make_float2(z.y, -z.x); }

template<int N, int STR, bool INV>
__device__ __forceinline__ void bfly4(const float2* __restrict__ in, float2* __restrict__ out,
                                      int t, int m, int off) {
  int j = t & ~(m-1);
  float2 a0 = in[t*STR + off];
  float2 a1 = in[(t + N/4)*STR + off];
  float2 a2 = in[(t + N/2)*STR + off];
  float2 a3 = in[(t + 3*(N/4))*STR + off];
  float2 e0 = cadd(a0,a2), o0 = cadd(a1,a3);
  float2 e1 = csub(a0,a2), o1 = csub(a1,a3);
  float2 c0 = cadd(e0,o0), c2 = csub(e0,o0);
  float2 r1 = cjrot<INV>(o1);
  float2 c1 = cadd(e1,r1), c3 = csub(e1,r1);
  float ang = (INV ? 6.2831853071795865f : -6.2831853071795865f) * (float)j * (1.0f/(float)N);
  float sn, cs; __sincosf(ang, &sn, &cs);
  float2 w1 = make_float2(cs, sn);
  float2 w2 = make_float2(cs*cs - sn*sn, 2.f*cs*sn);
  float2 w3 = cmulf(w2, w1);
  int base = 4*j + (t - j);
  out[base*STR + off]       = c0;
  out[(base+m)*STR + off]   = cmulf(c1, w1);
  out[(base+2*m)*STR + off] = cmulf(c2, w2);
  out[(base+3*m)*STR + off] = cmulf(c3, w3);
}

template<bool INV>
__device__ __forceinline__ void fft512_core_col(float2* __restrict__ b0, float2* __restrict__ b1,
                                                int w, int c) {
  __syncthreads();
  #pragma unroll
  for (int k=0;k<4;++k) bfly4<512,9,INV>(b0,b1,w+32*k,1,c);
  __syncthreads();
  #pragma unroll
  for (int k=0;k<4;++k) bfly4<512,9,INV>(b1,b0,w+32*k,4,c);
  __syncthreads();
  #pragma unroll
  for (int k=0;k<4;++k) bfly4<512,9,INV>(b0,b1,w+32*k,16,c);
  __syncthreads();
  #pragma unroll
  for (int k=0;k<4;++k) bfly4<512,9,INV>(b1,b0,w+32*k,64,c);
  __syncthreads();
  #pragma unroll
  for (int k=0;k<8;++k) {
    int tt = w + 32*k;
    float2 a = b0[tt*9+c], b = b0[(tt+256)*9+c];
    b1[tt*9+c] = cadd(a,b); b1[(tt+256)*9+c] = csub(a,b);
  }
  __syncthreads();
}

template<bool INV>
__device__ __forceinline__ void fft256_core_col(float2* __restrict__ b0, float2* __restrict__ b1,
                                                int w, int c) {
  __syncthreads();
  #pragma unroll
  for (int k=0;k<2;++k) bfly4<256,9,INV>(b0,b1,w+32*k,1,c);
  __syncthreads();
  #pragma unroll
  for (int k=0;k<2;++k) bfly4<256,9,INV>(b1,b0,w+32*k,4,c);
  __syncthreads();
  #pragma unroll
  for (int k=0;k<2;++k) bfly4<256,9,INV>(b0,b1,w+32*k,16,c);
  __syncthreads();
  #pragma unroll
  for (int k=0;k<2;++k) bfly4<256,9,INV>(b1,b0,w+32*k,64,c);
  __syncthreads();
}

// ---------------- height map ----------------
__global__ void k_height4(const float* __restrict__ zc, const float4* __restrict__ zv,
                          float4* __restrict__ hm) {
  int idx = blockIdx.x * 256 + threadIdx.x;
  float4 s = make_float4(0.f,0.f,0.f,0.f);
  #pragma unroll 8
  for (int t = 0; t < 64; ++t) {
    float c = zc[t];
    float4 v = zv[(size_t)t * (RR2/4) + idx];
    s.x += c*v.x; s.y += c*v.y; s.z += c*v.z; s.w += c*v.w;
  }
  hm[idx] = s;
}

// ---------------- aux tile + PSUM zero ----------------
__global__ void k_aux(const float* __restrict__ mp, const float* __restrict__ cf,
                      float* __restrict__ aux8, float* __restrict__ PSUM) {
  int idx = threadIdx.x;
  if (idx < 12) PSUM[idx] = 0.f;
  if (idx >= 192) return;
  int l = idx % 3, j = (idx / 3) & 7, i = idx / 24;
  int i4 = (i < 4) ? i : 7 - i;
  int j4 = (j < 4) ? j : 7 - j;
  float s = 0.f;
  for (int f = 0; f < 4; ++f) s += cf[f*3 + l] * mp[f*16 + i4*4 + j4];
  aux8[idx] = s;
}

// ---------------- transfer: both dists per band, one kz ----------------
__global__ void k_transfer(float2* __restrict__ HB) {
  int gid = blockIdx.x * 256 + threadIdx.x;   // 3 * RR2
  int band = gid >> 18, idx = gid & (RR2 - 1);
  double wl = d_wls[band];
  int u = idx >> 9, v = idx & 511;
  double inv_nd = 1.0 / (512.0 * 3.69e-6);
  double fu = (double)((u < 256) ? u : u - 512) * inv_nd;
  double fv = (double)((v < 256) ? v : v - 512) * inv_nd;
  double au = wl * fu, av = wl * fv;
  double argd = 1.0 - au*au - av*av;
  float2 h0 = make_float2(0.f, 0.f), h1 = h0;
  if (argd > 0.0) {
    double kz = (6.283185307179586 / wl) * sqrt(argd);
    float s, c;
    double p0 = fmod(0.047 * kz, 6.283185307179586);
    __sincosf((float)p0, &s, &c); h0 = make_float2(c, s);
    double p1 = fmod(0.003 * kz, 6.283185307179586);
    __sincosf((float)p1, &s, &c); h1 = make_float2(c, s);
  }
  HB[(size_t)(band*2    ) * RR2 + idx] = h0;
  HB[(size_t)(band*2 + 1) * RR2 + idx] = h1;
}

// ---------------- field build + wave rows-fwd ----------------
__global__ __launch_bounds__(256) void k_r512f_field(
    const float* __restrict__ hm, float2* __restrict__ A) {
  const int BR3[8] = {0,4,2,6,1,5,3,7};
  int lane = threadIdx.x & 63;
  int wid = (blockIdx.x << 2) | (threadIdx.x >> 6);   // band*512 + r
  int band = wid >> 9, r = wid & 511;
  float K = (float)(6.283185307179586 / d_wls[band] * d_dn[band]);
  const float* hrow = hm + (size_t)r * 512;
  int dx = r - 256;
  float2 v[8];
  #pragma unroll
  for (int m = 0; m < 8; ++m) {
    int col = lane + (m << 6);
    int dy = col - 256;
    float2 f = make_float2(0.f, 0.f);
    if (dx*dx + dy*dy < 65025) {
      float ph = K * hrow[col];
      float s, c;
      sincosf(ph, &s, &c);
      f = make_float2(c, s);
    }
    v[m] = f;
  }
  wfft512_fwd(v, lane);
  float2* row = A + (size_t)wid * 512;
  #pragma unroll
  for (int m = 0; m < 8; ++m) row[lane + (m << 6)] = v[BR3[m]];
}

// ---------------- 512 cols: fwd + xH + inv (H at permuted fu) ----------------
__global__ __launch_bounds__(256) void k_c512_H(
    float2* __restrict__ data, const float2* __restrict__ HB, int pshift, int hodd) {
  __shared__ float2 b0[512*9], b1[512*9];
  int c = threadIdx.x, w = threadIdx.y;          // (8,32)
  int p = blockIdx.y;
  int band = p >> pshift;
  int s = blockIdx.x * 8 + c;                    // stored column
  int fu = (s >> 6) + 8 * (__brev(s & 63) >> 26);
  float2* img = data + ((size_t)p << 18) + s;
  const float2* Hcol = HB + (((size_t)(band*2 + hodd)) << 18) + fu;
  #pragma unroll
  for (int r = w; r < 512; r += 32) b0[r*9 + c] = img[(size_t)r * 512];
  fft512_core_col<false>(b0, b1, w, c);
  #pragma unroll
  for (int r = w; r < 512; r += 32) b0[r*9 + c] = cmulf(b1[r*9 + c], Hcol[(size_t)r * 512]);
  fft512_core_col<true>(b0, b1, w, c);
  const float sc = 1.f/512.f;
  #pragma unroll
  for (int r = w; r < 512; r += 32) {
    float2 v = b1[r*9 + c];
    img[(size_t)r * 512] = make_float2(v.x*sc, v.y*sc);
  }
}

// ------- wave rows-inv(u1) + mask expand + wave rows-fwd x4 -------
__global__ __launch_bounds__(256) void k_r512_invexpand(
    const float2* __restrict__ A, const float* __restrict__ aux8,
    float2* __restrict__ U) {
  const int BR3[8] = {0,4,2,6,1,5,3,7};
  int lane = threadIdx.x & 63;
  int wid = (blockIdx.x << 2) | (threadIdx.x >> 6);   // band*512 + r
  int band = wid >> 9, r = wid & 511;
  const float2* row = A + (size_t)wid * 512;
  float2 v[8];
  #pragma unroll
  for (int m = 0; m < 8; ++m) v[m] = row[lane + (m << 6)];
  wfft512_inv(v, lane);
  const float sc = 1.f/512.f;
  float2 u1[8];                       // natural n2 order
  #pragma unroll
  for (int n2 = 0; n2 < 8; ++n2) {
    float2 t = v[BR3[n2]];
    u1[n2] = make_float2(t.x*sc, t.y*sc);
  }
  int j8base = lane & 7;
  for (int pm = 0; pm < 4; ++pm) {
    int i8 = (r + (pm >> 1)) & 7;
    float mval = aux8[i8*24 + ((j8base + (pm & 1)) & 7) * 3 + band];
    float2 wv[8];
    #pragma unroll
    for (int n2 = 0; n2 < 8; ++n2) wv[n2] = make_float2(u1[n2].x*mval, u1[n2].y*mval);
    wfft512_fwd(wv, lane);
    float2* orow = U + (((size_t)(band*4 + pm)) << 18) + (size_t)r * 512;
    #pragma unroll
    for (int m = 0; m < 8; ++m) orow[lane + (m << 6)] = wv[BR3[m]];
  }
}

// ------- wave rows-inv (row pair) + |.|^2 + 2x2 downsample + PSF sum -------
__global__ __launch_bounds__(256) void k_r512_inv_psf(
    const float2* __restrict__ U, float* __restrict__ PSF, float* __restrict__ PSUM) {
  const int BR3[8] = {0,4,2,6,1,5,3,7};
  int lane = threadIdx.x & 63;
  int wid = (blockIdx.x << 2) | (threadIdx.x >> 6);   // p*256 + i
  int p = wid >> 8, i = wid & 255;
  const float2* base = U + ((size_t)p << 18);
  float colsum[8];
  #pragma unroll
  for (int m = 0; m < 8; ++m) colsum[m] = 0.f;
  float tot = 0.f;
  #pragma unroll
  for (int rr = 0; rr < 2; ++rr) {
    const float2* row = base + (size_t)(2*i + rr) * 512;
    float2 v[8];
    #pragma unroll
    for (int m = 0; m < 8; ++m) v[m] = row[lane + (m << 6)];
    wfft512_inv(v, lane);
    #pragma unroll
    for (int pos = 0; pos < 8; ++pos) {
      float sq = v[pos].x*v[pos].x + v[pos].y*v[pos].y;
      tot += sq;
      colsum[pos] += sq;
    }
  }
  const float sc2 = 0.25f / (512.f * 512.f);
  #pragma unroll
  for (int pos = 0; pos < 8; ++pos) {
    float pairs = colsum[pos] + __shfl_xor(colsum[pos], 1);
    if (!(lane & 1)) {
      int col = (lane >> 1) + (BR3[pos] << 5);
      PSF[((size_t)p << 16) | (i << 8) | col] = sc2 * pairs;
    }
  }
  #pragma unroll
  for (int h = 1; h < 64; h <<= 1) tot += __shfl_xor(tot, h);
  if (lane == 0) atomicAdd(PSUM + p, tot * sc2);
}

// ---------------- wave rows-fwd fused with OTF load (shift+normalize) --------
__global__ __launch_bounds__(256) void k_r256f_otf(
    const float* __restrict__ PSF, const float* __restrict__ PSUM,
    float2* __restrict__ OTF) {
  const int BR2[4] = {0,2,1,3};
  int lane = threadIdx.x & 63;
  int wid = (blockIdx.x << 2) | (threadIdx.x >> 6);   // p*256 + i
  int p = wid >> 8, i = wid & 255;
  float inv = 1.0f / PSUM[p];
  int si = (i + 128) & 255;
  const float* prow = PSF + ((size_t)p << 16) + (si << 8);
  float2 v[4];
  #pragma unroll
  for (int m = 0; m < 4; ++m) {
    int col = lane + (((m + 2) & 3) << 6);   // (n+128)&255 with n = lane+64m
    v[m] = make_float2(prow[col] * inv, 0.f);
  }
  wfft256_fwd(v, lane);
  float2* row = OTF + (size_t)wid * 256;
  #pragma unroll
  for (int m = 0; m < 4; ++m) row[lane + (m << 6)] = v[BR2[m]];
}

// ------- OTF cols-fwd (4 planes of one band) fused with parity S build ------
__global__ __launch_bounds__(256) void k_c256w(
    const float2* __restrict__ OTF, float2* __restrict__ Sb) {
  __shared__ float2 b0[256*9], b1[256*9];
  int c = threadIdx.x, w = threadIdx.y;          // (8,32)
  int band = blockIdx.y;
  int col = blockIdx.x * 8 + c;
  float2 S0[8], S1[8], S2[8], S3[8];
  #pragma unroll
  for (int k = 0; k < 8; ++k) {
    S0[k] = make_float2(0.f,0.f); S1[k] = make_float2(0.f,0.f);
    S2[k] = make_float2(0.f,0.f); S3[k] = make_float2(0.f,0.f);
  }
  for (int q = 0; q < 4; ++q) {
    const float2* img = OTF + (((size_t)(band*4 + q)) << 16) + col;
    #pragma unroll
    for (int r = w; r < 256; r += 32) b0[r*9 + c] = img[(size_t)r * 256];
    fft256_core_col<false>(b0, b1, w, c);
    float sg1 = (q & 1) ? -1.f : 1.f;
    float sg2 = (q & 2) ? -1.f : 1.f;
    float sg3 = sg1 * sg2;
    #pragma unroll
    for (int k = 0; k < 8; ++k) {
      int r = w + 32*k;
      float2 z = b0[r*9 + c];
      S0[k] = cadd(S0[k], z);
      S1[k] = make_float2(S1[k].x + sg1*z.x, S1[k].y + sg1*z.y);
      S2[k] = make_float2(S2[k].x + sg2*z.x, S2[k].y + sg2*z.y);
      S3[k] = make_float2(S3[k].x + sg3*z.x, S3[k].y + sg3*z.y);
    }
    __syncthreads();
  }
  float2* S = Sb + (((size_t)(band*4)) << 16);
  #pragma unroll
  for (int k = 0; k < 8; ++k) {
    int r = w + 32*k;
    int uv = (r << 8) | col;
    S[uv] = S0[k];
    S[(1<<16) | uv] = S1[k];
    S[(2<<16) | uv] = S2[k];
    S[(3<<16) | uv] = S3[k];
  }
}

// ---------------- wave rows-fwd fused with input load ----------------
__global__ __launch_bounds__(256) void k_r256f_x(
    const float* __restrict__ in, float2* __restrict__ X) {
  const int BR2[4] = {0,2,1,3};
  int lane = threadIdx.x & 63;
  int wid = (blockIdx.x << 2) | (threadIdx.x >> 6);   // p*256 + i, p = band*8+img
  int p = wid >> 8, i = wid & 255;
  int band = p >> 3, img = p & 7;
  const float* src = in + (((size_t)img * 256 + i) * 256) * 3 + band;
  float2 v[4];
  #pragma unroll
  for (int m = 0; m < 4; ++m) v[m] = make_float2(src[(lane + (m << 6)) * 3], 0.f);
  wfft256_fwd(v, lane);
  float2* row = X + (size_t)wid * 256;
  #pragma unroll
  for (int m = 0; m < 4; ++m) row[lane + (m << 6)] = v[BR2[m]];
}

// ---------------- 256 cols fwd (X) ----------------
__global__ __launch_bounds__(256) void k_c256_fwd(float2* __restrict__ data) {
  __shared__ float2 b0[256*9], b1[256*9];
  int c = threadIdx.x, w = threadIdx.y;
  float2* img = data + ((size_t)blockIdx.y << 16) + (size_t)blockIdx.x * 8 + c;
  #pragma unroll
  for (int r = w; r < 256; r += 32) b0[r*9 + c] = img[(size_t)r * 256];
  fft256_core_col<false>(b0, b1, w, c);
  #pragma unroll
  for (int r = w; r < 256; r += 32) img[(size_t)r * 256] = b0[r*9 + c];
}

// ------- ybuild (4-term S combine; quads = lane low-2-bit perm) + cols-inv ---
__global__ __launch_bounds__(256) void k_ybuild_cinv(
    const float2* __restrict__ X, const float2* __restrict__ Sb,
    float2* __restrict__ Y) {
  __shared__ float2 Xl[256*9];
  __shared__ float2 b0[256*9], b1[256*9];
  const int CAm[4] = {3,2,0,1};   // v-tap a=1 (fx-64) member map
  const int CBm[4] = {2,3,1,0};   // v-tap a=3 (fx-192) member map
  int c = threadIdx.x, w = threadIdx.y;          // (8,32)
  int n = blockIdx.y;
  int band = n >> 3;
  int col = blockIdx.x * 8 + c;                  // stored column
  const float2* Xn = X + ((size_t)n << 16);
  #pragma unroll
  for (int r = w; r < 256; r += 32) Xl[r*9 + c] = Xn[(r << 8) | col];
  __syncthreads();
  const float2* S = Sb + (((size_t)(band*4)) << 16);
  int cA = (c & 4) | CAm[c & 3];
  int cB = (c & 4) | CBm[c & 3];
  #pragma unroll
  for (int k = 0; k < 8; ++k) {
    int u = w + 32*k;
    int ua = (u + 192) & 255, ub = (u + 64) & 255;
    float2 X00 = Xl[u*9 + c];
    float2 X01 = Xl[u*9 + cA], X03 = Xl[u*9 + cB];
    float2 X10 = Xl[ua*9 + c], X30 = Xl[ub*9 + c];
    float2 X11 = Xl[ua*9 + cA], X13 = Xl[ua*9 + cB];
    float2 X31 = Xl[ub*9 + cA], X33 = Xl[ub*9 + cB];
    float2 t00 = make_float2(0.25f*X00.x, 0.25f*X00.y);
    float2 t01 = make_float2(0.125f*(X01.x + X03.x - (X03.y - X01.y)),
                             0.125f*(X01.y + X03.y + (X03.x - X01.x)));
    float2 t10 = make_float2(0.125f*(X10.x + X30.x - (X30.y - X10.y)),
                             0.125f*(X10.y + X30.y + (X30.x - X10.x)));
    float2 t11 = make_float2(0.125f*(X13.x + X31.x - (X33.y - X11.y)),
                             0.125f*(X13.y + X31.y + (X33.x - X11.x)));
    int uv = (u << 8) | col;
    float2 acc = cmulf(S[uv], t00);
    acc = cadd(acc, cmulf(S[(1<<16) | uv], t01));
    acc = cadd(acc, cmulf(S[(2<<16) | uv], t10));
    acc = cadd(acc, cmulf(S[(3<<16) | uv], t11));
    b0[u*9 + c] = acc;
  }
  fft256_core_col<true>(b0, b1, w, c);
  const float sc = 1.f/256.f;
  float2* Yp = Y + ((size_t)n << 16) + col;
  #pragma unroll
  for (int r = w; r < 256; r += 32) {
    float2 v = b0[r*9 + c];
    Yp[(size_t)r * 256] = make_float2(v.x*sc, v.y*sc);
  }
}

// ---------------- wave rows-inv over 3 bands + color accumulate ----------------
__global__ __launch_bounds__(256) void k_r256_inv_accum3(
    const float2* __restrict__ Y, float* __restrict__ out,
    const float* __restrict__ cf) {
  const int BR2[4] = {0,2,1,3};
  int lane = threadIdx.x & 63;
  int wid = (blockIdx.x << 2) | (threadIdx.x >> 6);   // img*256 + i
  int img = wid >> 8, i = wid & 255;
  float accR[4] = {0.f,0.f,0.f,0.f};
  float accG[4] = {0.f,0.f,0.f,0.f};
  float accB[4] = {0.f,0.f,0.f,0.f};
  const float sc = 1.f/256.f;
  for (int band = 0; band < 3; ++band) {
    const float2* row = Y + (((size_t)(band*8 + img)) << 16) + ((size_t)i << 8);
    float2 v[4];
    #pragma unroll
    for (int m = 0; m < 4; ++m) v[m] = row[lane + (m << 6)];
    wfft256_inv(v, lane);
    float c0 = cf[band], c1 = cf[3 + band], c2 = cf[9 + band];
    #pragma unroll
    for (int pos = 0; pos < 4; ++pos) {
      float re = v[pos].x * sc;
      int n2 = BR2[pos];
      accR[n2] += c0*re; accG[n2] += c1*re; accB[n2] += c2*re;
    }
  }
  #pragma unroll
  for (int n2 = 0; n2 < 4; ++n2) {
    int col = lane + (n2 << 6);
    float* o = out + (((size_t)img * 256 + i) * 256 + col) * 3;
    o[0] = accR[n2]; o[1] = accG[n2]; o[2] = accB[n2];
  }
}

// ================= host-side dispatch =================

extern "C" void kernel_launch(void* const* d_in, const int* in_sizes, int n_in,
                              void* d_out, int out_size, void* d_ws, size_t ws_size,
                              hipStream_t stream) {
  const float* inp = (const float*)d_in[0];
  const float* zc  = (const float*)d_in[1];
  const float* zv  = (const float*)d_in[2];
  const float* mp  = (const float*)d_in[3];
  const float* cf  = (const float*)d_in[4];
  float* out = (float*)d_out;

  char* ws = (char*)d_ws;
  size_t off = 0;
  auto alloc = [&](size_t bytes) -> void* {
    void* p = ws + off;
    off = (off + bytes + 255) & ~(size_t)255;
    return p;
  };
  float*  hm   = (float*) alloc((size_t)RR2 * 4);
  float*  aux8 = (float*) alloc(256 * 4);
  float*  PSUM = (float*) alloc(64 * 4);
  float2* A    = (float2*)alloc((size_t)3 * RR2 * 8);
  float2* HB   = (float2*)alloc((size_t)6 * RR2 * 8);
  float2* U    = (float2*)alloc((size_t)12 * RR2 * 8);
  float*  PSF  = (float*) alloc((size_t)12 * PP2 * 4);
  float2* OTF  = (float2*)alloc((size_t)12 * PP2 * 8);
  float2* Sb   = (float2*)alloc((size_t)12 * PP2 * 8);
  float2* X    = (float2*)alloc((size_t)24 * PP2 * 8);
  float2* Y    = (float2*)alloc((size_t)24 * PP2 * 8);

  // ---- setup ----
  k_height4<<<RR2/4/256, 256, 0, stream>>>(zc, (const float4*)zv, (float4*)hm);
  k_aux<<<1, 256, 0, stream>>>(mp, cf, aux8, PSUM);
  k_transfer<<<3*RR2/256, 256, 0, stream>>>(HB);

  // ---- u1: wave rows-fwd -> (cols-fwd + xH + cols-inv) ----
  k_r512f_field<<<3*512/4, 256, 0, stream>>>(hm, A);
  k_c512_H<<<dim3(64, 3), dim3(8, 32), 0, stream>>>(A, HB, 0, 0);

  // ---- wave rows-inv(u1) + expand + rows-fwd -> U (12 planes) ----
  k_r512_invexpand<<<3*512/4, 256, 0, stream>>>(A, aux8, U);
  k_c512_H<<<dim3(64, 12), dim3(8, 32), 0, stream>>>(U, HB, 2, 1);
  k_r512_inv_psf<<<12*256/4, 256, 0, stream>>>(U, PSF, PSUM);

  // ---- OTFs + parity S build ----
  k_r256f_otf<<<12*256/4, 256, 0, stream>>>(PSF, PSUM, OTF);
  k_c256w<<<dim3(32, 3), dim3(8, 32), 0, stream>>>(OTF, Sb);

  // ---- convolution ----
  k_r256f_x<<<24*256/4, 256, 0, stream>>>(inp, X);
  k_c256_fwd<<<dim3(32, 24), dim3(8, 32), 0, stream>>>(X);
  k_ybuild_cinv<<<dim3(32, 24), dim3(8, 32), 0, stream>>>(X, Sb, Y);
  k_r256_inv_accum3<<<8*256/4, 256, 0, stream>>>(Y, out, cf);
}

// Round 6
// 193.616 us; speedup vs baseline: 1.1901x; 1.1798x over previous
//
#include <hip/hip_runtime.h>
#include <math.h>

#define RR 512
#define RR2 (RR*RR)
#define PP 256
#define PP2 (PP*PP)

__constant__ double d_wls[3] = {4.6e-7, 5.4e-7, 6.2e-7};
__constant__ double d_dn[3]  = {0.52, 0.515, 0.51};

__device__ __forceinline__ float2 cadd(float2 a, float2 b){ return make_float2(a.x+b.x, a.y+b.y); }
__device__ __forceinline__ float2 csub(float2 a, float2 b){ return make_float2(a.x-b.x, a.y-b.y); }
__device__ __forceinline__ float2 cmulf(float2 a, float2 b){ return make_float2(a.x*b.x-a.y*b.y, a.x*b.y+a.y*b.x); }

// ======================================================================
// Wave-level FFT: N = 64 lanes x R regs, element n = lane + 64*reg.
// fwd: reg-DFT (R-pt) -> twiddle W_N^{lane*m} -> cross-lane 64 DIF (shfl).
//      storage: out[lane + 64*m] = v[brR(m)]  ->  f(s) = (s>>6) + R_hi*bitrev6(s&63)
// inv: exact mirror; output pos p = x[lane + 64*brR(p)] (unscaled).
// ======================================================================

template<int R>
__device__ __forceinline__ void xf64_fwd(float2* v, int lane) {
  #pragma unroll
  for (int h = 32; h >= 1; h >>= 1) {
    float ang = -6.2831853071795865f * (float)(lane & (h-1)) / (float)(2*h);
    float sn, cs;
    __sincosf(ang, &sn, &cs);
    bool odd = (lane & h) != 0;
    float wc = odd ? cs : 1.f;
    float ws = odd ? sn : 0.f;
    #pragma unroll
    for (int r = 0; r < R; ++r) {
      float2 t;
      t.x = __shfl_xor(v[r].x, h);
      t.y = __shfl_xor(v[r].y, h);
      float2 d = odd ? csub(t, v[r]) : cadd(v[r], t);
      v[r] = make_float2(d.x*wc - d.y*ws, d.x*ws + d.y*wc);
    }
  }
}

template<int R>
__device__ __forceinline__ void xf64_inv(float2* v, int lane) {
  #pragma unroll
  for (int h = 1; h <= 32; h <<= 1) {
    float ang = 6.2831853071795865f * (float)(lane & (h-1)) / (float)(2*h);
    float sn, cs;
    __sincosf(ang, &sn, &cs);
    bool odd = (lane & h) != 0;
    #pragma unroll
    for (int r = 0; r < R; ++r) {
      float2 t;
      t.x = __shfl_xor(v[r].x, h);
      t.y = __shfl_xor(v[r].y, h);
      float2 s = odd ? v[r] : t;
      float2 ws = make_float2(s.x*cs - s.y*sn, s.x*sn + s.y*cs);
      v[r] = odd ? csub(t, ws) : cadd(v[r], ws);
    }
  }
}

template<bool INV>
__device__ __forceinline__ void reg_fft8(float2* a) {
  const float C = 0.70710678118654752f;
  {
    float2 t0 = csub(a[0], a[4]); a[0] = cadd(a[0], a[4]); a[4] = t0;
    float2 t1 = csub(a[1], a[5]); a[1] = cadd(a[1], a[5]);
    a[5] = INV ? make_float2(C*(t1.x - t1.y), C*(t1.x + t1.y))
               : make_float2(C*(t1.x + t1.y), C*(t1.y - t1.x));
    float2 t2 = csub(a[2], a[6]); a[2] = cadd(a[2], a[6]);
    a[6] = INV ? make_float2(-t2.y, t2.x) : make_float2(t2.y, -t2.x);
    float2 t3 = csub(a[3], a[7]); a[3] = cadd(a[3], a[7]);
    a[7] = INV ? make_float2(-C*(t3.x + t3.y), C*(t3.x - t3.y))
               : make_float2(C*(t3.y - t3.x), -C*(t3.x + t3.y));
  }
  #pragma unroll
  for (int g = 0; g < 2; ++g) {
    int b = g*4;
    float2 t0 = csub(a[b], a[b+2]); a[b] = cadd(a[b], a[b+2]); a[b+2] = t0;
    float2 t1 = csub(a[b+1], a[b+3]); a[b+1] = cadd(a[b+1], a[b+3]);
    a[b+3] = INV ? make_float2(-t1.y, t1.x) : make_float2(t1.y, -t1.x);
  }
  #pragma unroll
  for (int g = 0; g < 4; ++g) {
    int b = g*2;
    float2 t = csub(a[b], a[b+1]); a[b] = cadd(a[b], a[b+1]); a[b+1] = t;
  }
}

template<bool INV>
__device__ __forceinline__ void reg_fft4(float2* a) {
  float2 t0 = csub(a[0], a[2]); a[0] = cadd(a[0], a[2]); a[2] = t0;
  float2 t1 = csub(a[1], a[3]); a[1] = cadd(a[1], a[3]);
  a[3] = INV ? make_float2(-t1.y, t1.x) : make_float2(t1.y, -t1.x);
  t0 = csub(a[0], a[1]); a[0] = cadd(a[0], a[1]); a[1] = t0;
  t1 = csub(a[2], a[3]); a[2] = cadd(a[2], a[3]); a[3] = t1;
}

__device__ __forceinline__ void wfft512_fwd(float2* v, int lane) {
  const int BR3[8] = {0,4,2,6,1,5,3,7};
  reg_fft8<false>(v);
  float ang = -6.2831853071795865f * (float)lane * (1.f/512.f);
  float sn, cs; __sincosf(ang, &sn, &cs);
  float2 w1 = make_float2(cs, sn), w = w1;
  #pragma unroll
  for (int m = 1; m < 8; ++m) {
    v[BR3[m]] = cmulf(v[BR3[m]], w);
    if (m < 7) w = cmulf(w, w1);
  }
  xf64_fwd<8>(v, lane);
}

__device__ __forceinline__ void wfft512_inv(float2* v, int lane) {
  xf64_inv<8>(v, lane);
  float ang = 6.2831853071795865f * (float)lane * (1.f/512.f);
  float sn, cs; __sincosf(ang, &sn, &cs);
  float2 w1 = make_float2(cs, sn), w = w1;
  #pragma unroll
  for (int m = 1; m < 8; ++m) {
    v[m] = cmulf(v[m], w);
    if (m < 7) w = cmulf(w, w1);
  }
  reg_fft8<true>(v);
}

__device__ __forceinline__ void wfft256_fwd(float2* v, int lane) {
  const int BR2[4] = {0,2,1,3};
  reg_fft4<false>(v);
  float ang = -6.2831853071795865f * (float)lane * (1.f/256.f);
  float sn, cs; __sincosf(ang, &sn, &cs);
  float2 w1 = make_float2(cs, sn), w = w1;
  #pragma unroll
  for (int m = 1; m < 4; ++m) {
    v[BR2[m]] = cmulf(v[BR2[m]], w);
    if (m < 3) w = cmulf(w, w1);
  }
  xf64_fwd<4>(v, lane);
}

__device__ __forceinline__ void wfft256_inv(float2* v, int lane) {
  xf64_inv<4>(v, lane);
  float ang = 6.2831853071795865f * (float)lane * (1.f/256.f);
  float sn, cs; __sincosf(ang, &sn, &cs);
  float2 w1 = make_float2(cs, sn), w = w1;
  #pragma unroll
  for (int m = 1; m < 4; ++m) {
    v[m] = cmulf(v[m], w);
    if (m < 3) w = cmulf(w, w1);
  }
  reg_fft4<true>(v);
}

// ================= LDS column-FFT cores =================

template<bool INV>
__device__ __forceinline__ float2 cjrot(float2 z){ return INV ? make_float2(-z.y, z.x) : make_float2(z.y, -z.x); }

template<int N, int STR, bool INV>
__device__ __forceinline__ void bfly4(const float2* __restrict__ in, float2* __restrict__ out,
                                      int t, int m, int off) {
  int j = t & ~(m-1);
  float2 a0 = in[t*STR + off];
  float2 a1 = in[(t + N/4)*STR + off];
  float2 a2 = in[(t + N/2)*STR + off];
  float2 a3 = in[(t + 3*(N/4))*STR + off];
  float2 e0 = cadd(a0,a2), o0 = cadd(a1,a3);
  float2 e1 = csub(a0,a2), o1 = csub(a1,a3);
  float2 c0 = cadd(e0,o0), c2 = csub(e0,o0);
  float2 r1 = cjrot<INV>(o1);
  float2 c1 = cadd(e1,r1), c3 = csub(e1,r1);
  float ang = (INV ? 6.2831853071795865f : -6.2831853071795865f) * (float)j * (1.0f/(float)N);
  float sn, cs; __sincosf(ang, &sn, &cs);
  float2 w1 = make_float2(cs, sn);
  float2 w2 = make_float2(cs*cs - sn*sn, 2.f*cs*sn);
  float2 w3 = cmulf(w2, w1);
  int base = 4*j + (t - j);
  out[base*STR + off]       = c0;
  out[(base+m)*STR + off]   = cmulf(c1, w1);
  out[(base+2*m)*STR + off] = cmulf(c2, w2);
  out[(base+3*m)*STR + off] = cmulf(c3, w3);
}

template<bool INV>
__device__ __forceinline__ void fft512_core_col(float2* __restrict__ b0, float2* __restrict__ b1,
                                                int w, int c) {
  __syncthreads();
  #pragma unroll
  for (int k=0;k<4;++k) bfly4<512,9,INV>(b0,b1,w+32*k,1,c);
  __syncthreads();
  #pragma unroll
  for (int k=0;k<4;++k) bfly4<512,9,INV>(b1,b0,w+32*k,4,c);
  __syncthreads();
  #pragma unroll
  for (int k=0;k<4;++k) bfly4<512,9,INV>(b0,b1,w+32*k,16,c);
  __syncthreads();
  #pragma unroll
  for (int k=0;k<4;++k) bfly4<512,9,INV>(b1,b0,w+32*k,64,c);
  __syncthreads();
  #pragma unroll
  for (int k=0;k<8;++k) {
    int tt = w + 32*k;
    float2 a = b0[tt*9+c], b = b0[(tt+256)*9+c];
    b1[tt*9+c] = cadd(a,b); b1[(tt+256)*9+c] = csub(a,b);
  }
  __syncthreads();
}

template<bool INV>
__device__ __forceinline__ void fft256_core_col(float2* __restrict__ b0, float2* __restrict__ b1,
                                                int w, int c) {
  __syncthreads();
  #pragma unroll
  for (int k=0;k<2;++k) bfly4<256,9,INV>(b0,b1,w+32*k,1,c);
  __syncthreads();
  #pragma unroll
  for (int k=0;k<2;++k) bfly4<256,9,INV>(b1,b0,w+32*k,4,c);
  __syncthreads();
  #pragma unroll
  for (int k=0;k<2;++k) bfly4<256,9,INV>(b0,b1,w+32*k,16,c);
  __syncthreads();
  #pragma unroll
  for (int k=0;k<2;++k) bfly4<256,9,INV>(b1,b0,w+32*k,64,c);
  __syncthreads();
}

// ---------------- height map ----------------
__global__ void k_height4(const float* __restrict__ zc, const float4* __restrict__ zv,
                          float4* __restrict__ hm) {
  int idx = blockIdx.x * 256 + threadIdx.x;
  float4 s = make_float4(0.f,0.f,0.f,0.f);
  #pragma unroll 8
  for (int t = 0; t < 64; ++t) {
    float c = zc[t];
    float4 v = zv[(size_t)t * (RR2/4) + idx];
    s.x += c*v.x; s.y += c*v.y; s.z += c*v.z; s.w += c*v.w;
  }
  hm[idx] = s;
}

// ---------------- aux tile ----------------
__global__ void k_aux(const float* __restrict__ mp, const float* __restrict__ cf,
                      float* __restrict__ aux8) {
  int idx = threadIdx.x;
  if (idx >= 192) return;
  int l = idx % 3, j = (idx / 3) & 7, i = idx / 24;
  int i4 = (i < 4) ? i : 7 - i;
  int j4 = (j < 4) ? j : 7 - j;
  float s = 0.f;
  for (int f = 0; f < 4; ++f) s += cf[f*3 + l] * mp[f*16 + i4*4 + j4];
  aux8[idx] = s;
}

// ---------------- transfer: both dists per band, one kz ----------------
__global__ void k_transfer(float2* __restrict__ HB) {
  int gid = blockIdx.x * 256 + threadIdx.x;   // 3 * RR2
  int band = gid >> 18, idx = gid & (RR2 - 1);
  double wl = d_wls[band];
  int u = idx >> 9, v = idx & 511;
  double inv_nd = 1.0 / (512.0 * 3.69e-6);
  double fu = (double)((u < 256) ? u : u - 512) * inv_nd;
  double fv = (double)((v < 256) ? v : v - 512) * inv_nd;
  double au = wl * fu, av = wl * fv;
  double argd = 1.0 - au*au - av*av;
  float2 h0 = make_float2(0.f, 0.f), h1 = h0;
  if (argd > 0.0) {
    double kz = (6.283185307179586 / wl) * sqrt(argd);
    float s, c;
    double p0 = fmod(0.047 * kz, 6.283185307179586);
    __sincosf((float)p0, &s, &c); h0 = make_float2(c, s);
    double p1 = fmod(0.003 * kz, 6.283185307179586);
    __sincosf((float)p1, &s, &c); h1 = make_float2(c, s);
  }
  HB[(size_t)(band*2    ) * RR2 + idx] = h0;
  HB[(size_t)(band*2 + 1) * RR2 + idx] = h1;
}

// ---------------- field build + wave rows-fwd ----------------
__global__ __launch_bounds__(256) void k_r512f_field(
    const float* __restrict__ hm, float2* __restrict__ A) {
  const int BR3[8] = {0,4,2,6,1,5,3,7};
  int lane = threadIdx.x & 63;
  int wid = (blockIdx.x << 2) | (threadIdx.x >> 6);   // band*512 + r
  int band = wid >> 9, r = wid & 511;
  float K = (float)(6.283185307179586 / d_wls[band] * d_dn[band]);
  const float* hrow = hm + (size_t)r * 512;
  int dx = r - 256;
  float2 v[8];
  #pragma unroll
  for (int m = 0; m < 8; ++m) {
    int col = lane + (m << 6);
    int dy = col - 256;
    float2 f = make_float2(0.f, 0.f);
    if (dx*dx + dy*dy < 65025) {
      float ph = K * hrow[col];
      float s, c;
      sincosf(ph, &s, &c);
      f = make_float2(c, s);
    }
    v[m] = f;
  }
  wfft512_fwd(v, lane);
  float2* row = A + (size_t)wid * 512;
  #pragma unroll
  for (int m = 0; m < 8; ++m) row[lane + (m << 6)] = v[BR3[m]];
}

// ---------------- 512 cols: fwd + xH + inv (H at permuted fu) ----------------
__global__ __launch_bounds__(256) void k_c512_H(
    float2* __restrict__ data, const float2* __restrict__ HB, int pshift, int hodd) {
  __shared__ float2 b0[512*9], b1[512*9];
  int c = threadIdx.x, w = threadIdx.y;          // (8,32)
  int p = blockIdx.y;
  int band = p >> pshift;
  int s = blockIdx.x * 8 + c;                    // stored column
  int fu = (s >> 6) + 8 * (__brev(s & 63) >> 26);
  float2* img = data + ((size_t)p << 18) + s;
  const float2* Hcol = HB + (((size_t)(band*2 + hodd)) << 18) + fu;
  #pragma unroll
  for (int r = w; r < 512; r += 32) b0[r*9 + c] = img[(size_t)r * 512];
  fft512_core_col<false>(b0, b1, w, c);
  #pragma unroll
  for (int r = w; r < 512; r += 32) b0[r*9 + c] = cmulf(b1[r*9 + c], Hcol[(size_t)r * 512]);
  fft512_core_col<true>(b0, b1, w, c);
  const float sc = 1.f/512.f;
  #pragma unroll
  for (int r = w; r < 512; r += 32) {
    float2 v = b1[r*9 + c];
    img[(size_t)r * 512] = make_float2(v.x*sc, v.y*sc);
  }
}

// ------- wave rows-inv(u1) + mask expand + wave rows-fwd x4 -------
__global__ __launch_bounds__(256) void k_r512_invexpand(
    const float2* __restrict__ A, const float* __restrict__ aux8,
    float2* __restrict__ U) {
  const int BR3[8] = {0,4,2,6,1,5,3,7};
  int lane = threadIdx.x & 63;
  int wid = (blockIdx.x << 2) | (threadIdx.x >> 6);   // band*512 + r
  int band = wid >> 9, r = wid & 511;
  const float2* row = A + (size_t)wid * 512;
  float2 v[8];
  #pragma unroll
  for (int m = 0; m < 8; ++m) v[m] = row[lane + (m << 6)];
  wfft512_inv(v, lane);
  const float sc = 1.f/512.f;
  float2 u1[8];                       // natural n2 order
  #pragma unroll
  for (int n2 = 0; n2 < 8; ++n2) {
    float2 t = v[BR3[n2]];
    u1[n2] = make_float2(t.x*sc, t.y*sc);
  }
  int j8base = lane & 7;
  for (int pm = 0; pm < 4; ++pm) {
    int i8 = (r + (pm >> 1)) & 7;
    float mval = aux8[i8*24 + ((j8base + (pm & 1)) & 7) * 3 + band];
    float2 wv[8];
    #pragma unroll
    for (int n2 = 0; n2 < 8; ++n2) wv[n2] = make_float2(u1[n2].x*mval, u1[n2].y*mval);
    wfft512_fwd(wv, lane);
    float2* orow = U + (((size_t)(band*4 + pm)) << 18) + (size_t)r * 512;
    #pragma unroll
    for (int m = 0; m < 8; ++m) orow[lane + (m << 6)] = wv[BR3[m]];
  }
}

// ------- wave rows-inv (row pair, pipelined) + |.|^2 + 2x2 down + partial sum --
__global__ __launch_bounds__(256) void k_r512_inv_psf(
    const float2* __restrict__ U, float* __restrict__ PSF, float* __restrict__ PSUMP) {
  const int BR3[8] = {0,4,2,6,1,5,3,7};
  int lane = threadIdx.x & 63;
  int wid = (blockIdx.x << 2) | (threadIdx.x >> 6);   // p*256 + i
  int p = wid >> 8, i = wid & 255;
  const float2* row0 = U + ((size_t)p << 18) + (size_t)(2*i) * 512;
  const float2* row1 = row0 + 512;
  float2 v0[8], v1[8];
  #pragma unroll
  for (int m = 0; m < 8; ++m) v0[m] = row0[lane + (m << 6)];
  #pragma unroll
  for (int m = 0; m < 8; ++m) v1[m] = row1[lane + (m << 6)];
  wfft512_inv(v0, lane);
  wfft512_inv(v1, lane);
  float colsum[8];
  float tot = 0.f;
  #pragma unroll
  for (int pos = 0; pos < 8; ++pos) {
    float sq = v0[pos].x*v0[pos].x + v0[pos].y*v0[pos].y
             + v1[pos].x*v1[pos].x + v1[pos].y*v1[pos].y;
    tot += sq;
    colsum[pos] = sq;
  }
  const float sc2 = 0.25f / (512.f * 512.f);
  #pragma unroll
  for (int pos = 0; pos < 8; ++pos) {
    float pairs = colsum[pos] + __shfl_xor(colsum[pos], 1);
    if (!(lane & 1)) {
      int col = (lane >> 1) + (BR3[pos] << 5);
      PSF[((size_t)p << 16) | (i << 8) | col] = sc2 * pairs;
    }
  }
  #pragma unroll
  for (int h = 1; h < 64; h <<= 1) tot += __shfl_xor(tot, h);
  if (lane == 0) PSUMP[(p << 8) | i] = tot * sc2;   // plain store, no atomic
}

// --- wave rows-fwd fused with OTF load (shift + in-wave psum reduce + norm) ---
__global__ __launch_bounds__(256) void k_r256f_otf(
    const float* __restrict__ PSF, const float* __restrict__ PSUMP,
    float2* __restrict__ OTF) {
  const int BR2[4] = {0,2,1,3};
  int lane = threadIdx.x & 63;
  int wid = (blockIdx.x << 2) | (threadIdx.x >> 6);   // p*256 + i
  int p = wid >> 8, i = wid & 255;
  // reduce 256 per-row partials of plane p (coalesced float4 + butterfly)
  const float4* pp = reinterpret_cast<const float4*>(PSUMP + (p << 8));
  float4 q = pp[lane];
  float tot = (q.x + q.y) + (q.z + q.w);
  #pragma unroll
  for (int h = 1; h < 64; h <<= 1) tot += __shfl_xor(tot, h);
  float inv = 1.0f / tot;
  int si = (i + 128) & 255;
  const float* prow = PSF + ((size_t)p << 16) + (si << 8);
  float2 v[4];
  #pragma unroll
  for (int m = 0; m < 4; ++m) {
    int col = lane + (((m + 2) & 3) << 6);   // (n+128)&255 with n = lane+64m
    v[m] = make_float2(prow[col] * inv, 0.f);
  }
  wfft256_fwd(v, lane);
  float2* row = OTF + (size_t)wid * 256;
  #pragma unroll
  for (int m = 0; m < 4; ++m) row[lane + (m << 6)] = v[BR2[m]];
}

// ------- OTF cols-fwd (4 planes of one band) fused with parity S build ------
__global__ __launch_bounds__(256) void k_c256w(
    const float2* __restrict__ OTF, float2* __restrict__ Sb) {
  __shared__ float2 b0[256*9], b1[256*9];
  int c = threadIdx.x, w = threadIdx.y;          // (8,32)
  int band = blockIdx.y;
  int col = blockIdx.x * 8 + c;
  float2 S0[8], S1[8], S2[8], S3[8];
  #pragma unroll
  for (int k = 0; k < 8; ++k) {
    S0[k] = make_float2(0.f,0.f); S1[k] = make_float2(0.f,0.f);
    S2[k] = make_float2(0.f,0.f); S3[k] = make_float2(0.f,0.f);
  }
  for (int q = 0; q < 4; ++q) {
    const float2* img = OTF + (((size_t)(band*4 + q)) << 16) + col;
    #pragma unroll
    for (int r = w; r < 256; r += 32) b0[r*9 + c] = img[(size_t)r * 256];
    fft256_core_col<false>(b0, b1, w, c);
    float sg1 = (q & 1) ? -1.f : 1.f;
    float sg2 = (q & 2) ? -1.f : 1.f;
    float sg3 = sg1 * sg2;
    #pragma unroll
    for (int k = 0; k < 8; ++k) {
      int r = w + 32*k;
      float2 z = b0[r*9 + c];
      S0[k] = cadd(S0[k], z);
      S1[k] = make_float2(S1[k].x + sg1*z.x, S1[k].y + sg1*z.y);
      S2[k] = make_float2(S2[k].x + sg2*z.x, S2[k].y + sg2*z.y);
      S3[k] = make_float2(S3[k].x + sg3*z.x, S3[k].y + sg3*z.y);
    }
    __syncthreads();
  }
  float2* S = Sb + (((size_t)(band*4)) << 16);
  #pragma unroll
  for (int k = 0; k < 8; ++k) {
    int r = w + 32*k;
    int uv = (r << 8) | col;
    S[uv] = S0[k];
    S[(1<<16) | uv] = S1[k];
    S[(2<<16) | uv] = S2[k];
    S[(3<<16) | uv] = S3[k];
  }
}

// ---------------- wave rows-fwd fused with input load ----------------
__global__ __launch_bounds__(256) void k_r256f_x(
    const float* __restrict__ in, float2* __restrict__ X) {
  const int BR2[4] = {0,2,1,3};
  int lane = threadIdx.x & 63;
  int wid = (blockIdx.x << 2) | (threadIdx.x >> 6);   // p*256 + i, p = band*8+img
  int p = wid >> 8, i = wid & 255;
  int band = p >> 3, img = p & 7;
  const float* src = in + (((size_t)img * 256 + i) * 256) * 3 + band;
  float2 v[4];
  #pragma unroll
  for (int m = 0; m < 4; ++m) v[m] = make_float2(src[(lane + (m << 6)) * 3], 0.f);
  wfft256_fwd(v, lane);
  float2* row = X + (size_t)wid * 256;
  #pragma unroll
  for (int m = 0; m < 4; ++m) row[lane + (m << 6)] = v[BR2[m]];
}

// ---------------- 256 cols fwd (X) ----------------
__global__ __launch_bounds__(256) void k_c256_fwd(float2* __restrict__ data) {
  __shared__ float2 b0[256*9], b1[256*9];
  int c = threadIdx.x, w = threadIdx.y;
  float2* img = data + ((size_t)blockIdx.y << 16) + (size_t)blockIdx.x * 8 + c;
  #pragma unroll
  for (int r = w; r < 256; r += 32) b0[r*9 + c] = img[(size_t)r * 256];
  fft256_core_col<false>(b0, b1, w, c);
  #pragma unroll
  for (int r = w; r < 256; r += 32) img[(size_t)r * 256] = b0[r*9 + c];
}

// ------- ybuild (4-term S combine; quads = lane low-2-bit perm) + cols-inv ---
__global__ __launch_bounds__(256) void k_ybuild_cinv(
    const float2* __restrict__ X, const float2* __restrict__ Sb,
    float2* __restrict__ Y) {
  __shared__ float2 Xl[256*9];
  __shared__ float2 b0[256*9], b1[256*9];
  const int CAm[4] = {3,2,0,1};
  const int CBm[4] = {2,3,1,0};
  int c = threadIdx.x, w = threadIdx.y;          // (8,32)
  int n = blockIdx.y;
  int band = n >> 3;
  int col = blockIdx.x * 8 + c;                  // stored column
  const float2* Xn = X + ((size_t)n << 16);
  #pragma unroll
  for (int r = w; r < 256; r += 32) Xl[r*9 + c] = Xn[(r << 8) | col];
  __syncthreads();
  const float2* S = Sb + (((size_t)(band*4)) << 16);
  int cA = (c & 4) | CAm[c & 3];
  int cB = (c & 4) | CBm[c & 3];
  #pragma unroll
  for (int k = 0; k < 8; ++k) {
    int u = w + 32*k;
    int ua = (u + 192) & 255, ub = (u + 64) & 255;
    float2 X00 = Xl[u*9 + c];
    float2 X01 = Xl[u*9 + cA], X03 = Xl[u*9 + cB];
    float2 X10 = Xl[ua*9 + c], X30 = Xl[ub*9 + c];
    float2 X11 = Xl[ua*9 + cA], X13 = Xl[ua*9 + cB];
    float2 X31 = Xl[ub*9 + cA], X33 = Xl[ub*9 + cB];
    float2 t00 = make_float2(0.25f*X00.x, 0.25f*X00.y);
    float2 t01 = make_float2(0.125f*(X01.x + X03.x - (X03.y - X01.y)),
                             0.125f*(X01.y + X03.y + (X03.x - X01.x)));
    float2 t10 = make_float2(0.125f*(X10.x + X30.x - (X30.y - X10.y)),
                             0.125f*(X10.y + X30.y + (X30.x - X10.x)));
    float2 t11 = make_float2(0.125f*(X13.x + X31.x - (X33.y - X11.y)),
                             0.125f*(X13.y + X31.y + (X33.x - X11.x)));
    int uv = (u << 8) | col;
    float2 acc = cmulf(S[uv], t00);
    acc = cadd(acc, cmulf(S[(1<<16) | uv], t01));
    acc = cadd(acc, cmulf(S[(2<<16) | uv], t10));
    acc = cadd(acc, cmulf(S[(3<<16) | uv], t11));
    b0[u*9 + c] = acc;
  }
  fft256_core_col<true>(b0, b1, w, c);
  const float sc = 1.f/256.f;
  float2* Yp = Y + ((size_t)n << 16) + col;
  #pragma unroll
  for (int r = w; r < 256; r += 32) {
    float2 v = b0[r*9 + c];
    Yp[(size_t)r * 256] = make_float2(v.x*sc, v.y*sc);
  }
}

// ---------------- wave rows-inv over 3 bands + color accumulate ----------------
__global__ __launch_bounds__(256) void k_r256_inv_accum3(
    const float2* __restrict__ Y, float* __restrict__ out,
    const float* __restrict__ cf) {
  const int BR2[4] = {0,2,1,3};
  int lane = threadIdx.x & 63;
  int wid = (blockIdx.x << 2) | (threadIdx.x >> 6);   // img*256 + i
  int img = wid >> 8, i = wid & 255;
  float accR[4] = {0.f,0.f,0.f,0.f};
  float accG[4] = {0.f,0.f,0.f,0.f};
  float accB[4] = {0.f,0.f,0.f,0.f};
  const float sc = 1.f/256.f;
  for (int band = 0; band < 3; ++band) {
    const float2* row = Y + (((size_t)(band*8 + img)) << 16) + ((size_t)i << 8);
    float2 v[4];
    #pragma unroll
    for (int m = 0; m < 4; ++m) v[m] = row[lane + (m << 6)];
    wfft256_inv(v, lane);
    float c0 = cf[band], c1 = cf[3 + band], c2 = cf[9 + band];
    #pragma unroll
    for (int pos = 0; pos < 4; ++pos) {
      float re = v[pos].x * sc;
      int n2 = BR2[pos];
      accR[n2] += c0*re; accG[n2] += c1*re; accB[n2] += c2*re;
    }
  }
  #pragma unroll
  for (int n2 = 0; n2 < 4; ++n2) {
    int col = lane + (n2 << 6);
    float* o = out + (((size_t)img * 256 + i) * 256 + col) * 3;
    o[0] = accR[n2]; o[1] = accG[n2]; o[2] = accB[n2];
  }
}

// ================= host-side dispatch =================

extern "C" void kernel_launch(void* const* d_in, const int* in_sizes, int n_in,
                              void* d_out, int out_size, void* d_ws, size_t ws_size,
                              hipStream_t stream) {
  const float* inp = (const float*)d_in[0];
  const float* zc  = (const float*)d_in[1];
  const float* zv  = (const float*)d_in[2];
  const float* mp  = (const float*)d_in[3];
  const float* cf  = (const float*)d_in[4];
  float* out = (float*)d_out;

  char* ws = (char*)d_ws;
  size_t off = 0;
  auto alloc = [&](size_t bytes) -> void* {
    void* p = ws + off;
    off = (off + bytes + 255) & ~(size_t)255;
    return p;
  };
  float*  hm    = (float*) alloc((size_t)RR2 * 4);
  float*  aux8  = (float*) alloc(256 * 4);
  float*  PSUMP = (float*) alloc((size_t)12 * 256 * 4);
  float2* A     = (float2*)alloc((size_t)3 * RR2 * 8);
  float2* HB    = (float2*)alloc((size_t)6 * RR2 * 8);
  float2* U     = (float2*)alloc((size_t)12 * RR2 * 8);
  float*  PSF   = (float*) alloc((size_t)12 * PP2 * 4);
  float2* OTF   = (float2*)alloc((size_t)12 * PP2 * 8);
  float2* Sb    = (float2*)alloc((size_t)12 * PP2 * 8);
  float2* X     = (float2*)alloc((size_t)24 * PP2 * 8);
  float2* Y     = (float2*)alloc((size_t)24 * PP2 * 8);

  // ---- setup ----
  k_height4<<<RR2/4/256, 256, 0, stream>>>(zc, (const float4*)zv, (float4*)hm);
  k_aux<<<1, 256, 0, stream>>>(mp, cf, aux8);
  k_transfer<<<3*RR2/256, 256, 0, stream>>>(HB);

  // ---- u1: wave rows-fwd -> (cols-fwd + xH + cols-inv) ----
  k_r512f_field<<<3*512/4, 256, 0, stream>>>(hm, A);
  k_c512_H<<<dim3(64, 3), dim3(8, 32), 0, stream>>>(A, HB, 0, 0);

  // ---- wave rows-inv(u1) + expand + rows-fwd -> U (12 planes) ----
  k_r512_invexpand<<<3*512/4, 256, 0, stream>>>(A, aux8, U);
  k_c512_H<<<dim3(64, 12), dim3(8, 32), 0, stream>>>(U, HB, 2, 1);
  k_r512_inv_psf<<<12*256/4, 256, 0, stream>>>(U, PSF, PSUMP);

  // ---- OTFs + parity S build ----
  k_r256f_otf<<<12*256/4, 256, 0, stream>>>(PSF, PSUMP, OTF);
  k_c256w<<<dim3(32, 3), dim3(8, 32), 0, stream>>>(OTF, Sb);

  // ---- convolution ----
  k_r256f_x<<<24*256/4, 256, 0, stream>>>(inp, X);
  k_c256_fwd<<<dim3(32, 24), dim3(8, 32), 0, stream>>>(X);
  k_ybuild_cinv<<<dim3(32, 24), dim3(8, 32), 0, stream>>>(X, Sb, Y);
  k_r256_inv_accum3<<<8*256/4, 256, 0, stream>>>(Y, out, cf);
}

// Round 7
// 179.340 us; speedup vs baseline: 1.2849x; 1.0796x over previous
//
#include <hip/hip_runtime.h>
#include <math.h>

#define RR 512
#define RR2 (RR*RR)
#define PP 256
#define PP2 (PP*PP)

__constant__ double d_wls[3] = {4.6e-7, 5.4e-7, 6.2e-7};
__constant__ double d_dn[3]  = {0.52, 0.515, 0.51};

__device__ __forceinline__ float2 cadd(float2 a, float2 b){ return make_float2(a.x+b.x, a.y+b.y); }
__device__ __forceinline__ float2 csub(float2 a, float2 b){ return make_float2(a.x-b.x, a.y-b.y); }
__device__ __forceinline__ float2 cmulf(float2 a, float2 b){ return make_float2(a.x*b.x-a.y*b.y, a.x*b.y+a.y*b.x); }

// ======================================================================
// Wave-level FFT: N = 64 lanes x R regs, element n = lane + 64*reg.
// fwd: reg-DFT (R-pt) -> twiddle W_N^{lane*m} -> cross-lane 64 DIF (shfl).
//      storage: out[lane + 64*m] = v[brR(m)]  ->  f(s) = (s>>6) + R_hi*bitrev6(s&63)
// inv: exact mirror; output pos p = x[lane + 64*brR(p)] (unscaled).
// ======================================================================

template<int R>
__device__ __forceinline__ void xf64_fwd(float2* v, int lane) {
  #pragma unroll
  for (int h = 32; h >= 1; h >>= 1) {
    float ang = -6.2831853071795865f * (float)(lane & (h-1)) / (float)(2*h);
    float sn, cs;
    __sincosf(ang, &sn, &cs);
    bool odd = (lane & h) != 0;
    float wc = odd ? cs : 1.f;
    float ws = odd ? sn : 0.f;
    #pragma unroll
    for (int r = 0; r < R; ++r) {
      float2 t;
      t.x = __shfl_xor(v[r].x, h);
      t.y = __shfl_xor(v[r].y, h);
      float2 d = odd ? csub(t, v[r]) : cadd(v[r], t);
      v[r] = make_float2(d.x*wc - d.y*ws, d.x*ws + d.y*wc);
    }
  }
}

template<int R>
__device__ __forceinline__ void xf64_inv(float2* v, int lane) {
  #pragma unroll
  for (int h = 1; h <= 32; h <<= 1) {
    float ang = 6.2831853071795865f * (float)(lane & (h-1)) / (float)(2*h);
    float sn, cs;
    __sincosf(ang, &sn, &cs);
    bool odd = (lane & h) != 0;
    #pragma unroll
    for (int r = 0; r < R; ++r) {
      float2 t;
      t.x = __shfl_xor(v[r].x, h);
      t.y = __shfl_xor(v[r].y, h);
      float2 s = odd ? v[r] : t;
      float2 ws = make_float2(s.x*cs - s.y*sn, s.x*sn + s.y*cs);
      v[r] = odd ? csub(t, ws) : cadd(v[r], ws);
    }
  }
}

template<bool INV>
__device__ __forceinline__ void reg_fft8(float2* a) {
  const float C = 0.70710678118654752f;
  {
    float2 t0 = csub(a[0], a[4]); a[0] = cadd(a[0], a[4]); a[4] = t0;
    float2 t1 = csub(a[1], a[5]); a[1] = cadd(a[1], a[5]);
    a[5] = INV ? make_float2(C*(t1.x - t1.y), C*(t1.x + t1.y))
               : make_float2(C*(t1.x + t1.y), C*(t1.y - t1.x));
    float2 t2 = csub(a[2], a[6]); a[2] = cadd(a[2], a[6]);
    a[6] = INV ? make_float2(-t2.y, t2.x) : make_float2(t2.y, -t2.x);
    float2 t3 = csub(a[3], a[7]); a[3] = cadd(a[3], a[7]);
    a[7] = INV ? make_float2(-C*(t3.x + t3.y), C*(t3.x - t3.y))
               : make_float2(C*(t3.y - t3.x), -C*(t3.x + t3.y));
  }
  #pragma unroll
  for (int g = 0; g < 2; ++g) {
    int b = g*4;
    float2 t0 = csub(a[b], a[b+2]); a[b] = cadd(a[b], a[b+2]); a[b+2] = t0;
    float2 t1 = csub(a[b+1], a[b+3]); a[b+1] = cadd(a[b+1], a[b+3]);
    a[b+3] = INV ? make_float2(-t1.y, t1.x) : make_float2(t1.y, -t1.x);
  }
  #pragma unroll
  for (int g = 0; g < 4; ++g) {
    int b = g*2;
    float2 t = csub(a[b], a[b+1]); a[b] = cadd(a[b], a[b+1]); a[b+1] = t;
  }
}

template<bool INV>
__device__ __forceinline__ void reg_fft4(float2* a) {
  float2 t0 = csub(a[0], a[2]); a[0] = cadd(a[0], a[2]); a[2] = t0;
  float2 t1 = csub(a[1], a[3]); a[1] = cadd(a[1], a[3]);
  a[3] = INV ? make_float2(-t1.y, t1.x) : make_float2(t1.y, -t1.x);
  t0 = csub(a[0], a[1]); a[0] = cadd(a[0], a[1]); a[1] = t0;
  t1 = csub(a[2], a[3]); a[2] = cadd(a[2], a[3]); a[3] = t1;
}

__device__ __forceinline__ void wfft512_fwd(float2* v, int lane) {
  const int BR3[8] = {0,4,2,6,1,5,3,7};
  reg_fft8<false>(v);
  float ang = -6.2831853071795865f * (float)lane * (1.f/512.f);
  float sn, cs; __sincosf(ang, &sn, &cs);
  float2 w1 = make_float2(cs, sn), w = w1;
  #pragma unroll
  for (int m = 1; m < 8; ++m) {
    v[BR3[m]] = cmulf(v[BR3[m]], w);
    if (m < 7) w = cmulf(w, w1);
  }
  xf64_fwd<8>(v, lane);
}

__device__ __forceinline__ void wfft512_inv(float2* v, int lane) {
  xf64_inv<8>(v, lane);
  float ang = 6.2831853071795865f * (float)lane * (1.f/512.f);
  float sn, cs; __sincosf(ang, &sn, &cs);
  float2 w1 = make_float2(cs, sn), w = w1;
  #pragma unroll
  for (int m = 1; m < 8; ++m) {
    v[m] = cmulf(v[m], w);
    if (m < 7) w = cmulf(w, w1);
  }
  reg_fft8<true>(v);
}

__device__ __forceinline__ void wfft256_fwd(float2* v, int lane) {
  const int BR2[4] = {0,2,1,3};
  reg_fft4<false>(v);
  float ang = -6.2831853071795865f * (float)lane * (1.f/256.f);
  float sn, cs; __sincosf(ang, &sn, &cs);
  float2 w1 = make_float2(cs, sn), w = w1;
  #pragma unroll
  for (int m = 1; m < 4; ++m) {
    v[BR2[m]] = cmulf(v[BR2[m]], w);
    if (m < 3) w = cmulf(w, w1);
  }
  xf64_fwd<4>(v, lane);
}

__device__ __forceinline__ void wfft256_inv(float2* v, int lane) {
  xf64_inv<4>(v, lane);
  float ang = 6.2831853071795865f * (float)lane * (1.f/256.f);
  float sn, cs; __sincosf(ang, &sn, &cs);
  float2 w1 = make_float2(cs, sn), w = w1;
  #pragma unroll
  for (int m = 1; m < 4; ++m) {
    v[m] = cmulf(v[m], w);
    if (m < 3) w = cmulf(w, w1);
  }
  reg_fft4<true>(v);
}

// ================= LDS column-FFT cores (still used by 256-col kernels) ======

template<bool INV>
__device__ __forceinline__ float2 cjrot(float2 z){ return INV ? make_float2(-z.y, z.x) : make_float2(z.y, -z.x); }

template<int N, int STR, bool INV>
__device__ __forceinline__ void bfly4(const float2* __restrict__ in, float2* __restrict__ out,
                                      int t, int m, int off) {
  int j = t & ~(m-1);
  float2 a0 = in[t*STR + off];
  float2 a1 = in[(t + N/4)*STR + off];
  float2 a2 = in[(t + N/2)*STR + off];
  float2 a3 = in[(t + 3*(N/4))*STR + off];
  float2 e0 = cadd(a0,a2), o0 = cadd(a1,a3);
  float2 e1 = csub(a0,a2), o1 = csub(a1,a3);
  float2 c0 = cadd(e0,o0), c2 = csub(e0,o0);
  float2 r1 = cjrot<INV>(o1);
  float2 c1 = cadd(e1,r1), c3 = csub(e1,r1);
  float ang = (INV ? 6.2831853071795865f : -6.2831853071795865f) * (float)j * (1.0f/(float)N);
  float sn, cs; __sincosf(ang, &sn, &cs);
  float2 w1 = make_float2(cs, sn);
  float2 w2 = make_float2(cs*cs - sn*sn, 2.f*cs*sn);
  float2 w3 = cmulf(w2, w1);
  int base = 4*j + (t - j);
  out[base*STR + off]       = c0;
  out[(base+m)*STR + off]   = cmulf(c1, w1);
  out[(base+2*m)*STR + off] = cmulf(c2, w2);
  out[(base+3*m)*STR + off] = cmulf(c3, w3);
}

template<bool INV>
__device__ __forceinline__ void fft256_core_col(float2* __restrict__ b0, float2* __restrict__ b1,
                                                int w, int c) {
  __syncthreads();
  #pragma unroll
  for (int k=0;k<2;++k) bfly4<256,9,INV>(b0,b1,w+32*k,1,c);
  __syncthreads();
  #pragma unroll
  for (int k=0;k<2;++k) bfly4<256,9,INV>(b1,b0,w+32*k,4,c);
  __syncthreads();
  #pragma unroll
  for (int k=0;k<2;++k) bfly4<256,9,INV>(b0,b1,w+32*k,16,c);
  __syncthreads();
  #pragma unroll
  for (int k=0;k<2;++k) bfly4<256,9,INV>(b1,b0,w+32*k,64,c);
  __syncthreads();
}

// ---------------- height map ----------------
__global__ void k_height4(const float* __restrict__ zc, const float4* __restrict__ zv,
                          float4* __restrict__ hm) {
  int idx = blockIdx.x * 256 + threadIdx.x;
  float4 s = make_float4(0.f,0.f,0.f,0.f);
  #pragma unroll 8
  for (int t = 0; t < 64; ++t) {
    float c = zc[t];
    float4 v = zv[(size_t)t * (RR2/4) + idx];
    s.x += c*v.x; s.y += c*v.y; s.z += c*v.z; s.w += c*v.w;
  }
  hm[idx] = s;
}

// ---------------- aux tile ----------------
__global__ void k_aux(const float* __restrict__ mp, const float* __restrict__ cf,
                      float* __restrict__ aux8) {
  int idx = threadIdx.x;
  if (idx >= 192) return;
  int l = idx % 3, j = (idx / 3) & 7, i = idx / 24;
  int i4 = (i < 4) ? i : 7 - i;
  int j4 = (j < 4) ? j : 7 - j;
  float s = 0.f;
  for (int f = 0; f < 4; ++f) s += cf[f*3 + l] * mp[f*16 + i4*4 + j4];
  aux8[idx] = s;
}

// ------- transfer: PERMUTED both dims (HBp[s_u][s_v] = H[f(s_u)][f(s_v)]) -----
__global__ void k_transfer(float2* __restrict__ HB) {
  int gid = blockIdx.x * 256 + threadIdx.x;   // 3 * RR2
  int band = gid >> 18, idx = gid & (RR2 - 1);
  double wl = d_wls[band];
  int su = idx >> 9, sv = idx & 511;
  int fui = (su >> 6) + 8 * (__brev(su & 63) >> 26);
  int fvi = (sv >> 6) + 8 * (__brev(sv & 63) >> 26);
  double inv_nd = 1.0 / (512.0 * 3.69e-6);
  double fu = (double)((fui < 256) ? fui : fui - 512) * inv_nd;
  double fv = (double)((fvi < 256) ? fvi : fvi - 512) * inv_nd;
  double au = wl * fu, av = wl * fv;
  double argd = 1.0 - au*au - av*av;
  float2 h0 = make_float2(0.f, 0.f), h1 = h0;
  if (argd > 0.0) {
    double kz = (6.283185307179586 / wl) * sqrt(argd);
    float s, c;
    double p0 = fmod(0.047 * kz, 6.283185307179586);
    __sincosf((float)p0, &s, &c); h0 = make_float2(c, s);
    double p1 = fmod(0.003 * kz, 6.283185307179586);
    __sincosf((float)p1, &s, &c); h1 = make_float2(c, s);
  }
  HB[(size_t)(band*2    ) * RR2 + idx] = h0;
  HB[(size_t)(band*2 + 1) * RR2 + idx] = h1;
}

// ---------------- field build + wave rows-fwd ----------------
__global__ __launch_bounds__(256) void k_r512f_field(
    const float* __restrict__ hm, float2* __restrict__ A) {
  const int BR3[8] = {0,4,2,6,1,5,3,7};
  int lane = threadIdx.x & 63;
  int wid = (blockIdx.x << 2) | (threadIdx.x >> 6);   // band*512 + r
  int band = wid >> 9, r = wid & 511;
  float K = (float)(6.283185307179586 / d_wls[band] * d_dn[band]);
  const float* hrow = hm + (size_t)r * 512;
  int dx = r - 256;
  float2 v[8];
  #pragma unroll
  for (int m = 0; m < 8; ++m) {
    int col = lane + (m << 6);
    int dy = col - 256;
    float2 f = make_float2(0.f, 0.f);
    if (dx*dx + dy*dy < 65025) {
      float ph = K * hrow[col];
      float s, c;
      sincosf(ph, &s, &c);
      f = make_float2(c, s);
    }
    v[m] = f;
  }
  wfft512_fwd(v, lane);
  float2* row = A + (size_t)wid * 512;
  #pragma unroll
  for (int m = 0; m < 8; ++m) row[lane + (m << 6)] = v[BR3[m]];
}

// ---- 512 cols: wave-FFT fwd + xH(permuted, symmetric) + inv; LDS = staging ----
__global__ __launch_bounds__(256) void k_c512_H(
    float2* __restrict__ data, const float2* __restrict__ HBp, int pshift, int hodd) {
  const int BR3[8] = {0,4,2,6,1,5,3,7};
  __shared__ float2 tile[512*9];
  int tid = threadIdx.x;
  int c = tid & 7, w = tid >> 3;
  int p = blockIdx.y;
  int band = p >> pshift;
  float2* img = data + ((size_t)p << 18) + (size_t)blockIdx.x * 8;
  #pragma unroll
  for (int r = w; r < 512; r += 32) tile[r*9 + c] = img[(size_t)r * 512 + c];
  __syncthreads();
  int lane = tid & 63;
  int wv = tid >> 6;
  const float2* Hbase = HBp + (((size_t)(band*2 + hodd)) << 18);
  #pragma unroll
  for (int q = 0; q < 2; ++q) {
    int cc = wv*2 + q;                          // wave-private column
    int sc = blockIdx.x*8 + cc;                 // stored column index
    float2 v[8];
    #pragma unroll
    for (int m = 0; m < 8; ++m) v[m] = tile[(lane + (m << 6))*9 + cc];
    wfft512_fwd(v, lane);
    const float2* Hrow = Hbase + (size_t)sc * 512;   // symmetric H: row == column
    float2 u[8];
    #pragma unroll
    for (int m = 0; m < 8; ++m) u[m] = cmulf(v[BR3[m]], Hrow[lane + (m << 6)]);
    wfft512_inv(u, lane);
    const float sc2 = 1.f/512.f;
    #pragma unroll
    for (int m = 0; m < 8; ++m) {
      float2 t = u[BR3[m]];
      tile[(lane + (m << 6))*9 + cc] = make_float2(t.x*sc2, t.y*sc2);
    }
  }
  __syncthreads();
  #pragma unroll
  for (int r = w; r < 512; r += 32) img[(size_t)r * 512 + c] = tile[r*9 + c];
}

// ------- wave rows-inv(u1) + mask expand + wave rows-fwd x4 -------
__global__ __launch_bounds__(256) void k_r512_invexpand(
    const float2* __restrict__ A, const float* __restrict__ aux8,
    float2* __restrict__ U) {
  const int BR3[8] = {0,4,2,6,1,5,3,7};
  int lane = threadIdx.x & 63;
  int wid = (blockIdx.x << 2) | (threadIdx.x >> 6);   // band*512 + r
  int band = wid >> 9, r = wid & 511;
  const float2* row = A + (size_t)wid * 512;
  float2 v[8];
  #pragma unroll
  for (int m = 0; m < 8; ++m) v[m] = row[lane + (m << 6)];
  wfft512_inv(v, lane);
  const float sc = 1.f/512.f;
  float2 u1[8];                       // natural n2 order
  #pragma unroll
  for (int n2 = 0; n2 < 8; ++n2) {
    float2 t = v[BR3[n2]];
    u1[n2] = make_float2(t.x*sc, t.y*sc);
  }
  int j8base = lane & 7;
  for (int pm = 0; pm < 4; ++pm) {
    int i8 = (r + (pm >> 1)) & 7;
    float mval = aux8[i8*24 + ((j8base + (pm & 1)) & 7) * 3 + band];
    float2 wv[8];
    #pragma unroll
    for (int n2 = 0; n2 < 8; ++n2) wv[n2] = make_float2(u1[n2].x*mval, u1[n2].y*mval);
    wfft512_fwd(wv, lane);
    float2* orow = U + (((size_t)(band*4 + pm)) << 18) + (size_t)r * 512;
    #pragma unroll
    for (int m = 0; m < 8; ++m) orow[lane + (m << 6)] = wv[BR3[m]];
  }
}

// ------- wave rows-inv (row pair) + |.|^2 + 2x2 down + partial sum --
__global__ __launch_bounds__(256) void k_r512_inv_psf(
    const float2* __restrict__ U, float* __restrict__ PSF, float* __restrict__ PSUMP) {
  const int BR3[8] = {0,4,2,6,1,5,3,7};
  int lane = threadIdx.x & 63;
  int wid = (blockIdx.x << 2) | (threadIdx.x >> 6);   // p*256 + i
  int p = wid >> 8, i = wid & 255;
  const float2* row0 = U + ((size_t)p << 18) + (size_t)(2*i) * 512;
  const float2* row1 = row0 + 512;
  float2 v0[8], v1[8];
  #pragma unroll
  for (int m = 0; m < 8; ++m) v0[m] = row0[lane + (m << 6)];
  #pragma unroll
  for (int m = 0; m < 8; ++m) v1[m] = row1[lane + (m << 6)];
  wfft512_inv(v0, lane);
  wfft512_inv(v1, lane);
  float colsum[8];
  float tot = 0.f;
  #pragma unroll
  for (int pos = 0; pos < 8; ++pos) {
    float sq = v0[pos].x*v0[pos].x + v0[pos].y*v0[pos].y
             + v1[pos].x*v1[pos].x + v1[pos].y*v1[pos].y;
    tot += sq;
    colsum[pos] = sq;
  }
  const float sc2 = 0.25f / (512.f * 512.f);
  #pragma unroll
  for (int pos = 0; pos < 8; ++pos) {
    float pairs = colsum[pos] + __shfl_xor(colsum[pos], 1);
    if (!(lane & 1)) {
      int col = (lane >> 1) + (BR3[pos] << 5);
      PSF[((size_t)p << 16) | (i << 8) | col] = sc2 * pairs;
    }
  }
  #pragma unroll
  for (int h = 1; h < 64; h <<= 1) tot += __shfl_xor(tot, h);
  if (lane == 0) PSUMP[(p << 8) | i] = tot * sc2;   // plain store, no atomic
}

// --- wave rows-fwd fused with OTF load (shift + in-wave psum reduce + norm) ---
__global__ __launch_bounds__(256) void k_r256f_otf(
    const float* __restrict__ PSF, const float* __restrict__ PSUMP,
    float2* __restrict__ OTF) {
  const int BR2[4] = {0,2,1,3};
  int lane = threadIdx.x & 63;
  int wid = (blockIdx.x << 2) | (threadIdx.x >> 6);   // p*256 + i
  int p = wid >> 8, i = wid & 255;
  const float4* pp = reinterpret_cast<const float4*>(PSUMP + (p << 8));
  float4 q = pp[lane];
  float tot = (q.x + q.y) + (q.z + q.w);
  #pragma unroll
  for (int h = 1; h < 64; h <<= 1) tot += __shfl_xor(tot, h);
  float inv = 1.0f / tot;
  int si = (i + 128) & 255;
  const float* prow = PSF + ((size_t)p << 16) + (si << 8);
  float2 v[4];
  #pragma unroll
  for (int m = 0; m < 4; ++m) {
    int col = lane + (((m + 2) & 3) << 6);   // (n+128)&255 with n = lane+64m
    v[m] = make_float2(prow[col] * inv, 0.f);
  }
  wfft256_fwd(v, lane);
  float2* row = OTF + (size_t)wid * 256;
  #pragma unroll
  for (int m = 0; m < 4; ++m) row[lane + (m << 6)] = v[BR2[m]];
}

// ------- OTF cols-fwd (4 planes of one band) fused with parity S build ------
__global__ __launch_bounds__(256) void k_c256w(
    const float2* __restrict__ OTF, float2* __restrict__ Sb) {
  __shared__ float2 b0[256*9], b1[256*9];
  int c = threadIdx.x, w = threadIdx.y;          // (8,32)
  int band = blockIdx.y;
  int col = blockIdx.x * 8 + c;
  float2 S0[8], S1[8], S2[8], S3[8];
  #pragma unroll
  for (int k = 0; k < 8; ++k) {
    S0[k] = make_float2(0.f,0.f); S1[k] = make_float2(0.f,0.f);
    S2[k] = make_float2(0.f,0.f); S3[k] = make_float2(0.f,0.f);
  }
  for (int q = 0; q < 4; ++q) {
    const float2* img = OTF + (((size_t)(band*4 + q)) << 16) + col;
    #pragma unroll
    for (int r = w; r < 256; r += 32) b0[r*9 + c] = img[(size_t)r * 256];
    fft256_core_col<false>(b0, b1, w, c);
    float sg1 = (q & 1) ? -1.f : 1.f;
    float sg2 = (q & 2) ? -1.f : 1.f;
    float sg3 = sg1 * sg2;
    #pragma unroll
    for (int k = 0; k < 8; ++k) {
      int r = w + 32*k;
      float2 z = b0[r*9 + c];
      S0[k] = cadd(S0[k], z);
      S1[k] = make_float2(S1[k].x + sg1*z.x, S1[k].y + sg1*z.y);
      S2[k] = make_float2(S2[k].x + sg2*z.x, S2[k].y + sg2*z.y);
      S3[k] = make_float2(S3[k].x + sg3*z.x, S3[k].y + sg3*z.y);
    }
    __syncthreads();
  }
  float2* S = Sb + (((size_t)(band*4)) << 16);
  #pragma unroll
  for (int k = 0; k < 8; ++k) {
    int r = w + 32*k;
    int uv = (r << 8) | col;
    S[uv] = S0[k];
    S[(1<<16) | uv] = S1[k];
    S[(2<<16) | uv] = S2[k];
    S[(3<<16) | uv] = S3[k];
  }
}

// ---------------- wave rows-fwd fused with input load ----------------
__global__ __launch_bounds__(256) void k_r256f_x(
    const float* __restrict__ in, float2* __restrict__ X) {
  const int BR2[4] = {0,2,1,3};
  int lane = threadIdx.x & 63;
  int wid = (blockIdx.x << 2) | (threadIdx.x >> 6);   // p*256 + i, p = band*8+img
  int p = wid >> 8, i = wid & 255;
  int band = p >> 3, img = p & 7;
  const float* src = in + (((size_t)img * 256 + i) * 256) * 3 + band;
  float2 v[4];
  #pragma unroll
  for (int m = 0; m < 4; ++m) v[m] = make_float2(src[(lane + (m << 6)) * 3], 0.f);
  wfft256_fwd(v, lane);
  float2* row = X + (size_t)wid * 256;
  #pragma unroll
  for (int m = 0; m < 4; ++m) row[lane + (m << 6)] = v[BR2[m]];
}

// ---------------- 256 cols fwd (X) ----------------
__global__ __launch_bounds__(256) void k_c256_fwd(float2* __restrict__ data) {
  __shared__ float2 b0[256*9], b1[256*9];
  int c = threadIdx.x, w = threadIdx.y;
  float2* img = data + ((size_t)blockIdx.y << 16) + (size_t)blockIdx.x * 8 + c;
  #pragma unroll
  for (int r = w; r < 256; r += 32) b0[r*9 + c] = img[(size_t)r * 256];
  fft256_core_col<false>(b0, b1, w, c);
  #pragma unroll
  for (int r = w; r < 256; r += 32) img[(size_t)r * 256] = b0[r*9 + c];
}

// ------- ybuild (4-term S combine; quads = lane low-2-bit perm) + cols-inv ---
__global__ __launch_bounds__(256) void k_ybuild_cinv(
    const float2* __restrict__ X, const float2* __restrict__ Sb,
    float2* __restrict__ Y) {
  __shared__ float2 Xl[256*9];
  __shared__ float2 b0[256*9], b1[256*9];
  const int CAm[4] = {3,2,0,1};
  const int CBm[4] = {2,3,1,0};
  int c = threadIdx.x, w = threadIdx.y;          // (8,32)
  int n = blockIdx.y;
  int band = n >> 3;
  int col = blockIdx.x * 8 + c;                  // stored column
  const float2* Xn = X + ((size_t)n << 16);
  #pragma unroll
  for (int r = w; r < 256; r += 32) Xl[r*9 + c] = Xn[(r << 8) | col];
  __syncthreads();
  const float2* S = Sb + (((size_t)(band*4)) << 16);
  int cA = (c & 4) | CAm[c & 3];
  int cB = (c & 4) | CBm[c & 3];
  #pragma unroll
  for (int k = 0; k < 8; ++k) {
    int u = w + 32*k;
    int ua = (u + 192) & 255, ub = (u + 64) & 255;
    float2 X00 = Xl[u*9 + c];
    float2 X01 = Xl[u*9 + cA], X03 = Xl[u*9 + cB];
    float2 X10 = Xl[ua*9 + c], X30 = Xl[ub*9 + c];
    float2 X11 = Xl[ua*9 + cA], X13 = Xl[ua*9 + cB];
    float2 X31 = Xl[ub*9 + cA], X33 = Xl[ub*9 + cB];
    float2 t00 = make_float2(0.25f*X00.x, 0.25f*X00.y);
    float2 t01 = make_float2(0.125f*(X01.x + X03.x - (X03.y - X01.y)),
                             0.125f*(X01.y + X03.y + (X03.x - X01.x)));
    float2 t10 = make_float2(0.125f*(X10.x + X30.x - (X30.y - X10.y)),
                             0.125f*(X10.y + X30.y + (X30.x - X10.x)));
    float2 t11 = make_float2(0.125f*(X13.x + X31.x - (X33.y - X11.y)),
                             0.125f*(X13.y + X31.y + (X33.x - X11.x)));
    int uv = (u << 8) | col;
    float2 acc = cmulf(S[uv], t00);
    acc = cadd(acc, cmulf(S[(1<<16) | uv], t01));
    acc = cadd(acc, cmulf(S[(2<<16) | uv], t10));
    acc = cadd(acc, cmulf(S[(3<<16) | uv], t11));
    b0[u*9 + c] = acc;
  }
  fft256_core_col<true>(b0, b1, w, c);
  const float sc = 1.f/256.f;
  float2* Yp = Y + ((size_t)n << 16) + col;
  #pragma unroll
  for (int r = w; r < 256; r += 32) {
    float2 v = b0[r*9 + c];
    Yp[(size_t)r * 256] = make_float2(v.x*sc, v.y*sc);
  }
}

// ---------------- wave rows-inv over 3 bands + color accumulate ----------------
__global__ __launch_bounds__(256) void k_r256_inv_accum3(
    const float2* __restrict__ Y, float* __restrict__ out,
    const float* __restrict__ cf) {
  const int BR2[4] = {0,2,1,3};
  int lane = threadIdx.x & 63;
  int wid = (blockIdx.x << 2) | (threadIdx.x >> 6);   // img*256 + i
  int img = wid >> 8, i = wid & 255;
  float accR[4] = {0.f,0.f,0.f,0.f};
  float accG[4] = {0.f,0.f,0.f,0.f};
  float accB[4] = {0.f,0.f,0.f,0.f};
  const float sc = 1.f/256.f;
  for (int band = 0; band < 3; ++band) {
    const float2* row = Y + (((size_t)(band*8 + img)) << 16) + ((size_t)i << 8);
    float2 v[4];
    #pragma unroll
    for (int m = 0; m < 4; ++m) v[m] = row[lane + (m << 6)];
    wfft256_inv(v, lane);
    float c0 = cf[band], c1 = cf[3 + band], c2 = cf[9 + band];
    #pragma unroll
    for (int pos = 0; pos < 4; ++pos) {
      float re = v[pos].x * sc;
      int n2 = BR2[pos];
      accR[n2] += c0*re; accG[n2] += c1*re; accB[n2] += c2*re;
    }
  }
  #pragma unroll
  for (int n2 = 0; n2 < 4; ++n2) {
    int col = lane + (n2 << 6);
    float* o = out + (((size_t)img * 256 + i) * 256 + col) * 3;
    o[0] = accR[n2]; o[1] = accG[n2]; o[2] = accB[n2];
  }
}

// ================= host-side dispatch =================

extern "C" void kernel_launch(void* const* d_in, const int* in_sizes, int n_in,
                              void* d_out, int out_size, void* d_ws, size_t ws_size,
                              hipStream_t stream) {
  const float* inp = (const float*)d_in[0];
  const float* zc  = (const float*)d_in[1];
  const float* zv  = (const float*)d_in[2];
  const float* mp  = (const float*)d_in[3];
  const float* cf  = (const float*)d_in[4];
  float* out = (float*)d_out;

  char* ws = (char*)d_ws;
  size_t off = 0;
  auto alloc = [&](size_t bytes) -> void* {
    void* p = ws + off;
    off = (off + bytes + 255) & ~(size_t)255;
    return p;
  };
  float*  hm    = (float*) alloc((size_t)RR2 * 4);
  float*  aux8  = (float*) alloc(256 * 4);
  float*  PSUMP = (float*) alloc((size_t)12 * 256 * 4);
  float2* A     = (float2*)alloc((size_t)3 * RR2 * 8);
  float2* HB    = (float2*)alloc((size_t)6 * RR2 * 8);
  float2* U     = (float2*)alloc((size_t)12 * RR2 * 8);
  float*  PSF   = (float*) alloc((size_t)12 * PP2 * 4);
  float2* OTF   = (float2*)alloc((size_t)12 * PP2 * 8);
  float2* Sb    = (float2*)alloc((size_t)12 * PP2 * 8);
  float2* X     = (float2*)alloc((size_t)24 * PP2 * 8);
  float2* Y     = (float2*)alloc((size_t)24 * PP2 * 8);

  // ---- setup ----
  k_height4<<<RR2/4/256, 256, 0, stream>>>(zc, (const float4*)zv, (float4*)hm);
  k_aux<<<1, 256, 0, stream>>>(mp, cf, aux8);
  k_transfer<<<3*RR2/256, 256, 0, stream>>>(HB);

  // ---- u1: wave rows-fwd -> (wave cols-fwd + xH + cols-inv) ----
  k_r512f_field<<<3*512/4, 256, 0, stream>>>(hm, A);
  k_c512_H<<<dim3(64, 3), 256, 0, stream>>>(A, HB, 0, 0);

  // ---- wave rows-inv(u1) + expand + rows-fwd -> U (12 planes) ----
  k_r512_invexpand<<<3*512/4, 256, 0, stream>>>(A, aux8, U);
  k_c512_H<<<dim3(64, 12), 256, 0, stream>>>(U, HB, 2, 1);
  k_r512_inv_psf<<<12*256/4, 256, 0, stream>>>(U, PSF, PSUMP);

  // ---- OTFs + parity S build ----
  k_r256f_otf<<<12*256/4, 256, 0, stream>>>(PSF, PSUMP, OTF);
  k_c256w<<<dim3(32, 3), dim3(8, 32), 0, stream>>>(OTF, Sb);

  // ---- convolution ----
  k_r256f_x<<<24*256/4, 256, 0, stream>>>(inp, X);
  k_c256_fwd<<<dim3(32, 24), dim3(8, 32), 0, stream>>>(X);
  k_ybuild_cinv<<<dim3(32, 24), dim3(8, 32), 0, stream>>>(X, Sb, Y);
  k_r256_inv_accum3<<<8*256/4, 256, 0, stream>>>(Y, out, cf);
}

// Round 8
// 171.689 us; speedup vs baseline: 1.3421x; 1.0446x over previous
//
#include <hip/hip_runtime.h>
#include <math.h>

#define RR 512
#define RR2 (RR*RR)
#define PP 256
#define PP2 (PP*PP)

__constant__ double d_wls[3] = {4.6e-7, 5.4e-7, 6.2e-7};
__constant__ double d_dn[3]  = {0.52, 0.515, 0.51};

__device__ __forceinline__ float2 cadd(float2 a, float2 b){ return make_float2(a.x+b.x, a.y+b.y); }
__device__ __forceinline__ float2 csub(float2 a, float2 b){ return make_float2(a.x-b.x, a.y-b.y); }
__device__ __forceinline__ float2 cmulf(float2 a, float2 b){ return make_float2(a.x*b.x-a.y*b.y, a.x*b.y+a.y*b.x); }

// ======================================================================
// Wave-level FFT: N = 64 lanes x R regs, element n = lane + 64*reg.
// fwd: reg-DFT (R-pt) -> twiddle W_N^{lane*m} -> cross-lane 64 DIF (shfl).
//      storage: out[lane + 64*m] = v[brR(m)]  ->  f(s) = (s>>6) + R_hi*bitrev6(s&63)
// inv: exact mirror; output pos p = x[lane + 64*brR(p)] (unscaled).
// ======================================================================

template<int R>
__device__ __forceinline__ void xf64_fwd(float2* v, int lane) {
  #pragma unroll
  for (int h = 32; h >= 1; h >>= 1) {
    float ang = -6.2831853071795865f * (float)(lane & (h-1)) / (float)(2*h);
    float sn, cs;
    __sincosf(ang, &sn, &cs);
    bool odd = (lane & h) != 0;
    float wc = odd ? cs : 1.f;
    float ws = odd ? sn : 0.f;
    #pragma unroll
    for (int r = 0; r < R; ++r) {
      float2 t;
      t.x = __shfl_xor(v[r].x, h);
      t.y = __shfl_xor(v[r].y, h);
      float2 d = odd ? csub(t, v[r]) : cadd(v[r], t);
      v[r] = make_float2(d.x*wc - d.y*ws, d.x*ws + d.y*wc);
    }
  }
}

template<int R>
__device__ __forceinline__ void xf64_inv(float2* v, int lane) {
  #pragma unroll
  for (int h = 1; h <= 32; h <<= 1) {
    float ang = 6.2831853071795865f * (float)(lane & (h-1)) / (float)(2*h);
    float sn, cs;
    __sincosf(ang, &sn, &cs);
    bool odd = (lane & h) != 0;
    #pragma unroll
    for (int r = 0; r < R; ++r) {
      float2 t;
      t.x = __shfl_xor(v[r].x, h);
      t.y = __shfl_xor(v[r].y, h);
      float2 s = odd ? v[r] : t;
      float2 ws = make_float2(s.x*cs - s.y*sn, s.x*sn + s.y*cs);
      v[r] = odd ? csub(t, ws) : cadd(v[r], ws);
    }
  }
}

template<bool INV>
__device__ __forceinline__ void reg_fft8(float2* a) {
  const float C = 0.70710678118654752f;
  {
    float2 t0 = csub(a[0], a[4]); a[0] = cadd(a[0], a[4]); a[4] = t0;
    float2 t1 = csub(a[1], a[5]); a[1] = cadd(a[1], a[5]);
    a[5] = INV ? make_float2(C*(t1.x - t1.y), C*(t1.x + t1.y))
               : make_float2(C*(t1.x + t1.y), C*(t1.y - t1.x));
    float2 t2 = csub(a[2], a[6]); a[2] = cadd(a[2], a[6]);
    a[6] = INV ? make_float2(-t2.y, t2.x) : make_float2(t2.y, -t2.x);
    float2 t3 = csub(a[3], a[7]); a[3] = cadd(a[3], a[7]);
    a[7] = INV ? make_float2(-C*(t3.x + t3.y), C*(t3.x - t3.y))
               : make_float2(C*(t3.y - t3.x), -C*(t3.x + t3.y));
  }
  #pragma unroll
  for (int g = 0; g < 2; ++g) {
    int b = g*4;
    float2 t0 = csub(a[b], a[b+2]); a[b] = cadd(a[b], a[b+2]); a[b+2] = t0;
    float2 t1 = csub(a[b+1], a[b+3]); a[b+1] = cadd(a[b+1], a[b+3]);
    a[b+3] = INV ? make_float2(-t1.y, t1.x) : make_float2(t1.y, -t1.x);
  }
  #pragma unroll
  for (int g = 0; g < 4; ++g) {
    int b = g*2;
    float2 t = csub(a[b], a[b+1]); a[b] = cadd(a[b], a[b+1]); a[b+1] = t;
  }
}

template<bool INV>
__device__ __forceinline__ void reg_fft4(float2* a) {
  float2 t0 = csub(a[0], a[2]); a[0] = cadd(a[0], a[2]); a[2] = t0;
  float2 t1 = csub(a[1], a[3]); a[1] = cadd(a[1], a[3]);
  a[3] = INV ? make_float2(-t1.y, t1.x) : make_float2(t1.y, -t1.x);
  t0 = csub(a[0], a[1]); a[0] = cadd(a[0], a[1]); a[1] = t0;
  t1 = csub(a[2], a[3]); a[2] = cadd(a[2], a[3]); a[3] = t1;
}

__device__ __forceinline__ void wfft512_fwd(float2* v, int lane) {
  const int BR3[8] = {0,4,2,6,1,5,3,7};
  reg_fft8<false>(v);
  float ang = -6.2831853071795865f * (float)lane * (1.f/512.f);
  float sn, cs; __sincosf(ang, &sn, &cs);
  float2 w1 = make_float2(cs, sn), w = w1;
  #pragma unroll
  for (int m = 1; m < 8; ++m) {
    v[BR3[m]] = cmulf(v[BR3[m]], w);
    if (m < 7) w = cmulf(w, w1);
  }
  xf64_fwd<8>(v, lane);
}

__device__ __forceinline__ void wfft512_inv(float2* v, int lane) {
  xf64_inv<8>(v, lane);
  float ang = 6.2831853071795865f * (float)lane * (1.f/512.f);
  float sn, cs; __sincosf(ang, &sn, &cs);
  float2 w1 = make_float2(cs, sn), w = w1;
  #pragma unroll
  for (int m = 1; m < 8; ++m) {
    v[m] = cmulf(v[m], w);
    if (m < 7) w = cmulf(w, w1);
  }
  reg_fft8<true>(v);
}

__device__ __forceinline__ void wfft256_fwd(float2* v, int lane) {
  const int BR2[4] = {0,2,1,3};
  reg_fft4<false>(v);
  float ang = -6.2831853071795865f * (float)lane * (1.f/256.f);
  float sn, cs; __sincosf(ang, &sn, &cs);
  float2 w1 = make_float2(cs, sn), w = w1;
  #pragma unroll
  for (int m = 1; m < 4; ++m) {
    v[BR2[m]] = cmulf(v[BR2[m]], w);
    if (m < 3) w = cmulf(w, w1);
  }
  xf64_fwd<4>(v, lane);
}

__device__ __forceinline__ void wfft256_inv(float2* v, int lane) {
  xf64_inv<4>(v, lane);
  float ang = 6.2831853071795865f * (float)lane * (1.f/256.f);
  float sn, cs; __sincosf(ang, &sn, &cs);
  float2 w1 = make_float2(cs, sn), w = w1;
  #pragma unroll
  for (int m = 1; m < 4; ++m) {
    v[m] = cmulf(v[m], w);
    if (m < 3) w = cmulf(w, w1);
  }
  reg_fft4<true>(v);
}

// ---------------- height map ----------------
__global__ void k_height4(const float* __restrict__ zc, const float4* __restrict__ zv,
                          float4* __restrict__ hm) {
  int idx = blockIdx.x * 256 + threadIdx.x;
  float4 s = make_float4(0.f,0.f,0.f,0.f);
  #pragma unroll 8
  for (int t = 0; t < 64; ++t) {
    float c = zc[t];
    float4 v = zv[(size_t)t * (RR2/4) + idx];
    s.x += c*v.x; s.y += c*v.y; s.z += c*v.z; s.w += c*v.w;
  }
  hm[idx] = s;
}

// ---------------- aux tile ----------------
__global__ void k_aux(const float* __restrict__ mp, const float* __restrict__ cf,
                      float* __restrict__ aux8) {
  int idx = threadIdx.x;
  if (idx >= 192) return;
  int l = idx % 3, j = (idx / 3) & 7, i = idx / 24;
  int i4 = (i < 4) ? i : 7 - i;
  int j4 = (j < 4) ? j : 7 - j;
  float s = 0.f;
  for (int f = 0; f < 4; ++f) s += cf[f*3 + l] * mp[f*16 + i4*4 + j4];
  aux8[idx] = s;
}

// ------- transfer: PERMUTED both dims (HBp[s_u][s_v] = H[f(s_u)][f(s_v)]) -----
__global__ void k_transfer(float2* __restrict__ HB) {
  int gid = blockIdx.x * 256 + threadIdx.x;   // 3 * RR2
  int band = gid >> 18, idx = gid & (RR2 - 1);
  double wl = d_wls[band];
  int su = idx >> 9, sv = idx & 511;
  int fui = (su >> 6) + 8 * (__brev(su & 63) >> 26);
  int fvi = (sv >> 6) + 8 * (__brev(sv & 63) >> 26);
  double inv_nd = 1.0 / (512.0 * 3.69e-6);
  double fu = (double)((fui < 256) ? fui : fui - 512) * inv_nd;
  double fv = (double)((fvi < 256) ? fvi : fvi - 512) * inv_nd;
  double au = wl * fu, av = wl * fv;
  double argd = 1.0 - au*au - av*av;
  float2 h0 = make_float2(0.f, 0.f), h1 = h0;
  if (argd > 0.0) {
    double kz = (6.283185307179586 / wl) * sqrt(argd);
    float s, c;
    double p0 = fmod(0.047 * kz, 6.283185307179586);
    __sincosf((float)p0, &s, &c); h0 = make_float2(c, s);
    double p1 = fmod(0.003 * kz, 6.283185307179586);
    __sincosf((float)p1, &s, &c); h1 = make_float2(c, s);
  }
  HB[(size_t)(band*2    ) * RR2 + idx] = h0;
  HB[(size_t)(band*2 + 1) * RR2 + idx] = h1;
}

// ---------------- field build + wave rows-fwd ----------------
__global__ __launch_bounds__(256) void k_r512f_field(
    const float* __restrict__ hm, float2* __restrict__ A) {
  const int BR3[8] = {0,4,2,6,1,5,3,7};
  int lane = threadIdx.x & 63;
  int wid = (blockIdx.x << 2) | (threadIdx.x >> 6);   // band*512 + r
  int band = wid >> 9, r = wid & 511;
  float K = (float)(6.283185307179586 / d_wls[band] * d_dn[band]);
  const float* hrow = hm + (size_t)r * 512;
  int dx = r - 256;
  float2 v[8];
  #pragma unroll
  for (int m = 0; m < 8; ++m) {
    int col = lane + (m << 6);
    int dy = col - 256;
    float2 f = make_float2(0.f, 0.f);
    if (dx*dx + dy*dy < 65025) {
      float ph = K * hrow[col];
      float s, c;
      sincosf(ph, &s, &c);
      f = make_float2(c, s);
    }
    v[m] = f;
  }
  wfft512_fwd(v, lane);
  float2* row = A + (size_t)wid * 512;
  #pragma unroll
  for (int m = 0; m < 8; ++m) row[lane + (m << 6)] = v[BR3[m]];
}

// ---- 512 cols: wave-FFT fwd + xH(permuted, symmetric) + inv; LDS = staging ----
__global__ __launch_bounds__(256) void k_c512_H(
    float2* __restrict__ data, const float2* __restrict__ HBp, int pshift, int hodd) {
  const int BR3[8] = {0,4,2,6,1,5,3,7};
  __shared__ float2 tile[512*9];
  int tid = threadIdx.x;
  int c = tid & 7, w = tid >> 3;
  int p = blockIdx.y;
  int band = p >> pshift;
  float2* img = data + ((size_t)p << 18) + (size_t)blockIdx.x * 8;
  #pragma unroll
  for (int r = w; r < 512; r += 32) tile[r*9 + c] = img[(size_t)r * 512 + c];
  __syncthreads();
  int lane = tid & 63;
  int wv = tid >> 6;
  const float2* Hbase = HBp + (((size_t)(band*2 + hodd)) << 18);
  #pragma unroll
  for (int q = 0; q < 2; ++q) {
    int cc = wv*2 + q;                          // wave-private column
    int sc = blockIdx.x*8 + cc;                 // stored column index
    float2 v[8];
    #pragma unroll
    for (int m = 0; m < 8; ++m) v[m] = tile[(lane + (m << 6))*9 + cc];
    wfft512_fwd(v, lane);
    const float2* Hrow = Hbase + (size_t)sc * 512;   // symmetric H: row == column
    float2 u[8];
    #pragma unroll
    for (int m = 0; m < 8; ++m) u[m] = cmulf(v[BR3[m]], Hrow[lane + (m << 6)]);
    wfft512_inv(u, lane);
    const float sc2 = 1.f/512.f;
    #pragma unroll
    for (int m = 0; m < 8; ++m) {
      float2 t = u[BR3[m]];
      tile[(lane + (m << 6))*9 + cc] = make_float2(t.x*sc2, t.y*sc2);
    }
  }
  __syncthreads();
  #pragma unroll
  for (int r = w; r < 512; r += 32) img[(size_t)r * 512 + c] = tile[r*9 + c];
}

// ------- wave rows-inv(u1) + mask expand + wave rows-fwd x4 -------
__global__ __launch_bounds__(256) void k_r512_invexpand(
    const float2* __restrict__ A, const float* __restrict__ aux8,
    float2* __restrict__ U) {
  const int BR3[8] = {0,4,2,6,1,5,3,7};
  int lane = threadIdx.x & 63;
  int wid = (blockIdx.x << 2) | (threadIdx.x >> 6);   // band*512 + r
  int band = wid >> 9, r = wid & 511;
  const float2* row = A + (size_t)wid * 512;
  float2 v[8];
  #pragma unroll
  for (int m = 0; m < 8; ++m) v[m] = row[lane + (m << 6)];
  wfft512_inv(v, lane);
  const float sc = 1.f/512.f;
  float2 u1[8];                       // natural n2 order
  #pragma unroll
  for (int n2 = 0; n2 < 8; ++n2) {
    float2 t = v[BR3[n2]];
    u1[n2] = make_float2(t.x*sc, t.y*sc);
  }
  int j8base = lane & 7;
  for (int pm = 0; pm < 4; ++pm) {
    int i8 = (r + (pm >> 1)) & 7;
    float mval = aux8[i8*24 + ((j8base + (pm & 1)) & 7) * 3 + band];
    float2 wv[8];
    #pragma unroll
    for (int n2 = 0; n2 < 8; ++n2) wv[n2] = make_float2(u1[n2].x*mval, u1[n2].y*mval);
    wfft512_fwd(wv, lane);
    float2* orow = U + (((size_t)(band*4 + pm)) << 18) + (size_t)r * 512;
    #pragma unroll
    for (int m = 0; m < 8; ++m) orow[lane + (m << 6)] = wv[BR3[m]];
  }
}

// ------- wave rows-inv (row pair) + |.|^2 + 2x2 down + partial sum --
__global__ __launch_bounds__(256) void k_r512_inv_psf(
    const float2* __restrict__ U, float* __restrict__ PSF, float* __restrict__ PSUMP) {
  const int BR3[8] = {0,4,2,6,1,5,3,7};
  int lane = threadIdx.x & 63;
  int wid = (blockIdx.x << 2) | (threadIdx.x >> 6);   // p*256 + i
  int p = wid >> 8, i = wid & 255;
  const float2* row0 = U + ((size_t)p << 18) + (size_t)(2*i) * 512;
  const float2* row1 = row0 + 512;
  float2 v0[8], v1[8];
  #pragma unroll
  for (int m = 0; m < 8; ++m) v0[m] = row0[lane + (m << 6)];
  #pragma unroll
  for (int m = 0; m < 8; ++m) v1[m] = row1[lane + (m << 6)];
  wfft512_inv(v0, lane);
  wfft512_inv(v1, lane);
  float colsum[8];
  float tot = 0.f;
  #pragma unroll
  for (int pos = 0; pos < 8; ++pos) {
    float sq = v0[pos].x*v0[pos].x + v0[pos].y*v0[pos].y
             + v1[pos].x*v1[pos].x + v1[pos].y*v1[pos].y;
    tot += sq;
    colsum[pos] = sq;
  }
  const float sc2 = 0.25f / (512.f * 512.f);
  #pragma unroll
  for (int pos = 0; pos < 8; ++pos) {
    float pairs = colsum[pos] + __shfl_xor(colsum[pos], 1);
    if (!(lane & 1)) {
      int col = (lane >> 1) + (BR3[pos] << 5);
      PSF[((size_t)p << 16) | (i << 8) | col] = sc2 * pairs;
    }
  }
  #pragma unroll
  for (int h = 1; h < 64; h <<= 1) tot += __shfl_xor(tot, h);
  if (lane == 0) PSUMP[(p << 8) | i] = tot * sc2;   // plain store, no atomic
}

// --- wave rows-fwd fused with OTF load (shift + in-wave psum reduce + norm) ---
__global__ __launch_bounds__(256) void k_r256f_otf(
    const float* __restrict__ PSF, const float* __restrict__ PSUMP,
    float2* __restrict__ OTF) {
  const int BR2[4] = {0,2,1,3};
  int lane = threadIdx.x & 63;
  int wid = (blockIdx.x << 2) | (threadIdx.x >> 6);   // p*256 + i
  int p = wid >> 8, i = wid & 255;
  const float4* pp = reinterpret_cast<const float4*>(PSUMP + (p << 8));
  float4 q = pp[lane];
  float tot = (q.x + q.y) + (q.z + q.w);
  #pragma unroll
  for (int h = 1; h < 64; h <<= 1) tot += __shfl_xor(tot, h);
  float inv = 1.0f / tot;
  int si = (i + 128) & 255;
  const float* prow = PSF + ((size_t)p << 16) + (si << 8);
  float2 v[4];
  #pragma unroll
  for (int m = 0; m < 4; ++m) {
    int col = lane + (((m + 2) & 3) << 6);   // (n+128)&255 with n = lane+64m
    v[m] = make_float2(prow[col] * inv, 0.f);
  }
  wfft256_fwd(v, lane);
  float2* row = OTF + (size_t)wid * 256;
  #pragma unroll
  for (int m = 0; m < 4; ++m) row[lane + (m << 6)] = v[BR2[m]];
}

// ------- OTF cols-fwd (wave FFT, 1 col/wave) + parity S build in registers ----
__global__ __launch_bounds__(256) void k_c256w(
    const float2* __restrict__ OTF, float2* __restrict__ Sb) {
  const int BR2[4] = {0,2,1,3};
  __shared__ float2 tile[256*5];
  int tid = threadIdx.x;
  int c = tid & 3, w = tid >> 2;                 // load mapping (rows step 64)
  int lane = tid & 63, wv = tid >> 6;            // wave's column = wv
  int band = blockIdx.y;
  int col = blockIdx.x * 4 + c;                  // load column
  float2 S0[4], S1[4], S2[4], S3[4];
  #pragma unroll
  for (int m = 0; m < 4; ++m) {
    S0[m] = make_float2(0.f,0.f); S1[m] = make_float2(0.f,0.f);
    S2[m] = make_float2(0.f,0.f); S3[m] = make_float2(0.f,0.f);
  }
  for (int q = 0; q < 4; ++q) {
    __syncthreads();
    const float2* img = OTF + (((size_t)(band*4 + q)) << 16) + col;
    #pragma unroll
    for (int r = w; r < 256; r += 64) tile[r*5 + c] = img[(size_t)r * 256];
    __syncthreads();
    float2 v[4];
    #pragma unroll
    for (int m = 0; m < 4; ++m) v[m] = tile[(lane + (m << 6))*5 + wv];
    wfft256_fwd(v, lane);
    float sg1 = (q & 1) ? -1.f : 1.f;
    float sg2 = (q & 2) ? -1.f : 1.f;
    float sg3 = sg1 * sg2;
    #pragma unroll
    for (int m = 0; m < 4; ++m) {
      float2 z = v[BR2[m]];                      // value at stored row lane+64m
      S0[m] = cadd(S0[m], z);
      S1[m] = make_float2(S1[m].x + sg1*z.x, S1[m].y + sg1*z.y);
      S2[m] = make_float2(S2[m].x + sg2*z.x, S2[m].y + sg2*z.y);
      S3[m] = make_float2(S3[m].x + sg3*z.x, S3[m].y + sg3*z.y);
    }
  }
  float2* S = Sb + (((size_t)(band*4)) << 16);
  #define WRITE_S(idx, arr)                                               \
  {                                                                       \
    __syncthreads();                                                      \
    _Pragma("unroll")                                                     \
    for (int m = 0; m < 4; ++m) tile[(lane + (m << 6))*5 + wv] = arr[m];  \
    __syncthreads();                                                      \
    _Pragma("unroll")                                                     \
    for (int r = w; r < 256; r += 64)                                     \
      S[((size_t)(idx) << 16) + (r << 8) + col] = tile[r*5 + c];          \
  }
  WRITE_S(0, S0)
  WRITE_S(1, S1)
  WRITE_S(2, S2)
  WRITE_S(3, S3)
  #undef WRITE_S
}

// ---------------- wave rows-fwd fused with input load ----------------
__global__ __launch_bounds__(256) void k_r256f_x(
    const float* __restrict__ in, float2* __restrict__ X) {
  const int BR2[4] = {0,2,1,3};
  int lane = threadIdx.x & 63;
  int wid = (blockIdx.x << 2) | (threadIdx.x >> 6);   // p*256 + i, p = band*8+img
  int p = wid >> 8, i = wid & 255;
  int band = p >> 3, img = p & 7;
  const float* src = in + (((size_t)img * 256 + i) * 256) * 3 + band;
  float2 v[4];
  #pragma unroll
  for (int m = 0; m < 4; ++m) v[m] = make_float2(src[(lane + (m << 6)) * 3], 0.f);
  wfft256_fwd(v, lane);
  float2* row = X + (size_t)wid * 256;
  #pragma unroll
  for (int m = 0; m < 4; ++m) row[lane + (m << 6)] = v[BR2[m]];
}

// --- fused: X cols-fwd (wave) + 9-tap combine (permuted taps) + cols-inv ------
__global__ __launch_bounds__(256) void k_xyc(
    const float2* __restrict__ X, const float2* __restrict__ Sb,
    float2* __restrict__ Y) {
  const int BR2[4] = {0,2,1,3};
  const int CAm[4] = {3,2,0,1};   // freq -64 low-2-bit map
  const int CBm[4] = {2,3,1,0};   // freq +64 low-2-bit map
  __shared__ float2 Xl[256*9];
  int tid = threadIdx.x;
  int c = tid & 7, w = tid >> 3;
  int lane = tid & 63, wv = tid >> 6;
  int n = blockIdx.y;
  int band = n >> 3;
  int col0 = blockIdx.x * 8;
  const float2* Xn = X + ((size_t)n << 16);
  #pragma unroll
  for (int r = w; r < 256; r += 32) Xl[r*9 + c] = Xn[(r << 8) | (col0 + c)];
  __syncthreads();
  // wave cols-fwd on 2 private columns, store spectrum back (stored rows)
  #pragma unroll
  for (int q = 0; q < 2; ++q) {
    int cc = wv*2 + q;
    float2 v[4];
    #pragma unroll
    for (int m = 0; m < 4; ++m) v[m] = Xl[(lane + (m << 6))*9 + cc];
    wfft256_fwd(v, lane);
    #pragma unroll
    for (int m = 0; m < 4; ++m) Xl[(lane + (m << 6))*9 + cc] = v[BR2[m]];
  }
  __syncthreads();
  const float2* S = Sb + (((size_t)(band*4)) << 16);
  float2 pa0[4], pa1[4];
  #define COMBINE(pa, qq)                                                       \
  {                                                                             \
    int cc = wv*2 + (qq);                                                       \
    int cA = (cc & 4) | CAm[cc & 3];                                            \
    int cB = (cc & 4) | CBm[cc & 3];                                            \
    int scol = col0 + cc;                                                       \
    _Pragma("unroll")                                                           \
    for (int m = 0; m < 4; ++m) {                                               \
      int u  = lane + (m << 6);                                                 \
      int ua = (u & ~3) | CAm[u & 3];                                           \
      int ub = (u & ~3) | CBm[u & 3];                                           \
      float2 X00 = Xl[u*9 + cc];                                                \
      float2 X01 = Xl[u*9 + cA],  X03 = Xl[u*9 + cB];                           \
      float2 X10 = Xl[ua*9 + cc], X30 = Xl[ub*9 + cc];                          \
      float2 X11 = Xl[ua*9 + cA], X13 = Xl[ua*9 + cB];                          \
      float2 X31 = Xl[ub*9 + cA], X33 = Xl[ub*9 + cB];                          \
      float2 t00 = make_float2(0.25f*X00.x, 0.25f*X00.y);                       \
      float2 t01 = make_float2(0.125f*(X01.x + X03.x - (X03.y - X01.y)),        \
                               0.125f*(X01.y + X03.y + (X03.x - X01.x)));       \
      float2 t10 = make_float2(0.125f*(X10.x + X30.x - (X30.y - X10.y)),        \
                               0.125f*(X10.y + X30.y + (X30.x - X10.x)));       \
      float2 t11 = make_float2(0.125f*(X13.x + X31.x - (X33.y - X11.y)),        \
                               0.125f*(X13.y + X31.y + (X33.x - X11.x)));       \
      int uv = (u << 8) | scol;                                                 \
      float2 acc = cmulf(S[uv], t00);                                           \
      acc = cadd(acc, cmulf(S[(1<<16) | uv], t01));                             \
      acc = cadd(acc, cmulf(S[(2<<16) | uv], t10));                             \
      acc = cadd(acc, cmulf(S[(3<<16) | uv], t11));                             \
      pa[m] = acc;                                                              \
    }                                                                           \
  }
  COMBINE(pa0, 0)
  COMBINE(pa1, 1)
  #undef COMBINE
  __syncthreads();     // all taps consumed before overwrite
  const float sc = 1.f/256.f;
  wfft256_inv(pa0, lane);
  wfft256_inv(pa1, lane);
  #pragma unroll
  for (int pos = 0; pos < 4; ++pos) {
    int rown = lane + (BR2[pos] << 6);           // natural row
    float2 a = pa0[pos], b = pa1[pos];
    Xl[rown*9 + wv*2]     = make_float2(a.x*sc, a.y*sc);
    Xl[rown*9 + wv*2 + 1] = make_float2(b.x*sc, b.y*sc);
  }
  __syncthreads();
  float2* Yn = Y + ((size_t)n << 16);
  #pragma unroll
  for (int r = w; r < 256; r += 32) Yn[(r << 8) | (col0 + c)] = Xl[r*9 + c];
}

// ---------------- wave rows-inv over 3 bands + color accumulate ----------------
__global__ __launch_bounds__(256) void k_r256_inv_accum3(
    const float2* __restrict__ Y, float* __restrict__ out,
    const float* __restrict__ cf) {
  const int BR2[4] = {0,2,1,3};
  int lane = threadIdx.x & 63;
  int wid = (blockIdx.x << 2) | (threadIdx.x >> 6);   // img*256 + i
  int img = wid >> 8, i = wid & 255;
  float accR[4] = {0.f,0.f,0.f,0.f};
  float accG[4] = {0.f,0.f,0.f,0.f};
  float accB[4] = {0.f,0.f,0.f,0.f};
  const float sc = 1.f/256.f;
  for (int band = 0; band < 3; ++band) {
    const float2* row = Y + (((size_t)(band*8 + img)) << 16) + ((size_t)i << 8);
    float2 v[4];
    #pragma unroll
    for (int m = 0; m < 4; ++m) v[m] = row[lane + (m << 6)];
    wfft256_inv(v, lane);
    float c0 = cf[band], c1 = cf[3 + band], c2 = cf[9 + band];
    #pragma unroll
    for (int pos = 0; pos < 4; ++pos) {
      float re = v[pos].x * sc;
      int n2 = BR2[pos];
      accR[n2] += c0*re; accG[n2] += c1*re; accB[n2] += c2*re;
    }
  }
  #pragma unroll
  for (int n2 = 0; n2 < 4; ++n2) {
    int col = lane + (n2 << 6);
    float* o = out + (((size_t)img * 256 + i) * 256 + col) * 3;
    o[0] = accR[n2]; o[1] = accG[n2]; o[2] = accB[n2];
  }
}

// ================= host-side dispatch =================

extern "C" void kernel_launch(void* const* d_in, const int* in_sizes, int n_in,
                              void* d_out, int out_size, void* d_ws, size_t ws_size,
                              hipStream_t stream) {
  const float* inp = (const float*)d_in[0];
  const float* zc  = (const float*)d_in[1];
  const float* zv  = (const float*)d_in[2];
  const float* mp  = (const float*)d_in[3];
  const float* cf  = (const float*)d_in[4];
  float* out = (float*)d_out;

  char* ws = (char*)d_ws;
  size_t off = 0;
  auto alloc = [&](size_t bytes) -> void* {
    void* p = ws + off;
    off = (off + bytes + 255) & ~(size_t)255;
    return p;
  };
  float*  hm    = (float*) alloc((size_t)RR2 * 4);
  float*  aux8  = (float*) alloc(256 * 4);
  float*  PSUMP = (float*) alloc((size_t)12 * 256 * 4);
  float2* A     = (float2*)alloc((size_t)3 * RR2 * 8);
  float2* HB    = (float2*)alloc((size_t)6 * RR2 * 8);
  float2* U     = (float2*)alloc((size_t)12 * RR2 * 8);
  float*  PSF   = (float*) alloc((size_t)12 * PP2 * 4);
  float2* OTF   = (float2*)alloc((size_t)12 * PP2 * 8);
  float2* Sb    = (float2*)alloc((size_t)12 * PP2 * 8);
  float2* X     = (float2*)alloc((size_t)24 * PP2 * 8);
  float2* Y     = (float2*)alloc((size_t)24 * PP2 * 8);

  // ---- setup ----
  k_height4<<<RR2/4/256, 256, 0, stream>>>(zc, (const float4*)zv, (float4*)hm);
  k_aux<<<1, 256, 0, stream>>>(mp, cf, aux8);
  k_transfer<<<3*RR2/256, 256, 0, stream>>>(HB);

  // ---- u1: wave rows-fwd -> (wave cols-fwd + xH + cols-inv) ----
  k_r512f_field<<<3*512/4, 256, 0, stream>>>(hm, A);
  k_c512_H<<<dim3(64, 3), 256, 0, stream>>>(A, HB, 0, 0);

  // ---- wave rows-inv(u1) + expand + rows-fwd -> U (12 planes) ----
  k_r512_invexpand<<<3*512/4, 256, 0, stream>>>(A, aux8, U);
  k_c512_H<<<dim3(64, 12), 256, 0, stream>>>(U, HB, 2, 1);
  k_r512_inv_psf<<<12*256/4, 256, 0, stream>>>(U, PSF, PSUMP);

  // ---- OTFs + parity S build (wave cols) ----
  k_r256f_otf<<<12*256/4, 256, 0, stream>>>(PSF, PSUMP, OTF);
  k_c256w<<<dim3(64, 3), 256, 0, stream>>>(OTF, Sb);

  // ---- convolution: rows-fwd -> fused (cols-fwd + combine + cols-inv) -> rows-inv ----
  k_r256f_x<<<24*256/4, 256, 0, stream>>>(inp, X);
  k_xyc<<<dim3(32, 24), 256, 0, stream>>>(X, Sb, Y);
  k_r256_inv_accum3<<<8*256/4, 256, 0, stream>>>(Y, out, cf);
}

// Round 9
// 143.314 us; speedup vs baseline: 1.6079x; 1.1980x over previous
//
#include <hip/hip_runtime.h>
#include <math.h>

#define RR 512
#define RR2 (RR*RR)
#define PP 256
#define PP2 (PP*PP)

__constant__ double d_wls[3] = {4.6e-7, 5.4e-7, 6.2e-7};
__constant__ double d_dn[3]  = {0.52, 0.515, 0.51};

__device__ __forceinline__ float2 cadd(float2 a, float2 b){ return make_float2(a.x+b.x, a.y+b.y); }
__device__ __forceinline__ float2 csub(float2 a, float2 b){ return make_float2(a.x-b.x, a.y-b.y); }
__device__ __forceinline__ float2 cmulf(float2 a, float2 b){ return make_float2(a.x*b.x-a.y*b.y, a.x*b.y+a.y*b.x); }

// ======================================================================
// Wave-level FFT: N = 64 lanes x R regs, element n = lane + 64*reg.
// storage: out[lane + 64*m] = v[brR(m)]  ->  f(s) = (s>>6) + R_hi*bitrev6(s&63)
// ======================================================================

template<int R>
__device__ __forceinline__ void xf64_fwd(float2* v, int lane) {
  #pragma unroll
  for (int h = 32; h >= 1; h >>= 1) {
    float ang = -6.2831853071795865f * (float)(lane & (h-1)) / (float)(2*h);
    float sn, cs;
    __sincosf(ang, &sn, &cs);
    bool odd = (lane & h) != 0;
    float wc = odd ? cs : 1.f;
    float ws = odd ? sn : 0.f;
    #pragma unroll
    for (int r = 0; r < R; ++r) {
      float2 t;
      t.x = __shfl_xor(v[r].x, h);
      t.y = __shfl_xor(v[r].y, h);
      float2 d = odd ? csub(t, v[r]) : cadd(v[r], t);
      v[r] = make_float2(d.x*wc - d.y*ws, d.x*ws + d.y*wc);
    }
  }
}

template<int R>
__device__ __forceinline__ void xf64_inv(float2* v, int lane) {
  #pragma unroll
  for (int h = 1; h <= 32; h <<= 1) {
    float ang = 6.2831853071795865f * (float)(lane & (h-1)) / (float)(2*h);
    float sn, cs;
    __sincosf(ang, &sn, &cs);
    bool odd = (lane & h) != 0;
    #pragma unroll
    for (int r = 0; r < R; ++r) {
      float2 t;
      t.x = __shfl_xor(v[r].x, h);
      t.y = __shfl_xor(v[r].y, h);
      float2 s = odd ? v[r] : t;
      float2 ws = make_float2(s.x*cs - s.y*sn, s.x*sn + s.y*cs);
      v[r] = odd ? csub(t, ws) : cadd(v[r], ws);
    }
  }
}

template<bool INV>
__device__ __forceinline__ void reg_fft8(float2* a) {
  const float C = 0.70710678118654752f;
  {
    float2 t0 = csub(a[0], a[4]); a[0] = cadd(a[0], a[4]); a[4] = t0;
    float2 t1 = csub(a[1], a[5]); a[1] = cadd(a[1], a[5]);
    a[5] = INV ? make_float2(C*(t1.x - t1.y), C*(t1.x + t1.y))
               : make_float2(C*(t1.x + t1.y), C*(t1.y - t1.x));
    float2 t2 = csub(a[2], a[6]); a[2] = cadd(a[2], a[6]);
    a[6] = INV ? make_float2(-t2.y, t2.x) : make_float2(t2.y, -t2.x);
    float2 t3 = csub(a[3], a[7]); a[3] = cadd(a[3], a[7]);
    a[7] = INV ? make_float2(-C*(t3.x + t3.y), C*(t3.x - t3.y))
               : make_float2(C*(t3.y - t3.x), -C*(t3.x + t3.y));
  }
  #pragma unroll
  for (int g = 0; g < 2; ++g) {
    int b = g*4;
    float2 t0 = csub(a[b], a[b+2]); a[b] = cadd(a[b], a[b+2]); a[b+2] = t0;
    float2 t1 = csub(a[b+1], a[b+3]); a[b+1] = cadd(a[b+1], a[b+3]);
    a[b+3] = INV ? make_float2(-t1.y, t1.x) : make_float2(t1.y, -t1.x);
  }
  #pragma unroll
  for (int g = 0; g < 4; ++g) {
    int b = g*2;
    float2 t = csub(a[b], a[b+1]); a[b] = cadd(a[b], a[b+1]); a[b+1] = t;
  }
}

template<bool INV>
__device__ __forceinline__ void reg_fft4(float2* a) {
  float2 t0 = csub(a[0], a[2]); a[0] = cadd(a[0], a[2]); a[2] = t0;
  float2 t1 = csub(a[1], a[3]); a[1] = cadd(a[1], a[3]);
  a[3] = INV ? make_float2(-t1.y, t1.x) : make_float2(t1.y, -t1.x);
  t0 = csub(a[0], a[1]); a[0] = cadd(a[0], a[1]); a[1] = t0;
  t1 = csub(a[2], a[3]); a[2] = cadd(a[2], a[3]); a[3] = t1;
}

__device__ __forceinline__ void wfft512_fwd(float2* v, int lane) {
  const int BR3[8] = {0,4,2,6,1,5,3,7};
  reg_fft8<false>(v);
  float ang = -6.2831853071795865f * (float)lane * (1.f/512.f);
  float sn, cs; __sincosf(ang, &sn, &cs);
  float2 w1 = make_float2(cs, sn), w = w1;
  #pragma unroll
  for (int m = 1; m < 8; ++m) {
    v[BR3[m]] = cmulf(v[BR3[m]], w);
    if (m < 7) w = cmulf(w, w1);
  }
  xf64_fwd<8>(v, lane);
}

__device__ __forceinline__ void wfft512_inv(float2* v, int lane) {
  xf64_inv<8>(v, lane);
  float ang = 6.2831853071795865f * (float)lane * (1.f/512.f);
  float sn, cs; __sincosf(ang, &sn, &cs);
  float2 w1 = make_float2(cs, sn), w = w1;
  #pragma unroll
  for (int m = 1; m < 8; ++m) {
    v[m] = cmulf(v[m], w);
    if (m < 7) w = cmulf(w, w1);
  }
  reg_fft8<true>(v);
}

__device__ __forceinline__ void wfft256_fwd(float2* v, int lane) {
  const int BR2[4] = {0,2,1,3};
  reg_fft4<false>(v);
  float ang = -6.2831853071795865f * (float)lane * (1.f/256.f);
  float sn, cs; __sincosf(ang, &sn, &cs);
  float2 w1 = make_float2(cs, sn), w = w1;
  #pragma unroll
  for (int m = 1; m < 4; ++m) {
    v[BR2[m]] = cmulf(v[BR2[m]], w);
    if (m < 3) w = cmulf(w, w1);
  }
  xf64_fwd<4>(v, lane);
}

__device__ __forceinline__ void wfft256_inv(float2* v, int lane) {
  xf64_inv<4>(v, lane);
  float ang = 6.2831853071795865f * (float)lane * (1.f/256.f);
  float sn, cs; __sincosf(ang, &sn, &cs);
  float2 w1 = make_float2(cs, sn), w = w1;
  #pragma unroll
  for (int m = 1; m < 4; ++m) {
    v[m] = cmulf(v[m], w);
    if (m < 3) w = cmulf(w, w1);
  }
  reg_fft4<true>(v);
}

// ------------- merged setup: height map + transfer + aux tile -------------
__global__ void k_setup(const float* __restrict__ zc, const float4* __restrict__ zv,
                        float4* __restrict__ hm, const float* __restrict__ mp,
                        const float* __restrict__ cf, float* __restrict__ aux8,
                        float2* __restrict__ HB) {
  int bid = blockIdx.x;
  if (bid < 256) {
    // height map (float4)
    int idx = bid * 256 + threadIdx.x;
    float4 s = make_float4(0.f,0.f,0.f,0.f);
    #pragma unroll 8
    for (int t = 0; t < 64; ++t) {
      float c = zc[t];
      float4 v = zv[(size_t)t * (RR2/4) + idx];
      s.x += c*v.x; s.y += c*v.y; s.z += c*v.z; s.w += c*v.w;
    }
    hm[idx] = s;
  } else if (bid < 256 + 3072) {
    // transfer: PERMUTED both dims, both dists per band
    int gid = (bid - 256) * 256 + threadIdx.x;   // 3 * RR2
    int band = gid >> 18, idx = gid & (RR2 - 1);
    double wl = d_wls[band];
    int su = idx >> 9, sv = idx & 511;
    int fui = (su >> 6) + 8 * (__brev(su & 63) >> 26);
    int fvi = (sv >> 6) + 8 * (__brev(sv & 63) >> 26);
    double inv_nd = 1.0 / (512.0 * 3.69e-6);
    double fu = (double)((fui < 256) ? fui : fui - 512) * inv_nd;
    double fv = (double)((fvi < 256) ? fvi : fvi - 512) * inv_nd;
    double au = wl * fu, av = wl * fv;
    double argd = 1.0 - au*au - av*av;
    float2 h0 = make_float2(0.f, 0.f), h1 = h0;
    if (argd > 0.0) {
      double kz = (6.283185307179586 / wl) * sqrt(argd);
      float s, c;
      double p0 = fmod(0.047 * kz, 6.283185307179586);
      __sincosf((float)p0, &s, &c); h0 = make_float2(c, s);
      double p1 = fmod(0.003 * kz, 6.283185307179586);
      __sincosf((float)p1, &s, &c); h1 = make_float2(c, s);
    }
    HB[(size_t)(band*2    ) * RR2 + idx] = h0;
    HB[(size_t)(band*2 + 1) * RR2 + idx] = h1;
  } else {
    int idx = threadIdx.x;
    if (idx >= 192) return;
    int l = idx % 3, j = (idx / 3) & 7, i = idx / 24;
    int i4 = (i < 4) ? i : 7 - i;
    int j4 = (j < 4) ? j : 7 - j;
    float s = 0.f;
    for (int f = 0; f < 4; ++f) s += cf[f*3 + l] * mp[f*16 + i4*4 + j4];
    aux8[idx] = s;
  }
}

// ---------------- field build + wave rows-fwd ----------------
__global__ __launch_bounds__(256) void k_r512f_field(
    const float* __restrict__ hm, float2* __restrict__ A) {
  const int BR3[8] = {0,4,2,6,1,5,3,7};
  int lane = threadIdx.x & 63;
  int wid = (blockIdx.x << 2) | (threadIdx.x >> 6);   // band*512 + r
  int band = wid >> 9, r = wid & 511;
  float K = (float)(6.283185307179586 / d_wls[band] * d_dn[band]);
  const float* hrow = hm + (size_t)r * 512;
  int dx = r - 256;
  float2 v[8];
  #pragma unroll
  for (int m = 0; m < 8; ++m) {
    int col = lane + (m << 6);
    int dy = col - 256;
    float2 f = make_float2(0.f, 0.f);
    if (dx*dx + dy*dy < 65025) {
      float ph = K * hrow[col];
      float s, c;
      sincosf(ph, &s, &c);
      f = make_float2(c, s);
    }
    v[m] = f;
  }
  wfft512_fwd(v, lane);
  float2* row = A + (size_t)wid * 512;
  #pragma unroll
  for (int m = 0; m < 8; ++m) row[lane + (m << 6)] = v[BR3[m]];
}

// ===== mega: cols-fwd + xH1 + freq-domain mask (8x8 tile DFT) + xH2 + cols-inv
// Replica orbit of stored index under f±64 shifts = the aligned contiguous
// 8-block (rows: [8g,8g+8); cols: the block's 8 columns). Per 8x8 subtile:
//   Shat = DFT8x8+(S)   [input gathered j=br3(beta), output pos p holds t=br3(p)]
//   V_p  = (1/64) IDFT8x8-( Shat * m0((t_r+dr)&7,(t_c+dc)&7) )  [pos p = stored j]
__global__ __launch_bounds__(256) void k_mega512(
    const float2* __restrict__ A, const float2* __restrict__ HBp,
    const float* __restrict__ aux8, float2* __restrict__ U) {
  const int BR3[8] = {0,4,2,6,1,5,3,7};
  __shared__ float2 bufA[512*9];
  __shared__ float2 bufB[512*9];
  int tid = threadIdx.x;
  int c8 = tid & 7, w32 = tid >> 3;
  int lane = tid & 63, wv = tid >> 6;
  int band = blockIdx.y;
  int col0 = blockIdx.x * 8;
  const float2* img = A + ((size_t)band << 18) + col0;
  // ---- stage 1: load strip (spatial rows x 8 stored cols) ----
  #pragma unroll
  for (int r = w32; r < 512; r += 32) bufA[r*9 + c8] = img[(size_t)r * 512 + c8];
  __syncthreads();
  // ---- stage 2: wave col-fwd + xH1 -> bufA holds Spec(u1), stored order ----
  const float2* H1 = HBp + (((size_t)(band*2)) << 18);
  #pragma unroll
  for (int q = 0; q < 2; ++q) {
    int cc = wv*2 + q, scol = col0 + cc;
    float2 v[8];
    #pragma unroll
    for (int m = 0; m < 8; ++m) v[m] = bufA[(lane + (m << 6))*9 + cc];
    wfft512_fwd(v, lane);
    const float2* Hrow = H1 + (size_t)scol * 512;
    #pragma unroll
    for (int m = 0; m < 8; ++m)
      bufA[(lane + (m << 6))*9 + cc] = cmulf(v[BR3[m]], Hrow[lane + (m << 6)]);
  }
  __syncthreads();
  // ---- stage 3: DFT8+ over col-axis (each stored row) ----
  #pragma unroll
  for (int r = tid; r < 512; r += 256) {
    float2 a[8];
    #pragma unroll
    for (int b = 0; b < 8; ++b) a[b] = bufA[r*9 + BR3[b]];
    reg_fft8<true>(a);
    #pragma unroll
    for (int p = 0; p < 8; ++p) bufA[r*9 + p] = a[p];
  }
  __syncthreads();
  // ---- stage 4: DFT8+ over row-axis per (group g, col c) ----
  #pragma unroll
  for (int t2 = tid; t2 < 512; t2 += 256) {
    int g = t2 >> 3, c = t2 & 7;
    float2 a[8];
    #pragma unroll
    for (int b = 0; b < 8; ++b) a[b] = bufA[(8*g + BR3[b])*9 + c];
    reg_fft8<true>(a);
    #pragma unroll
    for (int p = 0; p < 8; ++p) bufA[(8*g + p)*9 + c] = a[p];
  }
  __syncthreads();
  const float2* H2 = HBp + (((size_t)(band*2 + 1)) << 18);
  for (int pm = 0; pm < 4; ++pm) {
    int dr = pm >> 1, dc = pm & 1;
    // ---- 5a: row-axis inverse with mask multiply ----
    #pragma unroll
    for (int t2 = tid; t2 < 512; t2 += 256) {
      int g = t2 >> 3, c = t2 & 7;
      int tc = BR3[c];                 // t_c = br3(c)
      int jm = ((tc + dc) & 7) * 3 + band;
      float2 nat[8];
      #pragma unroll
      for (int t = 0; t < 8; ++t) {
        float2 z = bufA[(8*g + BR3[t])*9 + c];
        float mv = aux8[((t + dr) & 7) * 24 + jm];
        nat[t] = make_float2(z.x*mv, z.y*mv);
      }
      reg_fft8<false>(nat);
      #pragma unroll
      for (int p = 0; p < 8; ++p) bufB[(8*g + p)*9 + c] = nat[p];
    }
    __syncthreads();
    // ---- 5b: col-axis inverse (+1/64) ----
    #pragma unroll
    for (int r = tid; r < 512; r += 256) {
      float2 nat[8];
      #pragma unroll
      for (int t = 0; t < 8; ++t) nat[t] = bufB[r*9 + BR3[t]];
      reg_fft8<false>(nat);
      const float s64 = 1.f/64.f;
      #pragma unroll
      for (int p = 0; p < 8; ++p)
        bufB[r*9 + p] = make_float2(nat[p].x*s64, nat[p].y*s64);
    }
    __syncthreads();
    // ---- 5c: xH2 + wave col-inv ----
    #pragma unroll
    for (int q = 0; q < 2; ++q) {
      int cc = wv*2 + q, scol = col0 + cc;
      const float2* H2row = H2 + (size_t)scol * 512;
      float2 u[8];
      #pragma unroll
      for (int m = 0; m < 8; ++m)
        u[m] = cmulf(bufB[(lane + (m << 6))*9 + cc], H2row[lane + (m << 6)]);
      wfft512_inv(u, lane);
      const float sc = 1.f/512.f;
      #pragma unroll
      for (int m = 0; m < 8; ++m) {
        float2 t = u[BR3[m]];
        bufB[(lane + (m << 6))*9 + cc] = make_float2(t.x*sc, t.y*sc);
      }
    }
    __syncthreads();
    // ---- 5d: coalesced write-out (natural spatial rows, stored cols) ----
    float2* orow = U + (((size_t)(band*4 + pm)) << 18) + col0;
    #pragma unroll
    for (int r = w32; r < 512; r += 32) orow[(size_t)r * 512 + c8] = bufB[r*9 + c8];
    __syncthreads();
  }
}

// ------- wave rows-inv (row pair) + |.|^2 + 2x2 down + partial sum --
__global__ __launch_bounds__(256) void k_r512_inv_psf(
    const float2* __restrict__ U, float* __restrict__ PSF, float* __restrict__ PSUMP) {
  const int BR3[8] = {0,4,2,6,1,5,3,7};
  int lane = threadIdx.x & 63;
  int wid = (blockIdx.x << 2) | (threadIdx.x >> 6);   // p*256 + i
  int p = wid >> 8, i = wid & 255;
  const float2* row0 = U + ((size_t)p << 18) + (size_t)(2*i) * 512;
  const float2* row1 = row0 + 512;
  float2 v0[8], v1[8];
  #pragma unroll
  for (int m = 0; m < 8; ++m) v0[m] = row0[lane + (m << 6)];
  #pragma unroll
  for (int m = 0; m < 8; ++m) v1[m] = row1[lane + (m << 6)];
  wfft512_inv(v0, lane);
  wfft512_inv(v1, lane);
  float colsum[8];
  float tot = 0.f;
  #pragma unroll
  for (int pos = 0; pos < 8; ++pos) {
    float sq = v0[pos].x*v0[pos].x + v0[pos].y*v0[pos].y
             + v1[pos].x*v1[pos].x + v1[pos].y*v1[pos].y;
    tot += sq;
    colsum[pos] = sq;
  }
  const float sc2 = 0.25f / (512.f * 512.f);
  #pragma unroll
  for (int pos = 0; pos < 8; ++pos) {
    float pairs = colsum[pos] + __shfl_xor(colsum[pos], 1);
    if (!(lane & 1)) {
      int col = (lane >> 1) + (BR3[pos] << 5);
      PSF[((size_t)p << 16) | (i << 8) | col] = sc2 * pairs;
    }
  }
  #pragma unroll
  for (int h = 1; h < 64; h <<= 1) tot += __shfl_xor(tot, h);
  if (lane == 0) PSUMP[(p << 8) | i] = tot * sc2;
}

// --- wave rows-fwd fused with OTF load (shift + in-wave psum reduce + norm) ---
__global__ __launch_bounds__(256) void k_r256f_otf(
    const float* __restrict__ PSF, const float* __restrict__ PSUMP,
    float2* __restrict__ OTF) {
  const int BR2[4] = {0,2,1,3};
  int lane = threadIdx.x & 63;
  int wid = (blockIdx.x << 2) | (threadIdx.x >> 6);   // p*256 + i
  int p = wid >> 8, i = wid & 255;
  const float4* pp = reinterpret_cast<const float4*>(PSUMP + (p << 8));
  float4 q = pp[lane];
  float tot = (q.x + q.y) + (q.z + q.w);
  #pragma unroll
  for (int h = 1; h < 64; h <<= 1) tot += __shfl_xor(tot, h);
  float inv = 1.0f / tot;
  int si = (i + 128) & 255;
  const float* prow = PSF + ((size_t)p << 16) + (si << 8);
  float2 v[4];
  #pragma unroll
  for (int m = 0; m < 4; ++m) {
    int col = lane + (((m + 2) & 3) << 6);
    v[m] = make_float2(prow[col] * inv, 0.f);
  }
  wfft256_fwd(v, lane);
  float2* row = OTF + (size_t)wid * 256;
  #pragma unroll
  for (int m = 0; m < 4; ++m) row[lane + (m << 6)] = v[BR2[m]];
}

// ------- OTF cols-fwd (wave FFT, 1 col/wave) + parity S build in registers ----
__global__ __launch_bounds__(256) void k_c256w(
    const float2* __restrict__ OTF, float2* __restrict__ Sb) {
  const int BR2[4] = {0,2,1,3};
  __shared__ float2 tile[256*5];
  int tid = threadIdx.x;
  int c = tid & 3, w = tid >> 2;
  int lane = tid & 63, wv = tid >> 6;
  int band = blockIdx.y;
  int col = blockIdx.x * 4 + c;
  float2 S0[4], S1[4], S2[4], S3[4];
  #pragma unroll
  for (int m = 0; m < 4; ++m) {
    S0[m] = make_float2(0.f,0.f); S1[m] = make_float2(0.f,0.f);
    S2[m] = make_float2(0.f,0.f); S3[m] = make_float2(0.f,0.f);
  }
  for (int q = 0; q < 4; ++q) {
    __syncthreads();
    const float2* img = OTF + (((size_t)(band*4 + q)) << 16) + col;
    #pragma unroll
    for (int r = w; r < 256; r += 64) tile[r*5 + c] = img[(size_t)r * 256];
    __syncthreads();
    float2 v[4];
    #pragma unroll
    for (int m = 0; m < 4; ++m) v[m] = tile[(lane + (m << 6))*5 + wv];
    wfft256_fwd(v, lane);
    float sg1 = (q & 1) ? -1.f : 1.f;
    float sg2 = (q & 2) ? -1.f : 1.f;
    float sg3 = sg1 * sg2;
    #pragma unroll
    for (int m = 0; m < 4; ++m) {
      float2 z = v[BR2[m]];
      S0[m] = cadd(S0[m], z);
      S1[m] = make_float2(S1[m].x + sg1*z.x, S1[m].y + sg1*z.y);
      S2[m] = make_float2(S2[m].x + sg2*z.x, S2[m].y + sg2*z.y);
      S3[m] = make_float2(S3[m].x + sg3*z.x, S3[m].y + sg3*z.y);
    }
  }
  float2* S = Sb + (((size_t)(band*4)) << 16);
  #define WRITE_S(idx, arr)                                               \
  {                                                                       \
    __syncthreads();                                                      \
    _Pragma("unroll")                                                     \
    for (int m = 0; m < 4; ++m) tile[(lane + (m << 6))*5 + wv] = arr[m];  \
    __syncthreads();                                                      \
    _Pragma("unroll")                                                     \
    for (int r = w; r < 256; r += 64)                                     \
      S[((size_t)(idx) << 16) + (r << 8) + col] = tile[r*5 + c];          \
  }
  WRITE_S(0, S0)
  WRITE_S(1, S1)
  WRITE_S(2, S2)
  WRITE_S(3, S3)
  #undef WRITE_S
}

// ---------------- wave rows-fwd fused with input load ----------------
__global__ __launch_bounds__(256) void k_r256f_x(
    const float* __restrict__ in, float2* __restrict__ X) {
  const int BR2[4] = {0,2,1,3};
  int lane = threadIdx.x & 63;
  int wid = (blockIdx.x << 2) | (threadIdx.x >> 6);   // p*256 + i
  int p = wid >> 8, i = wid & 255;
  int band = p >> 3, img = p & 7;
  const float* src = in + (((size_t)img * 256 + i) * 256) * 3 + band;
  float2 v[4];
  #pragma unroll
  for (int m = 0; m < 4; ++m) v[m] = make_float2(src[(lane + (m << 6)) * 3], 0.f);
  wfft256_fwd(v, lane);
  float2* row = X + (size_t)wid * 256;
  #pragma unroll
  for (int m = 0; m < 4; ++m) row[lane + (m << 6)] = v[BR2[m]];
}

// --- fused: X cols-fwd (wave) + 9-tap combine (permuted taps) + cols-inv ------
__global__ __launch_bounds__(256) void k_xyc(
    const float2* __restrict__ X, const float2* __restrict__ Sb,
    float2* __restrict__ Y) {
  const int BR2[4] = {0,2,1,3};
  const int CAm[4] = {3,2,0,1};
  const int CBm[4] = {2,3,1,0};
  __shared__ float2 Xl[256*9];
  int tid = threadIdx.x;
  int c = tid & 7, w = tid >> 3;
  int lane = tid & 63, wv = tid >> 6;
  int n = blockIdx.y;
  int band = n >> 3;
  int col0 = blockIdx.x * 8;
  const float2* Xn = X + ((size_t)n << 16);
  #pragma unroll
  for (int r = w; r < 256; r += 32) Xl[r*9 + c] = Xn[(r << 8) | (col0 + c)];
  __syncthreads();
  #pragma unroll
  for (int q = 0; q < 2; ++q) {
    int cc = wv*2 + q;
    float2 v[4];
    #pragma unroll
    for (int m = 0; m < 4; ++m) v[m] = Xl[(lane + (m << 6))*9 + cc];
    wfft256_fwd(v, lane);
    #pragma unroll
    for (int m = 0; m < 4; ++m) Xl[(lane + (m << 6))*9 + cc] = v[BR2[m]];
  }
  __syncthreads();
  const float2* S = Sb + (((size_t)(band*4)) << 16);
  float2 pa0[4], pa1[4];
  #define COMBINE(pa, qq)                                                       \
  {                                                                             \
    int cc = wv*2 + (qq);                                                       \
    int cA = (cc & 4) | CAm[cc & 3];                                            \
    int cB = (cc & 4) | CBm[cc & 3];                                            \
    int scol = col0 + cc;                                                       \
    _Pragma("unroll")                                                           \
    for (int m = 0; m < 4; ++m) {                                               \
      int u  = lane + (m << 6);                                                 \
      int ua = (u & ~3) | CAm[u & 3];                                           \
      int ub = (u & ~3) | CBm[u & 3];                                           \
      float2 X00 = Xl[u*9 + cc];                                                \
      float2 X01 = Xl[u*9 + cA],  X03 = Xl[u*9 + cB];                           \
      float2 X10 = Xl[ua*9 + cc], X30 = Xl[ub*9 + cc];                          \
      float2 X11 = Xl[ua*9 + cA], X13 = Xl[ua*9 + cB];                          \
      float2 X31 = Xl[ub*9 + cA], X33 = Xl[ub*9 + cB];                          \
      float2 t00 = make_float2(0.25f*X00.x, 0.25f*X00.y);                       \
      float2 t01 = make_float2(0.125f*(X01.x + X03.x - (X03.y - X01.y)),        \
                               0.125f*(X01.y + X03.y + (X03.x - X01.x)));       \
      float2 t10 = make_float2(0.125f*(X10.x + X30.x - (X30.y - X10.y)),        \
                               0.125f*(X10.y + X30.y + (X30.x - X10.x)));       \
      float2 t11 = make_float2(0.125f*(X13.x + X31.x - (X33.y - X11.y)),        \
                               0.125f*(X13.y + X31.y + (X33.x - X11.x)));       \
      int uv = (u << 8) | scol;                                                 \
      float2 acc = cmulf(S[uv], t00);                                           \
      acc = cadd(acc, cmulf(S[(1<<16) | uv], t01));                             \
      acc = cadd(acc, cmulf(S[(2<<16) | uv], t10));                             \
      acc = cadd(acc, cmulf(S[(3<<16) | uv], t11));                             \
      pa[m] = acc;                                                              \
    }                                                                           \
  }
  COMBINE(pa0, 0)
  COMBINE(pa1, 1)
  #undef COMBINE
  __syncthreads();
  const float sc = 1.f/256.f;
  wfft256_inv(pa0, lane);
  wfft256_inv(pa1, lane);
  #pragma unroll
  for (int pos = 0; pos < 4; ++pos) {
    int rown = lane + (BR2[pos] << 6);
    float2 a = pa0[pos], b = pa1[pos];
    Xl[rown*9 + wv*2]     = make_float2(a.x*sc, a.y*sc);
    Xl[rown*9 + wv*2 + 1] = make_float2(b.x*sc, b.y*sc);
  }
  __syncthreads();
  float2* Yn = Y + ((size_t)n << 16);
  #pragma unroll
  for (int r = w; r < 256; r += 32) Yn[(r << 8) | (col0 + c)] = Xl[r*9 + c];
}

// ---------------- wave rows-inv over 3 bands + color accumulate ----------------
__global__ __launch_bounds__(256) void k_r256_inv_accum3(
    const float2* __restrict__ Y, float* __restrict__ out,
    const float* __restrict__ cf) {
  const int BR2[4] = {0,2,1,3};
  int lane = threadIdx.x & 63;
  int wid = (blockIdx.x << 2) | (threadIdx.x >> 6);   // img*256 + i
  int img = wid >> 8, i = wid & 255;
  float accR[4] = {0.f,0.f,0.f,0.f};
  float accG[4] = {0.f,0.f,0.f,0.f};
  float accB[4] = {0.f,0.f,0.f,0.f};
  const float sc = 1.f/256.f;
  for (int band = 0; band < 3; ++band) {
    const float2* row = Y + (((size_t)(band*8 + img)) << 16) + ((size_t)i << 8);
    float2 v[4];
    #pragma unroll
    for (int m = 0; m < 4; ++m) v[m] = row[lane + (m << 6)];
    wfft256_inv(v, lane);
    float c0 = cf[band], c1 = cf[3 + band], c2 = cf[9 + band];
    #pragma unroll
    for (int pos = 0; pos < 4; ++pos) {
      float re = v[pos].x * sc;
      int n2 = BR2[pos];
      accR[n2] += c0*re; accG[n2] += c1*re; accB[n2] += c2*re;
    }
  }
  #pragma unroll
  for (int n2 = 0; n2 < 4; ++n2) {
    int col = lane + (n2 << 6);
    float* o = out + (((size_t)img * 256 + i) * 256 + col) * 3;
    o[0] = accR[n2]; o[1] = accG[n2]; o[2] = accB[n2];
  }
}

// ================= host-side dispatch =================

extern "C" void kernel_launch(void* const* d_in, const int* in_sizes, int n_in,
                              void* d_out, int out_size, void* d_ws, size_t ws_size,
                              hipStream_t stream) {
  const float* inp = (const float*)d_in[0];
  const float* zc  = (const float*)d_in[1];
  const float* zv  = (const float*)d_in[2];
  const float* mp  = (const float*)d_in[3];
  const float* cf  = (const float*)d_in[4];
  float* out = (float*)d_out;

  char* ws = (char*)d_ws;
  size_t off = 0;
  auto alloc = [&](size_t bytes) -> void* {
    void* p = ws + off;
    off = (off + bytes + 255) & ~(size_t)255;
    return p;
  };
  float*  hm    = (float*) alloc((size_t)RR2 * 4);
  float*  aux8  = (float*) alloc(256 * 4);
  float*  PSUMP = (float*) alloc((size_t)12 * 256 * 4);
  float2* A     = (float2*)alloc((size_t)3 * RR2 * 8);
  float2* HB    = (float2*)alloc((size_t)6 * RR2 * 8);
  float2* U     = (float2*)alloc((size_t)12 * RR2 * 8);
  float*  PSF   = (float*) alloc((size_t)12 * PP2 * 4);
  float2* OTF   = (float2*)alloc((size_t)12 * PP2 * 8);
  float2* Sb    = (float2*)alloc((size_t)12 * PP2 * 8);
  float2* X     = (float2*)alloc((size_t)24 * PP2 * 8);
  float2* Y     = (float2*)alloc((size_t)24 * PP2 * 8);

  // ---- merged setup: height map + transfer + aux ----
  k_setup<<<256 + 3072 + 1, 256, 0, stream>>>(zc, (const float4*)zv, (float4*)hm,
                                              mp, cf, aux8, HB);

  // ---- field rows-fwd -> A ----
  k_r512f_field<<<3*512/4, 256, 0, stream>>>(hm, A);

  // ---- mega: cols-fwd + xH1 + freq-domain mask x4 + xH2 + cols-inv -> U ----
  k_mega512<<<dim3(64, 3), 256, 0, stream>>>(A, HB, aux8, U);

  // ---- rows-inv + |.|^2 + downsample -> PSF ----
  k_r512_inv_psf<<<12*256/4, 256, 0, stream>>>(U, PSF, PSUMP);

  // ---- OTFs + parity S build ----
  k_r256f_otf<<<12*256/4, 256, 0, stream>>>(PSF, PSUMP, OTF);
  k_c256w<<<dim3(64, 3), 256, 0, stream>>>(OTF, Sb);

  // ---- convolution ----
  k_r256f_x<<<24*256/4, 256, 0, stream>>>(inp, X);
  k_xyc<<<dim3(32, 24), 256, 0, stream>>>(X, Sb, Y);
  k_r256_inv_accum3<<<8*256/4, 256, 0, stream>>>(Y, out, cf);
}

// Round 10
// 130.122 us; speedup vs baseline: 1.7709x; 1.1014x over previous
//
#include <hip/hip_runtime.h>
#include <math.h>

#define RR 512
#define RR2 (RR*RR)
#define PP 256
#define PP2 (PP*PP)

__constant__ double d_wls[3] = {4.6e-7, 5.4e-7, 6.2e-7};
__constant__ double d_dn[3]  = {0.52, 0.515, 0.51};

__device__ __forceinline__ float2 cadd(float2 a, float2 b){ return make_float2(a.x+b.x, a.y+b.y); }
__device__ __forceinline__ float2 csub(float2 a, float2 b){ return make_float2(a.x-b.x, a.y-b.y); }
__device__ __forceinline__ float2 cmulf(float2 a, float2 b){ return make_float2(a.x*b.x-a.y*b.y, a.x*b.y+a.y*b.x); }

// ======================================================================
// Wave-level FFT: N = 64 lanes x R regs, element n = lane + 64*reg.
// storage: out[lane + 64*m] = v[brR(m)]  ->  f(s) = (s>>6) + R_hi*bitrev6(s&63)
// ======================================================================

template<int R>
__device__ __forceinline__ void xf64_fwd(float2* v, int lane) {
  #pragma unroll
  for (int h = 32; h >= 1; h >>= 1) {
    float ang = -6.2831853071795865f * (float)(lane & (h-1)) / (float)(2*h);
    float sn, cs;
    __sincosf(ang, &sn, &cs);
    bool odd = (lane & h) != 0;
    float wc = odd ? cs : 1.f;
    float ws = odd ? sn : 0.f;
    #pragma unroll
    for (int r = 0; r < R; ++r) {
      float2 t;
      t.x = __shfl_xor(v[r].x, h);
      t.y = __shfl_xor(v[r].y, h);
      float2 d = odd ? csub(t, v[r]) : cadd(v[r], t);
      v[r] = make_float2(d.x*wc - d.y*ws, d.x*ws + d.y*wc);
    }
  }
}

template<int R>
__device__ __forceinline__ void xf64_inv(float2* v, int lane) {
  #pragma unroll
  for (int h = 1; h <= 32; h <<= 1) {
    float ang = 6.2831853071795865f * (float)(lane & (h-1)) / (float)(2*h);
    float sn, cs;
    __sincosf(ang, &sn, &cs);
    bool odd = (lane & h) != 0;
    #pragma unroll
    for (int r = 0; r < R; ++r) {
      float2 t;
      t.x = __shfl_xor(v[r].x, h);
      t.y = __shfl_xor(v[r].y, h);
      float2 s = odd ? v[r] : t;
      float2 ws = make_float2(s.x*cs - s.y*sn, s.x*sn + s.y*cs);
      v[r] = odd ? csub(t, ws) : cadd(v[r], ws);
    }
  }
}

template<bool INV>
__device__ __forceinline__ void reg_fft8(float2* a) {
  const float C = 0.70710678118654752f;
  {
    float2 t0 = csub(a[0], a[4]); a[0] = cadd(a[0], a[4]); a[4] = t0;
    float2 t1 = csub(a[1], a[5]); a[1] = cadd(a[1], a[5]);
    a[5] = INV ? make_float2(C*(t1.x - t1.y), C*(t1.x + t1.y))
               : make_float2(C*(t1.x + t1.y), C*(t1.y - t1.x));
    float2 t2 = csub(a[2], a[6]); a[2] = cadd(a[2], a[6]);
    a[6] = INV ? make_float2(-t2.y, t2.x) : make_float2(t2.y, -t2.x);
    float2 t3 = csub(a[3], a[7]); a[3] = cadd(a[3], a[7]);
    a[7] = INV ? make_float2(-C*(t3.x + t3.y), C*(t3.x - t3.y))
               : make_float2(C*(t3.y - t3.x), -C*(t3.x + t3.y));
  }
  #pragma unroll
  for (int g = 0; g < 2; ++g) {
    int b = g*4;
    float2 t0 = csub(a[b], a[b+2]); a[b] = cadd(a[b], a[b+2]); a[b+2] = t0;
    float2 t1 = csub(a[b+1], a[b+3]); a[b+1] = cadd(a[b+1], a[b+3]);
    a[b+3] = INV ? make_float2(-t1.y, t1.x) : make_float2(t1.y, -t1.x);
  }
  #pragma unroll
  for (int g = 0; g < 4; ++g) {
    int b = g*2;
    float2 t = csub(a[b], a[b+1]); a[b] = cadd(a[b], a[b+1]); a[b+1] = t;
  }
}

template<bool INV>
__device__ __forceinline__ void reg_fft4(float2* a) {
  float2 t0 = csub(a[0], a[2]); a[0] = cadd(a[0], a[2]); a[2] = t0;
  float2 t1 = csub(a[1], a[3]); a[1] = cadd(a[1], a[3]);
  a[3] = INV ? make_float2(-t1.y, t1.x) : make_float2(t1.y, -t1.x);
  t0 = csub(a[0], a[1]); a[0] = cadd(a[0], a[1]); a[1] = t0;
  t1 = csub(a[2], a[3]); a[2] = cadd(a[2], a[3]); a[3] = t1;
}

__device__ __forceinline__ void wfft512_fwd(float2* v, int lane) {
  const int BR3[8] = {0,4,2,6,1,5,3,7};
  reg_fft8<false>(v);
  float ang = -6.2831853071795865f * (float)lane * (1.f/512.f);
  float sn, cs; __sincosf(ang, &sn, &cs);
  float2 w1 = make_float2(cs, sn), w = w1;
  #pragma unroll
  for (int m = 1; m < 8; ++m) {
    v[BR3[m]] = cmulf(v[BR3[m]], w);
    if (m < 7) w = cmulf(w, w1);
  }
  xf64_fwd<8>(v, lane);
}

__device__ __forceinline__ void wfft512_inv(float2* v, int lane) {
  xf64_inv<8>(v, lane);
  float ang = 6.2831853071795865f * (float)lane * (1.f/512.f);
  float sn, cs; __sincosf(ang, &sn, &cs);
  float2 w1 = make_float2(cs, sn), w = w1;
  #pragma unroll
  for (int m = 1; m < 8; ++m) {
    v[m] = cmulf(v[m], w);
    if (m < 7) w = cmulf(w, w1);
  }
  reg_fft8<true>(v);
}

__device__ __forceinline__ void wfft256_fwd(float2* v, int lane) {
  const int BR2[4] = {0,2,1,3};
  reg_fft4<false>(v);
  float ang = -6.2831853071795865f * (float)lane * (1.f/256.f);
  float sn, cs; __sincosf(ang, &sn, &cs);
  float2 w1 = make_float2(cs, sn), w = w1;
  #pragma unroll
  for (int m = 1; m < 4; ++m) {
    v[BR2[m]] = cmulf(v[BR2[m]], w);
    if (m < 3) w = cmulf(w, w1);
  }
  xf64_fwd<4>(v, lane);
}

__device__ __forceinline__ void wfft256_inv(float2* v, int lane) {
  xf64_inv<4>(v, lane);
  float ang = 6.2831853071795865f * (float)lane * (1.f/256.f);
  float sn, cs; __sincosf(ang, &sn, &cs);
  float2 w1 = make_float2(cs, sn), w = w1;
  #pragma unroll
  for (int m = 1; m < 4; ++m) {
    v[m] = cmulf(v[m], w);
    if (m < 3) w = cmulf(w, w1);
  }
  reg_fft4<true>(v);
}

// ------------- merged setup: height map + transfer + aux tile -------------
__global__ void k_setup(const float* __restrict__ zc, const float4* __restrict__ zv,
                        float4* __restrict__ hm, const float* __restrict__ mp,
                        const float* __restrict__ cf, float* __restrict__ aux8,
                        float2* __restrict__ HB) {
  int bid = blockIdx.x;
  if (bid < 256) {
    int idx = bid * 256 + threadIdx.x;
    float4 s = make_float4(0.f,0.f,0.f,0.f);
    #pragma unroll 8
    for (int t = 0; t < 64; ++t) {
      float c = zc[t];
      float4 v = zv[(size_t)t * (RR2/4) + idx];
      s.x += c*v.x; s.y += c*v.y; s.z += c*v.z; s.w += c*v.w;
    }
    hm[idx] = s;
  } else if (bid < 256 + 3072) {
    int gid = (bid - 256) * 256 + threadIdx.x;   // 3 * RR2
    int band = gid >> 18, idx = gid & (RR2 - 1);
    double wl = d_wls[band];
    int su = idx >> 9, sv = idx & 511;
    int fui = (su >> 6) + 8 * (__brev(su & 63) >> 26);
    int fvi = (sv >> 6) + 8 * (__brev(sv & 63) >> 26);
    double inv_nd = 1.0 / (512.0 * 3.69e-6);
    double fu = (double)((fui < 256) ? fui : fui - 512) * inv_nd;
    double fv = (double)((fvi < 256) ? fvi : fvi - 512) * inv_nd;
    double au = wl * fu, av = wl * fv;
    double argd = 1.0 - au*au - av*av;
    float2 h0 = make_float2(0.f, 0.f), h1 = h0;
    if (argd > 0.0) {
      double kz = (6.283185307179586 / wl) * sqrt(argd);
      float s, c;
      double p0 = fmod(0.047 * kz, 6.283185307179586);
      __sincosf((float)p0, &s, &c); h0 = make_float2(c, s);
      double p1 = fmod(0.003 * kz, 6.283185307179586);
      __sincosf((float)p1, &s, &c); h1 = make_float2(c, s);
    }
    HB[(size_t)(band*2    ) * RR2 + idx] = h0;
    HB[(size_t)(band*2 + 1) * RR2 + idx] = h1;
  } else {
    int idx = threadIdx.x;
    if (idx >= 192) return;
    int l = idx % 3, j = (idx / 3) & 7, i = idx / 24;
    int i4 = (i < 4) ? i : 7 - i;
    int j4 = (j < 4) ? j : 7 - j;
    float s = 0.f;
    for (int f = 0; f < 4; ++f) s += cf[f*3 + l] * mp[f*16 + i4*4 + j4];
    aux8[idx] = s;
  }
}

// ---------------- field build + wave rows-fwd ----------------
__global__ __launch_bounds__(256) void k_r512f_field(
    const float* __restrict__ hm, float2* __restrict__ A) {
  const int BR3[8] = {0,4,2,6,1,5,3,7};
  int lane = threadIdx.x & 63;
  int wid = (blockIdx.x << 2) | (threadIdx.x >> 6);   // band*512 + r
  int band = wid >> 9, r = wid & 511;
  float K = (float)(6.283185307179586 / d_wls[band] * d_dn[band]);
  const float* hrow = hm + (size_t)r * 512;
  int dx = r - 256;
  float2 v[8];
  #pragma unroll
  for (int m = 0; m < 8; ++m) {
    int col = lane + (m << 6);
    int dy = col - 256;
    float2 f = make_float2(0.f, 0.f);
    if (dx*dx + dy*dy < 65025) {
      float ph = K * hrow[col];
      float s, c;
      sincosf(ph, &s, &c);
      f = make_float2(c, s);
    }
    v[m] = f;
  }
  wfft512_fwd(v, lane);
  float2* row = A + (size_t)wid * 512;
  #pragma unroll
  for (int m = 0; m < 8; ++m) row[lane + (m << 6)] = v[BR3[m]];
}

// ===== mega (pm split across blockIdx.z, single in-place 36KB LDS buffer) =====
// cols-fwd + xH1 + [DFT8x8 -> mask(dr,dc) -> IDFT8x8] + xH2 + cols-inv
__global__ __launch_bounds__(256) void k_mega512(
    const float2* __restrict__ A, const float2* __restrict__ HBp,
    const float* __restrict__ aux8, float2* __restrict__ U) {
  const int BR3[8] = {0,4,2,6,1,5,3,7};
  __shared__ float2 buf[512*9];
  int tid = threadIdx.x;
  int c8 = tid & 7, w32 = tid >> 3;
  int lane = tid & 63, wv = tid >> 6;
  int band = blockIdx.y;
  int pm = blockIdx.z;
  int dr = pm >> 1, dc = pm & 1;
  int col0 = blockIdx.x * 8;
  const float2* img = A + ((size_t)band << 18) + col0;
  // ---- load strip ----
  #pragma unroll
  for (int r = w32; r < 512; r += 32) buf[r*9 + c8] = img[(size_t)r * 512 + c8];
  __syncthreads();
  // ---- wave col-fwd + xH1 (wave-private columns, in-place) ----
  const float2* H1 = HBp + (((size_t)(band*2)) << 18);
  #pragma unroll
  for (int q = 0; q < 2; ++q) {
    int cc = wv*2 + q, scol = col0 + cc;
    float2 v[8];
    #pragma unroll
    for (int m = 0; m < 8; ++m) v[m] = buf[(lane + (m << 6))*9 + cc];
    wfft512_fwd(v, lane);
    const float2* Hrow = H1 + (size_t)scol * 512;
    #pragma unroll
    for (int m = 0; m < 8; ++m)
      buf[(lane + (m << 6))*9 + cc] = cmulf(v[BR3[m]], Hrow[lane + (m << 6)]);
  }
  __syncthreads();
  // ---- col-axis DFT8 (thread-per-row, in-place) ----
  #pragma unroll
  for (int r = tid; r < 512; r += 256) {
    float2 a[8];
    #pragma unroll
    for (int b = 0; b < 8; ++b) a[b] = buf[r*9 + BR3[b]];
    reg_fft8<true>(a);
    #pragma unroll
    for (int p = 0; p < 8; ++p) buf[r*9 + p] = a[p];
  }
  __syncthreads();
  // ---- row-axis DFT8 + mask + IDFT8, fused in registers (thread-per-(g,c)) ----
  #pragma unroll
  for (int t2 = tid; t2 < 512; t2 += 256) {
    int g = t2 >> 3, c = t2 & 7;
    int tc = BR3[c];
    int jm = ((tc + dc) & 7) * 3 + band;
    float2 a[8];
    #pragma unroll
    for (int b = 0; b < 8; ++b) a[b] = buf[(8*g + BR3[b])*9 + c];
    reg_fft8<true>(a);
    float2 nat[8];
    #pragma unroll
    for (int t = 0; t < 8; ++t) {
      float2 z = a[BR3[t]];
      float mv = aux8[((t + dr) & 7) * 24 + jm];
      nat[t] = make_float2(z.x*mv, z.y*mv);
    }
    reg_fft8<false>(nat);
    #pragma unroll
    for (int p = 0; p < 8; ++p) buf[(8*g + p)*9 + c] = nat[p];
  }
  __syncthreads();
  // ---- col-axis IDFT8 (+1/64, thread-per-row, in-place) ----
  #pragma unroll
  for (int r = tid; r < 512; r += 256) {
    float2 nat[8];
    #pragma unroll
    for (int t = 0; t < 8; ++t) nat[t] = buf[r*9 + BR3[t]];
    reg_fft8<false>(nat);
    const float s64 = 1.f/64.f;
    #pragma unroll
    for (int p = 0; p < 8; ++p)
      buf[r*9 + p] = make_float2(nat[p].x*s64, nat[p].y*s64);
  }
  __syncthreads();
  // ---- xH2 + wave col-inv (wave-private columns, in-place) ----
  const float2* H2 = HBp + (((size_t)(band*2 + 1)) << 18);
  #pragma unroll
  for (int q = 0; q < 2; ++q) {
    int cc = wv*2 + q, scol = col0 + cc;
    const float2* H2row = H2 + (size_t)scol * 512;
    float2 u[8];
    #pragma unroll
    for (int m = 0; m < 8; ++m)
      u[m] = cmulf(buf[(lane + (m << 6))*9 + cc], H2row[lane + (m << 6)]);
    wfft512_inv(u, lane);
    const float sc = 1.f/512.f;
    #pragma unroll
    for (int m = 0; m < 8; ++m) {
      float2 t = u[BR3[m]];
      buf[(lane + (m << 6))*9 + cc] = make_float2(t.x*sc, t.y*sc);
    }
  }
  __syncthreads();
  // ---- coalesced write-out ----
  float2* orow = U + (((size_t)(band*4 + pm)) << 18) + col0;
  #pragma unroll
  for (int r = w32; r < 512; r += 32) orow[(size_t)r * 512 + c8] = buf[r*9 + c8];
}

// ------- wave rows-inv (row pair) + |.|^2 + 2x2 down + partial sum --
__global__ __launch_bounds__(256) void k_r512_inv_psf(
    const float2* __restrict__ U, float* __restrict__ PSF, float* __restrict__ PSUMP) {
  const int BR3[8] = {0,4,2,6,1,5,3,7};
  int lane = threadIdx.x & 63;
  int wid = (blockIdx.x << 2) | (threadIdx.x >> 6);   // p*256 + i
  int p = wid >> 8, i = wid & 255;
  const float2* row0 = U + ((size_t)p << 18) + (size_t)(2*i) * 512;
  const float2* row1 = row0 + 512;
  float2 v0[8], v1[8];
  #pragma unroll
  for (int m = 0; m < 8; ++m) v0[m] = row0[lane + (m << 6)];
  #pragma unroll
  for (int m = 0; m < 8; ++m) v1[m] = row1[lane + (m << 6)];
  wfft512_inv(v0, lane);
  wfft512_inv(v1, lane);
  float colsum[8];
  float tot = 0.f;
  #pragma unroll
  for (int pos = 0; pos < 8; ++pos) {
    float sq = v0[pos].x*v0[pos].x + v0[pos].y*v0[pos].y
             + v1[pos].x*v1[pos].x + v1[pos].y*v1[pos].y;
    tot += sq;
    colsum[pos] = sq;
  }
  const float sc2 = 0.25f / (512.f * 512.f);
  #pragma unroll
  for (int pos = 0; pos < 8; ++pos) {
    float pairs = colsum[pos] + __shfl_xor(colsum[pos], 1);
    if (!(lane & 1)) {
      int col = (lane >> 1) + (BR3[pos] << 5);
      PSF[((size_t)p << 16) | (i << 8) | col] = sc2 * pairs;
    }
  }
  #pragma unroll
  for (int h = 1; h < 64; h <<= 1) tot += __shfl_xor(tot, h);
  if (lane == 0) PSUMP[(p << 8) | i] = tot * sc2;
}

// --- wave rows-fwd fused with OTF load (shift + in-wave psum reduce + norm) ---
__global__ __launch_bounds__(256) void k_r256f_otf(
    const float* __restrict__ PSF, const float* __restrict__ PSUMP,
    float2* __restrict__ OTF) {
  const int BR2[4] = {0,2,1,3};
  int lane = threadIdx.x & 63;
  int wid = (blockIdx.x << 2) | (threadIdx.x >> 6);   // p*256 + i
  int p = wid >> 8, i = wid & 255;
  const float4* pp = reinterpret_cast<const float4*>(PSUMP + (p << 8));
  float4 q = pp[lane];
  float tot = (q.x + q.y) + (q.z + q.w);
  #pragma unroll
  for (int h = 1; h < 64; h <<= 1) tot += __shfl_xor(tot, h);
  float inv = 1.0f / tot;
  int si = (i + 128) & 255;
  const float* prow = PSF + ((size_t)p << 16) + (si << 8);
  float2 v[4];
  #pragma unroll
  for (int m = 0; m < 4; ++m) {
    int col = lane + (((m + 2) & 3) << 6);
    v[m] = make_float2(prow[col] * inv, 0.f);
  }
  wfft256_fwd(v, lane);
  float2* row = OTF + (size_t)wid * 256;
  #pragma unroll
  for (int m = 0; m < 4; ++m) row[lane + (m << 6)] = v[BR2[m]];
}

// ------- OTF cols-fwd (wave FFT, 1 col/wave) + parity S build in registers ----
__global__ __launch_bounds__(256) void k_c256w(
    const float2* __restrict__ OTF, float2* __restrict__ Sb) {
  const int BR2[4] = {0,2,1,3};
  __shared__ float2 tile[256*5];
  int tid = threadIdx.x;
  int c = tid & 3, w = tid >> 2;
  int lane = tid & 63, wv = tid >> 6;
  int band = blockIdx.y;
  int col = blockIdx.x * 4 + c;
  float2 S0[4], S1[4], S2[4], S3[4];
  #pragma unroll
  for (int m = 0; m < 4; ++m) {
    S0[m] = make_float2(0.f,0.f); S1[m] = make_float2(0.f,0.f);
    S2[m] = make_float2(0.f,0.f); S3[m] = make_float2(0.f,0.f);
  }
  for (int q = 0; q < 4; ++q) {
    __syncthreads();
    const float2* img = OTF + (((size_t)(band*4 + q)) << 16) + col;
    #pragma unroll
    for (int r = w; r < 256; r += 64) tile[r*5 + c] = img[(size_t)r * 256];
    __syncthreads();
    float2 v[4];
    #pragma unroll
    for (int m = 0; m < 4; ++m) v[m] = tile[(lane + (m << 6))*5 + wv];
    wfft256_fwd(v, lane);
    float sg1 = (q & 1) ? -1.f : 1.f;
    float sg2 = (q & 2) ? -1.f : 1.f;
    float sg3 = sg1 * sg2;
    #pragma unroll
    for (int m = 0; m < 4; ++m) {
      float2 z = v[BR2[m]];
      S0[m] = cadd(S0[m], z);
      S1[m] = make_float2(S1[m].x + sg1*z.x, S1[m].y + sg1*z.y);
      S2[m] = make_float2(S2[m].x + sg2*z.x, S2[m].y + sg2*z.y);
      S3[m] = make_float2(S3[m].x + sg3*z.x, S3[m].y + sg3*z.y);
    }
  }
  float2* S = Sb + (((size_t)(band*4)) << 16);
  #define WRITE_S(idx, arr)                                               \
  {                                                                       \
    __syncthreads();                                                      \
    _Pragma("unroll")                                                     \
    for (int m = 0; m < 4; ++m) tile[(lane + (m << 6))*5 + wv] = arr[m];  \
    __syncthreads();                                                      \
    _Pragma("unroll")                                                     \
    for (int r = w; r < 256; r += 64)                                     \
      S[((size_t)(idx) << 16) + (r << 8) + col] = tile[r*5 + c];          \
  }
  WRITE_S(0, S0)
  WRITE_S(1, S1)
  WRITE_S(2, S2)
  WRITE_S(3, S3)
  #undef WRITE_S
}

// ---------------- wave rows-fwd fused with input load ----------------
__global__ __launch_bounds__(256) void k_r256f_x(
    const float* __restrict__ in, float2* __restrict__ X) {
  const int BR2[4] = {0,2,1,3};
  int lane = threadIdx.x & 63;
  int wid = (blockIdx.x << 2) | (threadIdx.x >> 6);   // p*256 + i
  int p = wid >> 8, i = wid & 255;
  int band = p >> 3, img = p & 7;
  const float* src = in + (((size_t)img * 256 + i) * 256) * 3 + band;
  float2 v[4];
  #pragma unroll
  for (int m = 0; m < 4; ++m) v[m] = make_float2(src[(lane + (m << 6)) * 3], 0.f);
  wfft256_fwd(v, lane);
  float2* row = X + (size_t)wid * 256;
  #pragma unroll
  for (int m = 0; m < 4; ++m) row[lane + (m << 6)] = v[BR2[m]];
}

// --- fused: X cols-fwd (wave) + 9-tap combine (permuted taps) + cols-inv ------
__global__ __launch_bounds__(256) void k_xyc(
    const float2* __restrict__ X, const float2* __restrict__ Sb,
    float2* __restrict__ Y) {
  const int BR2[4] = {0,2,1,3};
  const int CAm[4] = {3,2,0,1};
  const int CBm[4] = {2,3,1,0};
  __shared__ float2 Xl[256*9];
  int tid = threadIdx.x;
  int c = tid & 7, w = tid >> 3;
  int lane = tid & 63, wv = tid >> 6;
  int n = blockIdx.y;
  int band = n >> 3;
  int col0 = blockIdx.x * 8;
  const float2* Xn = X + ((size_t)n << 16);
  #pragma unroll
  for (int r = w; r < 256; r += 32) Xl[r*9 + c] = Xn[(r << 8) | (col0 + c)];
  __syncthreads();
  #pragma unroll
  for (int q = 0; q < 2; ++q) {
    int cc = wv*2 + q;
    float2 v[4];
    #pragma unroll
    for (int m = 0; m < 4; ++m) v[m] = Xl[(lane + (m << 6))*9 + cc];
    wfft256_fwd(v, lane);
    #pragma unroll
    for (int m = 0; m < 4; ++m) Xl[(lane + (m << 6))*9 + cc] = v[BR2[m]];
  }
  __syncthreads();
  const float2* S = Sb + (((size_t)(band*4)) << 16);
  float2 pa0[4], pa1[4];
  #define COMBINE(pa, qq)                                                       \
  {                                                                             \
    int cc = wv*2 + (qq);                                                       \
    int cA = (cc & 4) | CAm[cc & 3];                                            \
    int cB = (cc & 4) | CBm[cc & 3];                                            \
    int scol = col0 + cc;                                                       \
    _Pragma("unroll")                                                           \
    for (int m = 0; m < 4; ++m) {                                               \
      int u  = lane + (m << 6);                                                 \
      int ua = (u & ~3) | CAm[u & 3];                                           \
      int ub = (u & ~3) | CBm[u & 3];                                           \
      float2 X00 = Xl[u*9 + cc];                                                \
      float2 X01 = Xl[u*9 + cA],  X03 = Xl[u*9 + cB];                           \
      float2 X10 = Xl[ua*9 + cc], X30 = Xl[ub*9 + cc];                          \
      float2 X11 = Xl[ua*9 + cA], X13 = Xl[ua*9 + cB];                          \
      float2 X31 = Xl[ub*9 + cA], X33 = Xl[ub*9 + cB];                          \
      float2 t00 = make_float2(0.25f*X00.x, 0.25f*X00.y);                       \
      float2 t01 = make_float2(0.125f*(X01.x + X03.x - (X03.y - X01.y)),        \
                               0.125f*(X01.y + X03.y + (X03.x - X01.x)));       \
      float2 t10 = make_float2(0.125f*(X10.x + X30.x - (X30.y - X10.y)),        \
                               0.125f*(X10.y + X30.y + (X30.x - X10.x)));       \
      float2 t11 = make_float2(0.125f*(X13.x + X31.x - (X33.y - X11.y)),        \
                               0.125f*(X13.y + X31.y + (X33.x - X11.x)));       \
      int uv = (u << 8) | scol;                                                 \
      float2 acc = cmulf(S[uv], t00);                                           \
      acc = cadd(acc, cmulf(S[(1<<16) | uv], t01));                             \
      acc = cadd(acc, cmulf(S[(2<<16) | uv], t10));                             \
      acc = cadd(acc, cmulf(S[(3<<16) | uv], t11));                             \
      pa[m] = acc;                                                              \
    }                                                                           \
  }
  COMBINE(pa0, 0)
  COMBINE(pa1, 1)
  #undef COMBINE
  __syncthreads();
  const float sc = 1.f/256.f;
  wfft256_inv(pa0, lane);
  wfft256_inv(pa1, lane);
  #pragma unroll
  for (int pos = 0; pos < 4; ++pos) {
    int rown = lane + (BR2[pos] << 6);
    float2 a = pa0[pos], b = pa1[pos];
    Xl[rown*9 + wv*2]     = make_float2(a.x*sc, a.y*sc);
    Xl[rown*9 + wv*2 + 1] = make_float2(b.x*sc, b.y*sc);
  }
  __syncthreads();
  float2* Yn = Y + ((size_t)n << 16);
  #pragma unroll
  for (int r = w; r < 256; r += 32) Yn[(r << 8) | (col0 + c)] = Xl[r*9 + c];
}

// ---------------- wave rows-inv over 3 bands + color accumulate ----------------
__global__ __launch_bounds__(256) void k_r256_inv_accum3(
    const float2* __restrict__ Y, float* __restrict__ out,
    const float* __restrict__ cf) {
  const int BR2[4] = {0,2,1,3};
  int lane = threadIdx.x & 63;
  int wid = (blockIdx.x << 2) | (threadIdx.x >> 6);   // img*256 + i
  int img = wid >> 8, i = wid & 255;
  float accR[4] = {0.f,0.f,0.f,0.f};
  float accG[4] = {0.f,0.f,0.f,0.f};
  float accB[4] = {0.f,0.f,0.f,0.f};
  const float sc = 1.f/256.f;
  for (int band = 0; band < 3; ++band) {
    const float2* row = Y + (((size_t)(band*8 + img)) << 16) + ((size_t)i << 8);
    float2 v[4];
    #pragma unroll
    for (int m = 0; m < 4; ++m) v[m] = row[lane + (m << 6)];
    wfft256_inv(v, lane);
    float c0 = cf[band], c1 = cf[3 + band], c2 = cf[9 + band];
    #pragma unroll
    for (int pos = 0; pos < 4; ++pos) {
      float re = v[pos].x * sc;
      int n2 = BR2[pos];
      accR[n2] += c0*re; accG[n2] += c1*re; accB[n2] += c2*re;
    }
  }
  #pragma unroll
  for (int n2 = 0; n2 < 4; ++n2) {
    int col = lane + (n2 << 6);
    float* o = out + (((size_t)img * 256 + i) * 256 + col) * 3;
    o[0] = accR[n2]; o[1] = accG[n2]; o[2] = accB[n2];
  }
}

// ================= host-side dispatch =================

extern "C" void kernel_launch(void* const* d_in, const int* in_sizes, int n_in,
                              void* d_out, int out_size, void* d_ws, size_t ws_size,
                              hipStream_t stream) {
  const float* inp = (const float*)d_in[0];
  const float* zc  = (const float*)d_in[1];
  const float* zv  = (const float*)d_in[2];
  const float* mp  = (const float*)d_in[3];
  const float* cf  = (const float*)d_in[4];
  float* out = (float*)d_out;

  char* ws = (char*)d_ws;
  size_t off = 0;
  auto alloc = [&](size_t bytes) -> void* {
    void* p = ws + off;
    off = (off + bytes + 255) & ~(size_t)255;
    return p;
  };
  float*  hm    = (float*) alloc((size_t)RR2 * 4);
  float*  aux8  = (float*) alloc(256 * 4);
  float*  PSUMP = (float*) alloc((size_t)12 * 256 * 4);
  float2* A     = (float2*)alloc((size_t)3 * RR2 * 8);
  float2* HB    = (float2*)alloc((size_t)6 * RR2 * 8);
  float2* U     = (float2*)alloc((size_t)12 * RR2 * 8);
  float*  PSF   = (float*) alloc((size_t)12 * PP2 * 4);
  float2* OTF   = (float2*)alloc((size_t)12 * PP2 * 8);
  float2* Sb    = (float2*)alloc((size_t)12 * PP2 * 8);
  float2* X     = (float2*)alloc((size_t)24 * PP2 * 8);
  float2* Y     = (float2*)alloc((size_t)24 * PP2 * 8);

  // ---- merged setup: height map + transfer + aux ----
  k_setup<<<256 + 3072 + 1, 256, 0, stream>>>(zc, (const float4*)zv, (float4*)hm,
                                              mp, cf, aux8, HB);

  // ---- field rows-fwd -> A ----
  k_r512f_field<<<3*512/4, 256, 0, stream>>>(hm, A);

  // ---- mega (pm-split): cols-fwd + xH1 + freq-mask + xH2 + cols-inv -> U ----
  k_mega512<<<dim3(64, 3, 4), 256, 0, stream>>>(A, HB, aux8, U);

  // ---- rows-inv + |.|^2 + downsample -> PSF ----
  k_r512_inv_psf<<<12*256/4, 256, 0, stream>>>(U, PSF, PSUMP);

  // ---- OTFs + parity S build ----
  k_r256f_otf<<<12*256/4, 256, 0, stream>>>(PSF, PSUMP, OTF);
  k_c256w<<<dim3(64, 3), 256, 0, stream>>>(OTF, Sb);

  // ---- convolution ----
  k_r256f_x<<<24*256/4, 256, 0, stream>>>(inp, X);
  k_xyc<<<dim3(32, 24), 256, 0, stream>>>(X, Sb, Y);
  k_r256_inv_accum3<<<8*256/4, 256, 0, stream>>>(Y, out, cf);
}

// Round 11
// 117.408 us; speedup vs baseline: 1.9626x; 1.1083x over previous
//
#include <hip/hip_runtime.h>
#include <math.h>

#define RR 512
#define RR2 (RR*RR)
#define PP 256
#define PP2 (PP*PP)

__constant__ double d_wls[3] = {4.6e-7, 5.4e-7, 6.2e-7};
__constant__ double d_dn[3]  = {0.52, 0.515, 0.51};

__device__ __forceinline__ float2 cadd(float2 a, float2 b){ return make_float2(a.x+b.x, a.y+b.y); }
__device__ __forceinline__ float2 csub(float2 a, float2 b){ return make_float2(a.x-b.x, a.y-b.y); }
__device__ __forceinline__ float2 cmulf(float2 a, float2 b){ return make_float2(a.x*b.x-a.y*b.y, a.x*b.y+a.y*b.x); }

// ======================================================================
// Wave-level FFT: N = 64 lanes x R regs, element n = lane + 64*reg.
// storage: out[lane + 64*m] = v[brR(m)]  ->  f(s) = (s>>6) + R_hi*bitrev6(s&63)
// ======================================================================

template<int R>
__device__ __forceinline__ void xf64_fwd(float2* v, int lane) {
  #pragma unroll
  for (int h = 32; h >= 1; h >>= 1) {
    float ang = -6.2831853071795865f * (float)(lane & (h-1)) / (float)(2*h);
    float sn, cs;
    __sincosf(ang, &sn, &cs);
    bool odd = (lane & h) != 0;
    float wc = odd ? cs : 1.f;
    float ws = odd ? sn : 0.f;
    #pragma unroll
    for (int r = 0; r < R; ++r) {
      float2 t;
      t.x = __shfl_xor(v[r].x, h);
      t.y = __shfl_xor(v[r].y, h);
      float2 d = odd ? csub(t, v[r]) : cadd(v[r], t);
      v[r] = make_float2(d.x*wc - d.y*ws, d.x*ws + d.y*wc);
    }
  }
}

template<int R>
__device__ __forceinline__ void xf64_inv(float2* v, int lane) {
  #pragma unroll
  for (int h = 1; h <= 32; h <<= 1) {
    float ang = 6.2831853071795865f * (float)(lane & (h-1)) / (float)(2*h);
    float sn, cs;
    __sincosf(ang, &sn, &cs);
    bool odd = (lane & h) != 0;
    #pragma unroll
    for (int r = 0; r < R; ++r) {
      float2 t;
      t.x = __shfl_xor(v[r].x, h);
      t.y = __shfl_xor(v[r].y, h);
      float2 s = odd ? v[r] : t;
      float2 ws = make_float2(s.x*cs - s.y*sn, s.x*sn + s.y*cs);
      v[r] = odd ? csub(t, ws) : cadd(v[r], ws);
    }
  }
}

template<bool INV>
__device__ __forceinline__ void reg_fft8(float2* a) {
  const float C = 0.70710678118654752f;
  {
    float2 t0 = csub(a[0], a[4]); a[0] = cadd(a[0], a[4]); a[4] = t0;
    float2 t1 = csub(a[1], a[5]); a[1] = cadd(a[1], a[5]);
    a[5] = INV ? make_float2(C*(t1.x - t1.y), C*(t1.x + t1.y))
               : make_float2(C*(t1.x + t1.y), C*(t1.y - t1.x));
    float2 t2 = csub(a[2], a[6]); a[2] = cadd(a[2], a[6]);
    a[6] = INV ? make_float2(-t2.y, t2.x) : make_float2(t2.y, -t2.x);
    float2 t3 = csub(a[3], a[7]); a[3] = cadd(a[3], a[7]);
    a[7] = INV ? make_float2(-C*(t3.x + t3.y), C*(t3.x - t3.y))
               : make_float2(C*(t3.y - t3.x), -C*(t3.x + t3.y));
  }
  #pragma unroll
  for (int g = 0; g < 2; ++g) {
    int b = g*4;
    float2 t0 = csub(a[b], a[b+2]); a[b] = cadd(a[b], a[b+2]); a[b+2] = t0;
    float2 t1 = csub(a[b+1], a[b+3]); a[b+1] = cadd(a[b+1], a[b+3]);
    a[b+3] = INV ? make_float2(-t1.y, t1.x) : make_float2(t1.y, -t1.x);
  }
  #pragma unroll
  for (int g = 0; g < 4; ++g) {
    int b = g*2;
    float2 t = csub(a[b], a[b+1]); a[b] = cadd(a[b], a[b+1]); a[b+1] = t;
  }
}

template<bool INV>
__device__ __forceinline__ void reg_fft4(float2* a) {
  float2 t0 = csub(a[0], a[2]); a[0] = cadd(a[0], a[2]); a[2] = t0;
  float2 t1 = csub(a[1], a[3]); a[1] = cadd(a[1], a[3]);
  a[3] = INV ? make_float2(-t1.y, t1.x) : make_float2(t1.y, -t1.x);
  t0 = csub(a[0], a[1]); a[0] = cadd(a[0], a[1]); a[1] = t0;
  t1 = csub(a[2], a[3]); a[2] = cadd(a[2], a[3]); a[3] = t1;
}

__device__ __forceinline__ void wfft512_fwd(float2* v, int lane) {
  const int BR3[8] = {0,4,2,6,1,5,3,7};
  reg_fft8<false>(v);
  float ang = -6.2831853071795865f * (float)lane * (1.f/512.f);
  float sn, cs; __sincosf(ang, &sn, &cs);
  float2 w1 = make_float2(cs, sn), w = w1;
  #pragma unroll
  for (int m = 1; m < 8; ++m) {
    v[BR3[m]] = cmulf(v[BR3[m]], w);
    if (m < 7) w = cmulf(w, w1);
  }
  xf64_fwd<8>(v, lane);
}

__device__ __forceinline__ void wfft512_inv(float2* v, int lane) {
  xf64_inv<8>(v, lane);
  float ang = 6.2831853071795865f * (float)lane * (1.f/512.f);
  float sn, cs; __sincosf(ang, &sn, &cs);
  float2 w1 = make_float2(cs, sn), w = w1;
  #pragma unroll
  for (int m = 1; m < 8; ++m) {
    v[m] = cmulf(v[m], w);
    if (m < 7) w = cmulf(w, w1);
  }
  reg_fft8<true>(v);
}

__device__ __forceinline__ void wfft256_fwd(float2* v, int lane) {
  const int BR2[4] = {0,2,1,3};
  reg_fft4<false>(v);
  float ang = -6.2831853071795865f * (float)lane * (1.f/256.f);
  float sn, cs; __sincosf(ang, &sn, &cs);
  float2 w1 = make_float2(cs, sn), w = w1;
  #pragma unroll
  for (int m = 1; m < 4; ++m) {
    v[BR2[m]] = cmulf(v[BR2[m]], w);
    if (m < 3) w = cmulf(w, w1);
  }
  xf64_fwd<4>(v, lane);
}

__device__ __forceinline__ void wfft256_inv(float2* v, int lane) {
  xf64_inv<4>(v, lane);
  float ang = 6.2831853071795865f * (float)lane * (1.f/256.f);
  float sn, cs; __sincosf(ang, &sn, &cs);
  float2 w1 = make_float2(cs, sn), w = w1;
  #pragma unroll
  for (int m = 1; m < 4; ++m) {
    v[m] = cmulf(v[m], w);
    if (m < 3) w = cmulf(w, w1);
  }
  reg_fft4<true>(v);
}

// ------------- merged setup: height map + transfer + aux tile -------------
__global__ void k_setup(const float* __restrict__ zc, const float4* __restrict__ zv,
                        float4* __restrict__ hm, const float* __restrict__ mp,
                        const float* __restrict__ cf, float* __restrict__ aux8,
                        float2* __restrict__ HB) {
  int bid = blockIdx.x;
  if (bid < 256) {
    int idx = bid * 256 + threadIdx.x;
    float4 s = make_float4(0.f,0.f,0.f,0.f);
    #pragma unroll 8
    for (int t = 0; t < 64; ++t) {
      float c = zc[t];
      float4 v = zv[(size_t)t * (RR2/4) + idx];
      s.x += c*v.x; s.y += c*v.y; s.z += c*v.z; s.w += c*v.w;
    }
    hm[idx] = s;
  } else if (bid < 256 + 3072) {
    int gid = (bid - 256) * 256 + threadIdx.x;   // 3 * RR2
    int band = gid >> 18, idx = gid & (RR2 - 1);
    double wl = d_wls[band];
    int su = idx >> 9, sv = idx & 511;
    int fui = (su >> 6) + 8 * (__brev(su & 63) >> 26);
    int fvi = (sv >> 6) + 8 * (__brev(sv & 63) >> 26);
    double inv_nd = 1.0 / (512.0 * 3.69e-6);
    double fu = (double)((fui < 256) ? fui : fui - 512) * inv_nd;
    double fv = (double)((fvi < 256) ? fvi : fvi - 512) * inv_nd;
    double au = wl * fu, av = wl * fv;
    double argd = 1.0 - au*au - av*av;
    float2 h0 = make_float2(0.f, 0.f), h1 = h0;
    if (argd > 0.0) {
      double kz = (6.283185307179586 / wl) * sqrt(argd);
      float s, c;
      double p0 = fmod(0.047 * kz, 6.283185307179586);
      __sincosf((float)p0, &s, &c); h0 = make_float2(c, s);
      double p1 = fmod(0.003 * kz, 6.283185307179586);
      __sincosf((float)p1, &s, &c); h1 = make_float2(c, s);
    }
    HB[(size_t)(band*2    ) * RR2 + idx] = h0;
    HB[(size_t)(band*2 + 1) * RR2 + idx] = h1;
  } else {
    int idx = threadIdx.x;
    if (idx >= 192) return;
    int l = idx % 3, j = (idx / 3) & 7, i = idx / 24;
    int i4 = (i < 4) ? i : 7 - i;
    int j4 = (j < 4) ? j : 7 - j;
    float s = 0.f;
    for (int f = 0; f < 4; ++f) s += cf[f*3 + l] * mp[f*16 + i4*4 + j4];
    aux8[idx] = s;
  }
}

// ---------------- field build + wave rows-fwd ----------------
__global__ __launch_bounds__(256) void k_r512f_field(
    const float* __restrict__ hm, float2* __restrict__ A) {
  const int BR3[8] = {0,4,2,6,1,5,3,7};
  int lane = threadIdx.x & 63;
  int wid = (blockIdx.x << 2) | (threadIdx.x >> 6);   // band*512 + r
  int band = wid >> 9, r = wid & 511;
  float K = (float)(6.283185307179586 / d_wls[band] * d_dn[band]);
  const float* hrow = hm + (size_t)r * 512;
  int dx = r - 256;
  float2 v[8];
  #pragma unroll
  for (int m = 0; m < 8; ++m) {
    int col = lane + (m << 6);
    int dy = col - 256;
    float2 f = make_float2(0.f, 0.f);
    if (dx*dx + dy*dy < 65025) {
      float ph = K * hrow[col];
      float s, c;
      sincosf(ph, &s, &c);
      f = make_float2(c, s);
    }
    v[m] = f;
  }
  wfft512_fwd(v, lane);
  float2* row = A + (size_t)wid * 512;
  #pragma unroll
  for (int m = 0; m < 8; ++m) row[lane + (m << 6)] = v[BR3[m]];
}

// ===== mega (pm split across blockIdx.z, single in-place 36KB LDS buffer) =====
__global__ __launch_bounds__(256) void k_mega512(
    const float2* __restrict__ A, const float2* __restrict__ HBp,
    const float* __restrict__ aux8, float2* __restrict__ U) {
  const int BR3[8] = {0,4,2,6,1,5,3,7};
  __shared__ float2 buf[512*9];
  int tid = threadIdx.x;
  int c8 = tid & 7, w32 = tid >> 3;
  int lane = tid & 63, wv = tid >> 6;
  int band = blockIdx.y;
  int pm = blockIdx.z;
  int dr = pm >> 1, dc = pm & 1;
  int col0 = blockIdx.x * 8;
  const float2* img = A + ((size_t)band << 18) + col0;
  #pragma unroll
  for (int r = w32; r < 512; r += 32) buf[r*9 + c8] = img[(size_t)r * 512 + c8];
  __syncthreads();
  const float2* H1 = HBp + (((size_t)(band*2)) << 18);
  #pragma unroll
  for (int q = 0; q < 2; ++q) {
    int cc = wv*2 + q, scol = col0 + cc;
    float2 v[8];
    #pragma unroll
    for (int m = 0; m < 8; ++m) v[m] = buf[(lane + (m << 6))*9 + cc];
    wfft512_fwd(v, lane);
    const float2* Hrow = H1 + (size_t)scol * 512;
    #pragma unroll
    for (int m = 0; m < 8; ++m)
      buf[(lane + (m << 6))*9 + cc] = cmulf(v[BR3[m]], Hrow[lane + (m << 6)]);
  }
  __syncthreads();
  #pragma unroll
  for (int r = tid; r < 512; r += 256) {
    float2 a[8];
    #pragma unroll
    for (int b = 0; b < 8; ++b) a[b] = buf[r*9 + BR3[b]];
    reg_fft8<true>(a);
    #pragma unroll
    for (int p = 0; p < 8; ++p) buf[r*9 + p] = a[p];
  }
  __syncthreads();
  #pragma unroll
  for (int t2 = tid; t2 < 512; t2 += 256) {
    int g = t2 >> 3, c = t2 & 7;
    int tc = BR3[c];
    int jm = ((tc + dc) & 7) * 3 + band;
    float2 a[8];
    #pragma unroll
    for (int b = 0; b < 8; ++b) a[b] = buf[(8*g + BR3[b])*9 + c];
    reg_fft8<true>(a);
    float2 nat[8];
    #pragma unroll
    for (int t = 0; t < 8; ++t) {
      float2 z = a[BR3[t]];
      float mv = aux8[((t + dr) & 7) * 24 + jm];
      nat[t] = make_float2(z.x*mv, z.y*mv);
    }
    reg_fft8<false>(nat);
    #pragma unroll
    for (int p = 0; p < 8; ++p) buf[(8*g + p)*9 + c] = nat[p];
  }
  __syncthreads();
  #pragma unroll
  for (int r = tid; r < 512; r += 256) {
    float2 nat[8];
    #pragma unroll
    for (int t = 0; t < 8; ++t) nat[t] = buf[r*9 + BR3[t]];
    reg_fft8<false>(nat);
    const float s64 = 1.f/64.f;
    #pragma unroll
    for (int p = 0; p < 8; ++p)
      buf[r*9 + p] = make_float2(nat[p].x*s64, nat[p].y*s64);
  }
  __syncthreads();
  const float2* H2 = HBp + (((size_t)(band*2 + 1)) << 18);
  #pragma unroll
  for (int q = 0; q < 2; ++q) {
    int cc = wv*2 + q, scol = col0 + cc;
    const float2* H2row = H2 + (size_t)scol * 512;
    float2 u[8];
    #pragma unroll
    for (int m = 0; m < 8; ++m)
      u[m] = cmulf(buf[(lane + (m << 6))*9 + cc], H2row[lane + (m << 6)]);
    wfft512_inv(u, lane);
    const float sc = 1.f/512.f;
    #pragma unroll
    for (int m = 0; m < 8; ++m) {
      float2 t = u[BR3[m]];
      buf[(lane + (m << 6))*9 + cc] = make_float2(t.x*sc, t.y*sc);
    }
  }
  __syncthreads();
  float2* orow = U + (((size_t)(band*4 + pm)) << 18) + col0;
  #pragma unroll
  for (int r = w32; r < 512; r += 32) orow[(size_t)r * 512 + c8] = buf[r*9 + c8];
}

// ------- wave rows-inv (row pair) + |.|^2 + 2x2 down + partial sum --
__global__ __launch_bounds__(256) void k_r512_inv_psf(
    const float2* __restrict__ U, float* __restrict__ PSF, float* __restrict__ PSUMP) {
  const int BR3[8] = {0,4,2,6,1,5,3,7};
  int lane = threadIdx.x & 63;
  int wid = (blockIdx.x << 2) | (threadIdx.x >> 6);   // p*256 + i
  int p = wid >> 8, i = wid & 255;
  const float2* row0 = U + ((size_t)p << 18) + (size_t)(2*i) * 512;
  const float2* row1 = row0 + 512;
  float2 v0[8], v1[8];
  #pragma unroll
  for (int m = 0; m < 8; ++m) v0[m] = row0[lane + (m << 6)];
  #pragma unroll
  for (int m = 0; m < 8; ++m) v1[m] = row1[lane + (m << 6)];
  wfft512_inv(v0, lane);
  wfft512_inv(v1, lane);
  float colsum[8];
  float tot = 0.f;
  #pragma unroll
  for (int pos = 0; pos < 8; ++pos) {
    float sq = v0[pos].x*v0[pos].x + v0[pos].y*v0[pos].y
             + v1[pos].x*v1[pos].x + v1[pos].y*v1[pos].y;
    tot += sq;
    colsum[pos] = sq;
  }
  const float sc2 = 0.25f / (512.f * 512.f);
  #pragma unroll
  for (int pos = 0; pos < 8; ++pos) {
    float pairs = colsum[pos] + __shfl_xor(colsum[pos], 1);
    if (!(lane & 1)) {
      int col = (lane >> 1) + (BR3[pos] << 5);
      PSF[((size_t)p << 16) | (i << 8) | col] = sc2 * pairs;
    }
  }
  #pragma unroll
  for (int h = 1; h < 64; h <<= 1) tot += __shfl_xor(tot, h);
  if (lane == 0) PSUMP[(p << 8) | i] = tot * sc2;
}

// --- wave rows-fwd fused with OTF load (shift + in-wave psum reduce + norm) ---
__global__ __launch_bounds__(256) void k_r256f_otf(
    const float* __restrict__ PSF, const float* __restrict__ PSUMP,
    float2* __restrict__ OTF) {
  const int BR2[4] = {0,2,1,3};
  int lane = threadIdx.x & 63;
  int wid = (blockIdx.x << 2) | (threadIdx.x >> 6);   // p*256 + i
  int p = wid >> 8, i = wid & 255;
  const float4* pp = reinterpret_cast<const float4*>(PSUMP + (p << 8));
  float4 q = pp[lane];
  float tot = (q.x + q.y) + (q.z + q.w);
  #pragma unroll
  for (int h = 1; h < 64; h <<= 1) tot += __shfl_xor(tot, h);
  float inv = 1.0f / tot;
  int si = (i + 128) & 255;
  const float* prow = PSF + ((size_t)p << 16) + (si << 8);
  float2 v[4];
  #pragma unroll
  for (int m = 0; m < 4; ++m) {
    int col = lane + (((m + 2) & 3) << 6);
    v[m] = make_float2(prow[col] * inv, 0.f);
  }
  wfft256_fwd(v, lane);
  float2* row = OTF + (size_t)wid * 256;
  #pragma unroll
  for (int m = 0; m < 4; ++m) row[lane + (m << 6)] = v[BR2[m]];
}

// ------- OTF cols-fwd (wave FFT, 1 col/wave) + parity S build in registers ----
__global__ __launch_bounds__(256) void k_c256w(
    const float2* __restrict__ OTF, float2* __restrict__ Sb) {
  const int BR2[4] = {0,2,1,3};
  __shared__ float2 tile[256*5];
  int tid = threadIdx.x;
  int c = tid & 3, w = tid >> 2;
  int lane = tid & 63, wv = tid >> 6;
  int band = blockIdx.y;
  int col = blockIdx.x * 4 + c;
  float2 S0[4], S1[4], S2[4], S3[4];
  #pragma unroll
  for (int m = 0; m < 4; ++m) {
    S0[m] = make_float2(0.f,0.f); S1[m] = make_float2(0.f,0.f);
    S2[m] = make_float2(0.f,0.f); S3[m] = make_float2(0.f,0.f);
  }
  for (int q = 0; q < 4; ++q) {
    __syncthreads();
    const float2* img = OTF + (((size_t)(band*4 + q)) << 16) + col;
    #pragma unroll
    for (int r = w; r < 256; r += 64) tile[r*5 + c] = img[(size_t)r * 256];
    __syncthreads();
    float2 v[4];
    #pragma unroll
    for (int m = 0; m < 4; ++m) v[m] = tile[(lane + (m << 6))*5 + wv];
    wfft256_fwd(v, lane);
    float sg1 = (q & 1) ? -1.f : 1.f;
    float sg2 = (q & 2) ? -1.f : 1.f;
    float sg3 = sg1 * sg2;
    #pragma unroll
    for (int m = 0; m < 4; ++m) {
      float2 z = v[BR2[m]];
      S0[m] = cadd(S0[m], z);
      S1[m] = make_float2(S1[m].x + sg1*z.x, S1[m].y + sg1*z.y);
      S2[m] = make_float2(S2[m].x + sg2*z.x, S2[m].y + sg2*z.y);
      S3[m] = make_float2(S3[m].x + sg3*z.x, S3[m].y + sg3*z.y);
    }
  }
  float2* S = Sb + (((size_t)(band*4)) << 16);
  #define WRITE_S(idx, arr)                                               \
  {                                                                       \
    __syncthreads();                                                      \
    _Pragma("unroll")                                                     \
    for (int m = 0; m < 4; ++m) tile[(lane + (m << 6))*5 + wv] = arr[m];  \
    __syncthreads();                                                      \
    _Pragma("unroll")                                                     \
    for (int r = w; r < 256; r += 64)                                     \
      S[((size_t)(idx) << 16) + (r << 8) + col] = tile[r*5 + c];          \
  }
  WRITE_S(0, S0)
  WRITE_S(1, S1)
  WRITE_S(2, S2)
  WRITE_S(3, S3)
  #undef WRITE_S
}

// --- wave rows-fwd, PACKED input load: z = x_{2g} + i*x_{2g+1} ---
__global__ __launch_bounds__(256) void k_r256f_xp(
    const float* __restrict__ in, float2* __restrict__ X) {
  const int BR2[4] = {0,2,1,3};
  int lane = threadIdx.x & 63;
  int wid = (blockIdx.x << 2) | (threadIdx.x >> 6);   // p*256 + i, p = band*4+g
  int p = wid >> 8, i = wid & 255;
  int band = p >> 2, g = p & 3;
  const float* s0 = in + (((size_t)(2*g)     * 256 + i) * 256) * 3 + band;
  const float* s1 = in + (((size_t)(2*g + 1) * 256 + i) * 256) * 3 + band;
  float2 v[4];
  #pragma unroll
  for (int m = 0; m < 4; ++m) {
    int col = (lane + (m << 6)) * 3;
    v[m] = make_float2(s0[col], s1[col]);
  }
  wfft256_fwd(v, lane);
  float2* row = X + (size_t)wid * 256;
  #pragma unroll
  for (int m = 0; m < 4; ++m) row[lane + (m << 6)] = v[BR2[m]];
}

// --- fused: X cols-fwd (wave) + 9-tap combine (permuted taps) + cols-inv ------
__global__ __launch_bounds__(256) void k_xyc(
    const float2* __restrict__ X, const float2* __restrict__ Sb,
    float2* __restrict__ Y) {
  const int BR2[4] = {0,2,1,3};
  const int CAm[4] = {3,2,0,1};
  const int CBm[4] = {2,3,1,0};
  __shared__ float2 Xl[256*9];
  int tid = threadIdx.x;
  int c = tid & 7, w = tid >> 3;
  int lane = tid & 63, wv = tid >> 6;
  int n = blockIdx.y;                            // packed plane: band*4 + g
  int band = n >> 2;
  int col0 = blockIdx.x * 8;
  const float2* Xn = X + ((size_t)n << 16);
  #pragma unroll
  for (int r = w; r < 256; r += 32) Xl[r*9 + c] = Xn[(r << 8) | (col0 + c)];
  __syncthreads();
  #pragma unroll
  for (int q = 0; q < 2; ++q) {
    int cc = wv*2 + q;
    float2 v[4];
    #pragma unroll
    for (int m = 0; m < 4; ++m) v[m] = Xl[(lane + (m << 6))*9 + cc];
    wfft256_fwd(v, lane);
    #pragma unroll
    for (int m = 0; m < 4; ++m) Xl[(lane + (m << 6))*9 + cc] = v[BR2[m]];
  }
  __syncthreads();
  const float2* S = Sb + (((size_t)(band*4)) << 16);
  float2 pa0[4], pa1[4];
  #define COMBINE(pa, qq)                                                       \
  {                                                                             \
    int cc = wv*2 + (qq);                                                       \
    int cA = (cc & 4) | CAm[cc & 3];                                            \
    int cB = (cc & 4) | CBm[cc & 3];                                            \
    int scol = col0 + cc;                                                       \
    _Pragma("unroll")                                                           \
    for (int m = 0; m < 4; ++m) {                                               \
      int u  = lane + (m << 6);                                                 \
      int ua = (u & ~3) | CAm[u & 3];                                           \
      int ub = (u & ~3) | CBm[u & 3];                                           \
      float2 X00 = Xl[u*9 + cc];                                                \
      float2 X01 = Xl[u*9 + cA],  X03 = Xl[u*9 + cB];                           \
      float2 X10 = Xl[ua*9 + cc], X30 = Xl[ub*9 + cc];                          \
      float2 X11 = Xl[ua*9 + cA], X13 = Xl[ua*9 + cB];                          \
      float2 X31 = Xl[ub*9 + cA], X33 = Xl[ub*9 + cB];                          \
      float2 t00 = make_float2(0.25f*X00.x, 0.25f*X00.y);                       \
      float2 t01 = make_float2(0.125f*(X01.x + X03.x - (X03.y - X01.y)),        \
                               0.125f*(X01.y + X03.y + (X03.x - X01.x)));       \
      float2 t10 = make_float2(0.125f*(X10.x + X30.x - (X30.y - X10.y)),        \
                               0.125f*(X10.y + X30.y + (X30.x - X10.x)));       \
      float2 t11 = make_float2(0.125f*(X13.x + X31.x - (X33.y - X11.y)),        \
                               0.125f*(X13.y + X31.y + (X33.x - X11.x)));       \
      int uv = (u << 8) | scol;                                                 \
      float2 acc = cmulf(S[uv], t00);                                           \
      acc = cadd(acc, cmulf(S[(1<<16) | uv], t01));                             \
      acc = cadd(acc, cmulf(S[(2<<16) | uv], t10));                             \
      acc = cadd(acc, cmulf(S[(3<<16) | uv], t11));                             \
      pa[m] = acc;                                                              \
    }                                                                           \
  }
  COMBINE(pa0, 0)
  COMBINE(pa1, 1)
  #undef COMBINE
  __syncthreads();
  const float sc = 1.f/256.f;
  wfft256_inv(pa0, lane);
  wfft256_inv(pa1, lane);
  #pragma unroll
  for (int pos = 0; pos < 4; ++pos) {
    int rown = lane + (BR2[pos] << 6);
    float2 a = pa0[pos], b = pa1[pos];
    Xl[rown*9 + wv*2]     = make_float2(a.x*sc, a.y*sc);
    Xl[rown*9 + wv*2 + 1] = make_float2(b.x*sc, b.y*sc);
  }
  __syncthreads();
  float2* Yn = Y + ((size_t)n << 16);
  #pragma unroll
  for (int r = w; r < 256; r += 32) Yn[(r << 8) | (col0 + c)] = Xl[r*9 + c];
}

// ----- wave rows-inv over 3 bands + color accumulate; PACKED (Re/Im = 2 imgs) -
__global__ __launch_bounds__(256) void k_r256_inv_accum3(
    const float2* __restrict__ Y, float* __restrict__ out,
    const float* __restrict__ cf) {
  const int BR2[4] = {0,2,1,3};
  int lane = threadIdx.x & 63;
  int wid = (blockIdx.x << 2) | (threadIdx.x >> 6);   // g*256 + i, g in [0,4)
  int g = wid >> 8, i = wid & 255;
  float aR0[4] = {0.f,0.f,0.f,0.f}, aG0[4] = {0.f,0.f,0.f,0.f}, aB0[4] = {0.f,0.f,0.f,0.f};
  float aR1[4] = {0.f,0.f,0.f,0.f}, aG1[4] = {0.f,0.f,0.f,0.f}, aB1[4] = {0.f,0.f,0.f,0.f};
  const float sc = 1.f/256.f;
  for (int band = 0; band < 3; ++band) {
    const float2* row = Y + (((size_t)(band*4 + g)) << 16) + ((size_t)i << 8);
    float2 v[4];
    #pragma unroll
    for (int m = 0; m < 4; ++m) v[m] = row[lane + (m << 6)];
    wfft256_inv(v, lane);
    float c0 = cf[band], c1 = cf[3 + band], c2 = cf[9 + band];
    #pragma unroll
    for (int pos = 0; pos < 4; ++pos) {
      float re = v[pos].x * sc;    // image 2g
      float im = v[pos].y * sc;    // image 2g+1
      int n2 = BR2[pos];
      aR0[n2] += c0*re; aG0[n2] += c1*re; aB0[n2] += c2*re;
      aR1[n2] += c0*im; aG1[n2] += c1*im; aB1[n2] += c2*im;
    }
  }
  #pragma unroll
  for (int n2 = 0; n2 < 4; ++n2) {
    int col = lane + (n2 << 6);
    float* o0 = out + (((size_t)(2*g)     * 256 + i) * 256 + col) * 3;
    float* o1 = out + (((size_t)(2*g + 1) * 256 + i) * 256 + col) * 3;
    o0[0] = aR0[n2]; o0[1] = aG0[n2]; o0[2] = aB0[n2];
    o1[0] = aR1[n2]; o1[1] = aG1[n2]; o1[2] = aB1[n2];
  }
}

// ================= host-side dispatch =================

extern "C" void kernel_launch(void* const* d_in, const int* in_sizes, int n_in,
                              void* d_out, int out_size, void* d_ws, size_t ws_size,
                              hipStream_t stream) {
  const float* inp = (const float*)d_in[0];
  const float* zc  = (const float*)d_in[1];
  const float* zv  = (const float*)d_in[2];
  const float* mp  = (const float*)d_in[3];
  const float* cf  = (const float*)d_in[4];
  float* out = (float*)d_out;

  char* ws = (char*)d_ws;
  size_t off = 0;
  auto alloc = [&](size_t bytes) -> void* {
    void* p = ws + off;
    off = (off + bytes + 255) & ~(size_t)255;
    return p;
  };
  float*  hm    = (float*) alloc((size_t)RR2 * 4);
  float*  aux8  = (float*) alloc(256 * 4);
  float*  PSUMP = (float*) alloc((size_t)12 * 256 * 4);
  float2* A     = (float2*)alloc((size_t)3 * RR2 * 8);
  float2* HB    = (float2*)alloc((size_t)6 * RR2 * 8);
  float2* U     = (float2*)alloc((size_t)12 * RR2 * 8);
  float*  PSF   = (float*) alloc((size_t)12 * PP2 * 4);
  float2* OTF   = (float2*)alloc((size_t)12 * PP2 * 8);
  float2* Sb    = (float2*)alloc((size_t)12 * PP2 * 8);
  float2* X     = (float2*)alloc((size_t)12 * PP2 * 8);   // packed: 12 planes
  float2* Y     = (float2*)alloc((size_t)12 * PP2 * 8);   // packed: 12 planes

  // ---- merged setup: height map + transfer + aux ----
  k_setup<<<256 + 3072 + 1, 256, 0, stream>>>(zc, (const float4*)zv, (float4*)hm,
                                              mp, cf, aux8, HB);

  // ---- field rows-fwd -> A ----
  k_r512f_field<<<3*512/4, 256, 0, stream>>>(hm, A);

  // ---- mega (pm-split): cols-fwd + xH1 + freq-mask + xH2 + cols-inv -> U ----
  k_mega512<<<dim3(64, 3, 4), 256, 0, stream>>>(A, HB, aux8, U);

  // ---- rows-inv + |.|^2 + downsample -> PSF ----
  k_r512_inv_psf<<<12*256/4, 256, 0, stream>>>(U, PSF, PSUMP);

  // ---- OTFs + parity S build ----
  k_r256f_otf<<<12*256/4, 256, 0, stream>>>(PSF, PSUMP, OTF);
  k_c256w<<<dim3(64, 3), 256, 0, stream>>>(OTF, Sb);

  // ---- convolution (packed pairs: 12 planes) ----
  k_r256f_xp<<<12*256/4, 256, 0, stream>>>(inp, X);
  k_xyc<<<dim3(32, 12), 256, 0, stream>>>(X, Sb, Y);
  k_r256_inv_accum3<<<4*256/4, 256, 0, stream>>>(Y, out, cf);
}

// Round 12
// 117.359 us; speedup vs baseline: 1.9634x; 1.0004x over previous
//
#include <hip/hip_runtime.h>
#include <math.h>

#define RR 512
#define RR2 (RR*RR)
#define PP 256
#define PP2 (PP*PP)

__constant__ double d_wls[3] = {4.6e-7, 5.4e-7, 6.2e-7};
__constant__ double d_dn[3]  = {0.52, 0.515, 0.51};

__device__ __forceinline__ float2 cadd(float2 a, float2 b){ return make_float2(a.x+b.x, a.y+b.y); }
__device__ __forceinline__ float2 csub(float2 a, float2 b){ return make_float2(a.x-b.x, a.y-b.y); }
__device__ __forceinline__ float2 cmulf(float2 a, float2 b){ return make_float2(a.x*b.x-a.y*b.y, a.x*b.y+a.y*b.x); }

// ======================================================================
// Wave-level FFT: N = 64 lanes x R regs, element n = lane + 64*reg.
// storage: out[lane + 64*m] = v[brR(m)]  ->  f(s) = (s>>6) + R_hi*bitrev6(s&63)
// ======================================================================

template<int R>
__device__ __forceinline__ void xf64_fwd(float2* v, int lane) {
  #pragma unroll
  for (int h = 32; h >= 1; h >>= 1) {
    float ang = -6.2831853071795865f * (float)(lane & (h-1)) / (float)(2*h);
    float sn, cs;
    __sincosf(ang, &sn, &cs);
    bool odd = (lane & h) != 0;
    float wc = odd ? cs : 1.f;
    float ws = odd ? sn : 0.f;
    #pragma unroll
    for (int r = 0; r < R; ++r) {
      float2 t;
      t.x = __shfl_xor(v[r].x, h);
      t.y = __shfl_xor(v[r].y, h);
      float2 d = odd ? csub(t, v[r]) : cadd(v[r], t);
      v[r] = make_float2(d.x*wc - d.y*ws, d.x*ws + d.y*wc);
    }
  }
}

template<int R>
__device__ __forceinline__ void xf64_inv(float2* v, int lane) {
  #pragma unroll
  for (int h = 1; h <= 32; h <<= 1) {
    float ang = 6.2831853071795865f * (float)(lane & (h-1)) / (float)(2*h);
    float sn, cs;
    __sincosf(ang, &sn, &cs);
    bool odd = (lane & h) != 0;
    #pragma unroll
    for (int r = 0; r < R; ++r) {
      float2 t;
      t.x = __shfl_xor(v[r].x, h);
      t.y = __shfl_xor(v[r].y, h);
      float2 s = odd ? v[r] : t;
      float2 ws = make_float2(s.x*cs - s.y*sn, s.x*sn + s.y*cs);
      v[r] = odd ? csub(t, ws) : cadd(v[r], ws);
    }
  }
}

template<bool INV>
__device__ __forceinline__ void reg_fft8(float2* a) {
  const float C = 0.70710678118654752f;
  {
    float2 t0 = csub(a[0], a[4]); a[0] = cadd(a[0], a[4]); a[4] = t0;
    float2 t1 = csub(a[1], a[5]); a[1] = cadd(a[1], a[5]);
    a[5] = INV ? make_float2(C*(t1.x - t1.y), C*(t1.x + t1.y))
               : make_float2(C*(t1.x + t1.y), C*(t1.y - t1.x));
    float2 t2 = csub(a[2], a[6]); a[2] = cadd(a[2], a[6]);
    a[6] = INV ? make_float2(-t2.y, t2.x) : make_float2(t2.y, -t2.x);
    float2 t3 = csub(a[3], a[7]); a[3] = cadd(a[3], a[7]);
    a[7] = INV ? make_float2(-C*(t3.x + t3.y), C*(t3.x - t3.y))
               : make_float2(C*(t3.y - t3.x), -C*(t3.x + t3.y));
  }
  #pragma unroll
  for (int g = 0; g < 2; ++g) {
    int b = g*4;
    float2 t0 = csub(a[b], a[b+2]); a[b] = cadd(a[b], a[b+2]); a[b+2] = t0;
    float2 t1 = csub(a[b+1], a[b+3]); a[b+1] = cadd(a[b+1], a[b+3]);
    a[b+3] = INV ? make_float2(-t1.y, t1.x) : make_float2(t1.y, -t1.x);
  }
  #pragma unroll
  for (int g = 0; g < 4; ++g) {
    int b = g*2;
    float2 t = csub(a[b], a[b+1]); a[b] = cadd(a[b], a[b+1]); a[b+1] = t;
  }
}

template<bool INV>
__device__ __forceinline__ void reg_fft4(float2* a) {
  float2 t0 = csub(a[0], a[2]); a[0] = cadd(a[0], a[2]); a[2] = t0;
  float2 t1 = csub(a[1], a[3]); a[1] = cadd(a[1], a[3]);
  a[3] = INV ? make_float2(-t1.y, t1.x) : make_float2(t1.y, -t1.x);
  t0 = csub(a[0], a[1]); a[0] = cadd(a[0], a[1]); a[1] = t0;
  t1 = csub(a[2], a[3]); a[2] = cadd(a[2], a[3]); a[3] = t1;
}

__device__ __forceinline__ void wfft512_fwd(float2* v, int lane) {
  const int BR3[8] = {0,4,2,6,1,5,3,7};
  reg_fft8<false>(v);
  float ang = -6.2831853071795865f * (float)lane * (1.f/512.f);
  float sn, cs; __sincosf(ang, &sn, &cs);
  float2 w1 = make_float2(cs, sn), w = w1;
  #pragma unroll
  for (int m = 1; m < 8; ++m) {
    v[BR3[m]] = cmulf(v[BR3[m]], w);
    if (m < 7) w = cmulf(w, w1);
  }
  xf64_fwd<8>(v, lane);
}

__device__ __forceinline__ void wfft512_inv(float2* v, int lane) {
  xf64_inv<8>(v, lane);
  float ang = 6.2831853071795865f * (float)lane * (1.f/512.f);
  float sn, cs; __sincosf(ang, &sn, &cs);
  float2 w1 = make_float2(cs, sn), w = w1;
  #pragma unroll
  for (int m = 1; m < 8; ++m) {
    v[m] = cmulf(v[m], w);
    if (m < 7) w = cmulf(w, w1);
  }
  reg_fft8<true>(v);
}

__device__ __forceinline__ void wfft256_fwd(float2* v, int lane) {
  const int BR2[4] = {0,2,1,3};
  reg_fft4<false>(v);
  float ang = -6.2831853071795865f * (float)lane * (1.f/256.f);
  float sn, cs; __sincosf(ang, &sn, &cs);
  float2 w1 = make_float2(cs, sn), w = w1;
  #pragma unroll
  for (int m = 1; m < 4; ++m) {
    v[BR2[m]] = cmulf(v[BR2[m]], w);
    if (m < 3) w = cmulf(w, w1);
  }
  xf64_fwd<4>(v, lane);
}

__device__ __forceinline__ void wfft256_inv(float2* v, int lane) {
  xf64_inv<4>(v, lane);
  float ang = 6.2831853071795865f * (float)lane * (1.f/256.f);
  float sn, cs; __sincosf(ang, &sn, &cs);
  float2 w1 = make_float2(cs, sn), w = w1;
  #pragma unroll
  for (int m = 1; m < 4; ++m) {
    v[m] = cmulf(v[m], w);
    if (m < 3) w = cmulf(w, w1);
  }
  reg_fft4<true>(v);
}

// ------------- merged setup: height map + transfer + aux tile -------------
__global__ void k_setup(const float* __restrict__ zc, const float4* __restrict__ zv,
                        float4* __restrict__ hm, const float* __restrict__ mp,
                        const float* __restrict__ cf, float* __restrict__ aux8,
                        float2* __restrict__ HB) {
  int bid = blockIdx.x;
  if (bid < 256) {
    int idx = bid * 256 + threadIdx.x;
    float4 s = make_float4(0.f,0.f,0.f,0.f);
    #pragma unroll 8
    for (int t = 0; t < 64; ++t) {
      float c = zc[t];
      float4 v = zv[(size_t)t * (RR2/4) + idx];
      s.x += c*v.x; s.y += c*v.y; s.z += c*v.z; s.w += c*v.w;
    }
    hm[idx] = s;
  } else if (bid < 256 + 3072) {
    int gid = (bid - 256) * 256 + threadIdx.x;   // 3 * RR2
    int band = gid >> 18, idx = gid & (RR2 - 1);
    double wl = d_wls[band];
    int su = idx >> 9, sv = idx & 511;
    int fui = (su >> 6) + 8 * (__brev(su & 63) >> 26);
    int fvi = (sv >> 6) + 8 * (__brev(sv & 63) >> 26);
    double inv_nd = 1.0 / (512.0 * 3.69e-6);
    double fu = (double)((fui < 256) ? fui : fui - 512) * inv_nd;
    double fv = (double)((fvi < 256) ? fvi : fvi - 512) * inv_nd;
    double au = wl * fu, av = wl * fv;
    double argd = 1.0 - au*au - av*av;
    float2 h0 = make_float2(0.f, 0.f), h1 = h0;
    if (argd > 0.0) {
      double kz = (6.283185307179586 / wl) * sqrt(argd);
      float s, c;
      double p0 = fmod(0.047 * kz, 6.283185307179586);
      __sincosf((float)p0, &s, &c); h0 = make_float2(c, s);
      double p1 = fmod(0.003 * kz, 6.283185307179586);
      __sincosf((float)p1, &s, &c); h1 = make_float2(c, s);
    }
    HB[(size_t)(band*2    ) * RR2 + idx] = h0;
    HB[(size_t)(band*2 + 1) * RR2 + idx] = h1;
  } else {
    int idx = threadIdx.x;
    if (idx >= 192) return;
    int l = idx % 3, j = (idx / 3) & 7, i = idx / 24;
    int i4 = (i < 4) ? i : 7 - i;
    int j4 = (j < 4) ? j : 7 - j;
    float s = 0.f;
    for (int f = 0; f < 4; ++f) s += cf[f*3 + l] * mp[f*16 + i4*4 + j4];
    aux8[idx] = s;
  }
}

// ---------------- field build + wave rows-fwd ----------------
__global__ __launch_bounds__(256) void k_r512f_field(
    const float* __restrict__ hm, float2* __restrict__ A) {
  const int BR3[8] = {0,4,2,6,1,5,3,7};
  int lane = threadIdx.x & 63;
  int wid = (blockIdx.x << 2) | (threadIdx.x >> 6);   // band*512 + r
  int band = wid >> 9, r = wid & 511;
  float K = (float)(6.283185307179586 / d_wls[band] * d_dn[band]);
  const float* hrow = hm + (size_t)r * 512;
  int dx = r - 256;
  float2 v[8];
  #pragma unroll
  for (int m = 0; m < 8; ++m) {
    int col = lane + (m << 6);
    int dy = col - 256;
    float2 f = make_float2(0.f, 0.f);
    if (dx*dx + dy*dy < 65025) {
      float ph = K * hrow[col];
      float s, c;
      sincosf(ph, &s, &c);
      f = make_float2(c, s);
    }
    v[m] = f;
  }
  wfft512_fwd(v, lane);
  float2* row = A + (size_t)wid * 512;
  #pragma unroll
  for (int m = 0; m < 8; ++m) row[lane + (m << 6)] = v[BR3[m]];
}

// ===== mega (pm split across blockIdx.z, single in-place 36KB LDS buffer) =====
__global__ __launch_bounds__(256) void k_mega512(
    const float2* __restrict__ A, const float2* __restrict__ HBp,
    const float* __restrict__ aux8, float2* __restrict__ U) {
  const int BR3[8] = {0,4,2,6,1,5,3,7};
  __shared__ float2 buf[512*9];
  int tid = threadIdx.x;
  int c8 = tid & 7, w32 = tid >> 3;
  int lane = tid & 63, wv = tid >> 6;
  int band = blockIdx.y;
  int pm = blockIdx.z;
  int dr = pm >> 1, dc = pm & 1;
  int col0 = blockIdx.x * 8;
  const float2* img = A + ((size_t)band << 18) + col0;
  #pragma unroll
  for (int r = w32; r < 512; r += 32) buf[r*9 + c8] = img[(size_t)r * 512 + c8];
  __syncthreads();
  const float2* H1 = HBp + (((size_t)(band*2)) << 18);
  #pragma unroll
  for (int q = 0; q < 2; ++q) {
    int cc = wv*2 + q, scol = col0 + cc;
    float2 v[8];
    #pragma unroll
    for (int m = 0; m < 8; ++m) v[m] = buf[(lane + (m << 6))*9 + cc];
    wfft512_fwd(v, lane);
    const float2* Hrow = H1 + (size_t)scol * 512;
    #pragma unroll
    for (int m = 0; m < 8; ++m)
      buf[(lane + (m << 6))*9 + cc] = cmulf(v[BR3[m]], Hrow[lane + (m << 6)]);
  }
  __syncthreads();
  #pragma unroll
  for (int r = tid; r < 512; r += 256) {
    float2 a[8];
    #pragma unroll
    for (int b = 0; b < 8; ++b) a[b] = buf[r*9 + BR3[b]];
    reg_fft8<true>(a);
    #pragma unroll
    for (int p = 0; p < 8; ++p) buf[r*9 + p] = a[p];
  }
  __syncthreads();
  #pragma unroll
  for (int t2 = tid; t2 < 512; t2 += 256) {
    int g = t2 >> 3, c = t2 & 7;
    int tc = BR3[c];
    int jm = ((tc + dc) & 7) * 3 + band;
    float2 a[8];
    #pragma unroll
    for (int b = 0; b < 8; ++b) a[b] = buf[(8*g + BR3[b])*9 + c];
    reg_fft8<true>(a);
    float2 nat[8];
    #pragma unroll
    for (int t = 0; t < 8; ++t) {
      float2 z = a[BR3[t]];
      float mv = aux8[((t + dr) & 7) * 24 + jm];
      nat[t] = make_float2(z.x*mv, z.y*mv);
    }
    reg_fft8<false>(nat);
    #pragma unroll
    for (int p = 0; p < 8; ++p) buf[(8*g + p)*9 + c] = nat[p];
  }
  __syncthreads();
  #pragma unroll
  for (int r = tid; r < 512; r += 256) {
    float2 nat[8];
    #pragma unroll
    for (int t = 0; t < 8; ++t) nat[t] = buf[r*9 + BR3[t]];
    reg_fft8<false>(nat);
    const float s64 = 1.f/64.f;
    #pragma unroll
    for (int p = 0; p < 8; ++p)
      buf[r*9 + p] = make_float2(nat[p].x*s64, nat[p].y*s64);
  }
  __syncthreads();
  const float2* H2 = HBp + (((size_t)(band*2 + 1)) << 18);
  #pragma unroll
  for (int q = 0; q < 2; ++q) {
    int cc = wv*2 + q, scol = col0 + cc;
    const float2* H2row = H2 + (size_t)scol * 512;
    float2 u[8];
    #pragma unroll
    for (int m = 0; m < 8; ++m)
      u[m] = cmulf(buf[(lane + (m << 6))*9 + cc], H2row[lane + (m << 6)]);
    wfft512_inv(u, lane);
    const float sc = 1.f/512.f;
    #pragma unroll
    for (int m = 0; m < 8; ++m) {
      float2 t = u[BR3[m]];
      buf[(lane + (m << 6))*9 + cc] = make_float2(t.x*sc, t.y*sc);
    }
  }
  __syncthreads();
  float2* orow = U + (((size_t)(band*4 + pm)) << 18) + col0;
  #pragma unroll
  for (int r = w32; r < 512; r += 32) orow[(size_t)r * 512 + c8] = buf[r*9 + c8];
}

// ------- wave rows-inv (row pair) + |.|^2 + 2x2 down + partial sum --
__global__ __launch_bounds__(256) void k_r512_inv_psf(
    const float2* __restrict__ U, float* __restrict__ PSF, float* __restrict__ PSUMP) {
  const int BR3[8] = {0,4,2,6,1,5,3,7};
  int lane = threadIdx.x & 63;
  int wid = (blockIdx.x << 2) | (threadIdx.x >> 6);   // p*256 + i
  int p = wid >> 8, i = wid & 255;
  const float2* row0 = U + ((size_t)p << 18) + (size_t)(2*i) * 512;
  const float2* row1 = row0 + 512;
  float2 v0[8], v1[8];
  #pragma unroll
  for (int m = 0; m < 8; ++m) v0[m] = row0[lane + (m << 6)];
  #pragma unroll
  for (int m = 0; m < 8; ++m) v1[m] = row1[lane + (m << 6)];
  wfft512_inv(v0, lane);
  wfft512_inv(v1, lane);
  float colsum[8];
  float tot = 0.f;
  #pragma unroll
  for (int pos = 0; pos < 8; ++pos) {
    float sq = v0[pos].x*v0[pos].x + v0[pos].y*v0[pos].y
             + v1[pos].x*v1[pos].x + v1[pos].y*v1[pos].y;
    tot += sq;
    colsum[pos] = sq;
  }
  const float sc2 = 0.25f / (512.f * 512.f);
  #pragma unroll
  for (int pos = 0; pos < 8; ++pos) {
    float pairs = colsum[pos] + __shfl_xor(colsum[pos], 1);
    if (!(lane & 1)) {
      int col = (lane >> 1) + (BR3[pos] << 5);
      PSF[((size_t)p << 16) | (i << 8) | col] = sc2 * pairs;
    }
  }
  #pragma unroll
  for (int h = 1; h < 64; h <<= 1) tot += __shfl_xor(tot, h);
  if (lane == 0) PSUMP[(p << 8) | i] = tot * sc2;
}

// --- wave rows-fwd fused with OTF load (shift + in-wave psum reduce + norm) ---
__global__ __launch_bounds__(256) void k_r256f_otf(
    const float* __restrict__ PSF, const float* __restrict__ PSUMP,
    float2* __restrict__ OTF) {
  const int BR2[4] = {0,2,1,3};
  int lane = threadIdx.x & 63;
  int wid = (blockIdx.x << 2) | (threadIdx.x >> 6);   // p*256 + i
  int p = wid >> 8, i = wid & 255;
  const float4* pp = reinterpret_cast<const float4*>(PSUMP + (p << 8));
  float4 q = pp[lane];
  float tot = (q.x + q.y) + (q.z + q.w);
  #pragma unroll
  for (int h = 1; h < 64; h <<= 1) tot += __shfl_xor(tot, h);
  float inv = 1.0f / tot;
  int si = (i + 128) & 255;
  const float* prow = PSF + ((size_t)p << 16) + (si << 8);
  float2 v[4];
  #pragma unroll
  for (int m = 0; m < 4; ++m) {
    int col = lane + (((m + 2) & 3) << 6);
    v[m] = make_float2(prow[col] * inv, 0.f);
  }
  wfft256_fwd(v, lane);
  float2* row = OTF + (size_t)wid * 256;
  #pragma unroll
  for (int m = 0; m < 4; ++m) row[lane + (m << 6)] = v[BR2[m]];
}

// ------- OTF cols-fwd (wave FFT, 1 col/wave) + parity S build in registers ----
__global__ __launch_bounds__(256) void k_c256w(
    const float2* __restrict__ OTF, float2* __restrict__ Sb) {
  const int BR2[4] = {0,2,1,3};
  __shared__ float2 tile[256*5];
  int tid = threadIdx.x;
  int c = tid & 3, w = tid >> 2;
  int lane = tid & 63, wv = tid >> 6;
  int band = blockIdx.y;
  int col = blockIdx.x * 4 + c;
  float2 S0[4], S1[4], S2[4], S3[4];
  #pragma unroll
  for (int m = 0; m < 4; ++m) {
    S0[m] = make_float2(0.f,0.f); S1[m] = make_float2(0.f,0.f);
    S2[m] = make_float2(0.f,0.f); S3[m] = make_float2(0.f,0.f);
  }
  for (int q = 0; q < 4; ++q) {
    __syncthreads();
    const float2* img = OTF + (((size_t)(band*4 + q)) << 16) + col;
    #pragma unroll
    for (int r = w; r < 256; r += 64) tile[r*5 + c] = img[(size_t)r * 256];
    __syncthreads();
    float2 v[4];
    #pragma unroll
    for (int m = 0; m < 4; ++m) v[m] = tile[(lane + (m << 6))*5 + wv];
    wfft256_fwd(v, lane);
    float sg1 = (q & 1) ? -1.f : 1.f;
    float sg2 = (q & 2) ? -1.f : 1.f;
    float sg3 = sg1 * sg2;
    #pragma unroll
    for (int m = 0; m < 4; ++m) {
      float2 z = v[BR2[m]];
      S0[m] = cadd(S0[m], z);
      S1[m] = make_float2(S1[m].x + sg1*z.x, S1[m].y + sg1*z.y);
      S2[m] = make_float2(S2[m].x + sg2*z.x, S2[m].y + sg2*z.y);
      S3[m] = make_float2(S3[m].x + sg3*z.x, S3[m].y + sg3*z.y);
    }
  }
  float2* S = Sb + (((size_t)(band*4)) << 16);
  #define WRITE_S(idx, arr)                                               \
  {                                                                       \
    __syncthreads();                                                      \
    _Pragma("unroll")                                                     \
    for (int m = 0; m < 4; ++m) tile[(lane + (m << 6))*5 + wv] = arr[m];  \
    __syncthreads();                                                      \
    _Pragma("unroll")                                                     \
    for (int r = w; r < 256; r += 64)                                     \
      S[((size_t)(idx) << 16) + (r << 8) + col] = tile[r*5 + c];          \
  }
  WRITE_S(0, S0)
  WRITE_S(1, S1)
  WRITE_S(2, S2)
  WRITE_S(3, S3)
  #undef WRITE_S
}

// --- wave rows-fwd, PACKED input load: z = x_{2g} + i*x_{2g+1} ---
__global__ __launch_bounds__(256) void k_r256f_xp(
    const float* __restrict__ in, float2* __restrict__ X) {
  const int BR2[4] = {0,2,1,3};
  int lane = threadIdx.x & 63;
  int wid = (blockIdx.x << 2) | (threadIdx.x >> 6);   // p*256 + i, p = band*4+g
  int p = wid >> 8, i = wid & 255;
  int band = p >> 2, g = p & 3;
  const float* s0 = in + (((size_t)(2*g)     * 256 + i) * 256) * 3 + band;
  const float* s1 = in + (((size_t)(2*g + 1) * 256 + i) * 256) * 3 + band;
  float2 v[4];
  #pragma unroll
  for (int m = 0; m < 4; ++m) {
    int col = (lane + (m << 6)) * 3;
    v[m] = make_float2(s0[col], s1[col]);
  }
  wfft256_fwd(v, lane);
  float2* row = X + (size_t)wid * 256;
  #pragma unroll
  for (int m = 0; m < 4; ++m) row[lane + (m << 6)] = v[BR2[m]];
}

// --- fused: X cols-fwd (wave) + 9-tap combine (permuted taps) + cols-inv ------
__global__ __launch_bounds__(256) void k_xyc(
    const float2* __restrict__ X, const float2* __restrict__ Sb,
    float2* __restrict__ Y) {
  const int BR2[4] = {0,2,1,3};
  const int CAm[4] = {3,2,0,1};
  const int CBm[4] = {2,3,1,0};
  __shared__ float2 Xl[256*9];
  int tid = threadIdx.x;
  int c = tid & 7, w = tid >> 3;
  int lane = tid & 63, wv = tid >> 6;
  int n = blockIdx.y;                            // packed plane: band*4 + g
  int band = n >> 2;
  int col0 = blockIdx.x * 8;
  const float2* Xn = X + ((size_t)n << 16);
  #pragma unroll
  for (int r = w; r < 256; r += 32) Xl[r*9 + c] = Xn[(r << 8) | (col0 + c)];
  __syncthreads();
  #pragma unroll
  for (int q = 0; q < 2; ++q) {
    int cc = wv*2 + q;
    float2 v[4];
    #pragma unroll
    for (int m = 0; m < 4; ++m) v[m] = Xl[(lane + (m << 6))*9 + cc];
    wfft256_fwd(v, lane);
    #pragma unroll
    for (int m = 0; m < 4; ++m) Xl[(lane + (m << 6))*9 + cc] = v[BR2[m]];
  }
  __syncthreads();
  const float2* S = Sb + (((size_t)(band*4)) << 16);
  float2 pa0[4], pa1[4];
  #define COMBINE(pa, qq)                                                       \
  {                                                                             \
    int cc = wv*2 + (qq);                                                       \
    int cA = (cc & 4) | CAm[cc & 3];                                            \
    int cB = (cc & 4) | CBm[cc & 3];                                            \
    int scol = col0 + cc;                                                       \
    _Pragma("unroll")                                                           \
    for (int m = 0; m < 4; ++m) {                                               \
      int u  = lane + (m << 6);                                                 \
      int ua = (u & ~3) | CAm[u & 3];                                           \
      int ub = (u & ~3) | CBm[u & 3];                                           \
      float2 X00 = Xl[u*9 + cc];                                                \
      float2 X01 = Xl[u*9 + cA],  X03 = Xl[u*9 + cB];                           \
      float2 X10 = Xl[ua*9 + cc], X30 = Xl[ub*9 + cc];                          \
      float2 X11 = Xl[ua*9 + cA], X13 = Xl[ua*9 + cB];                          \
      float2 X31 = Xl[ub*9 + cA], X33 = Xl[ub*9 + cB];                          \
      float2 t00 = make_float2(0.25f*X00.x, 0.25f*X00.y);                       \
      float2 t01 = make_float2(0.125f*(X01.x + X03.x - (X03.y - X01.y)),        \
                               0.125f*(X01.y + X03.y + (X03.x - X01.x)));       \
      float2 t10 = make_float2(0.125f*(X10.x + X30.x - (X30.y - X10.y)),        \
                               0.125f*(X10.y + X30.y + (X30.x - X10.x)));       \
      float2 t11 = make_float2(0.125f*(X13.x + X31.x - (X33.y - X11.y)),        \
                               0.125f*(X13.y + X31.y + (X33.x - X11.x)));       \
      int uv = (u << 8) | scol;                                                 \
      float2 acc = cmulf(S[uv], t00);                                           \
      acc = cadd(acc, cmulf(S[(1<<16) | uv], t01));                             \
      acc = cadd(acc, cmulf(S[(2<<16) | uv], t10));                             \
      acc = cadd(acc, cmulf(S[(3<<16) | uv], t11));                             \
      pa[m] = acc;                                                              \
    }                                                                           \
  }
  COMBINE(pa0, 0)
  COMBINE(pa1, 1)
  #undef COMBINE
  __syncthreads();
  const float sc = 1.f/256.f;
  wfft256_inv(pa0, lane);
  wfft256_inv(pa1, lane);
  #pragma unroll
  for (int pos = 0; pos < 4; ++pos) {
    int rown = lane + (BR2[pos] << 6);
    float2 a = pa0[pos], b = pa1[pos];
    Xl[rown*9 + wv*2]     = make_float2(a.x*sc, a.y*sc);
    Xl[rown*9 + wv*2 + 1] = make_float2(b.x*sc, b.y*sc);
  }
  __syncthreads();
  float2* Yn = Y + ((size_t)n << 16);
  #pragma unroll
  for (int r = w; r < 256; r += 32) Yn[(r << 8) | (col0 + c)] = Xl[r*9 + c];
}

// ----- wave rows-inv over 3 bands + color accumulate; PACKED (Re/Im = 2 imgs) -
__global__ __launch_bounds__(256) void k_r256_inv_accum3(
    const float2* __restrict__ Y, float* __restrict__ out,
    const float* __restrict__ cf) {
  const int BR2[4] = {0,2,1,3};
  int lane = threadIdx.x & 63;
  int wid = (blockIdx.x << 2) | (threadIdx.x >> 6);   // g*256 + i, g in [0,4)
  int g = wid >> 8, i = wid & 255;
  float aR0[4] = {0.f,0.f,0.f,0.f}, aG0[4] = {0.f,0.f,0.f,0.f}, aB0[4] = {0.f,0.f,0.f,0.f};
  float aR1[4] = {0.f,0.f,0.f,0.f}, aG1[4] = {0.f,0.f,0.f,0.f}, aB1[4] = {0.f,0.f,0.f,0.f};
  const float sc = 1.f/256.f;
  for (int band = 0; band < 3; ++band) {
    const float2* row = Y + (((size_t)(band*4 + g)) << 16) + ((size_t)i << 8);
    float2 v[4];
    #pragma unroll
    for (int m = 0; m < 4; ++m) v[m] = row[lane + (m << 6)];
    wfft256_inv(v, lane);
    float c0 = cf[band], c1 = cf[3 + band], c2 = cf[9 + band];
    #pragma unroll
    for (int pos = 0; pos < 4; ++pos) {
      float re = v[pos].x * sc;    // image 2g
      float im = v[pos].y * sc;    // image 2g+1
      int n2 = BR2[pos];
      aR0[n2] += c0*re; aG0[n2] += c1*re; aB0[n2] += c2*re;
      aR1[n2] += c0*im; aG1[n2] += c1*im; aB1[n2] += c2*im;
    }
  }
  #pragma unroll
  for (int n2 = 0; n2 < 4; ++n2) {
    int col = lane + (n2 << 6);
    float* o0 = out + (((size_t)(2*g)     * 256 + i) * 256 + col) * 3;
    float* o1 = out + (((size_t)(2*g + 1) * 256 + i) * 256 + col) * 3;
    o0[0] = aR0[n2]; o0[1] = aG0[n2]; o0[2] = aB0[n2];
    o1[0] = aR1[n2]; o1[1] = aG1[n2]; o1[2] = aB1[n2];
  }
}

// ================= host-side dispatch =================

extern "C" void kernel_launch(void* const* d_in, const int* in_sizes, int n_in,
                              void* d_out, int out_size, void* d_ws, size_t ws_size,
                              hipStream_t stream) {
  const float* inp = (const float*)d_in[0];
  const float* zc  = (const float*)d_in[1];
  const float* zv  = (const float*)d_in[2];
  const float* mp  = (const float*)d_in[3];
  const float* cf  = (const float*)d_in[4];
  float* out = (float*)d_out;

  char* ws = (char*)d_ws;
  size_t off = 0;
  auto alloc = [&](size_t bytes) -> void* {
    void* p = ws + off;
    off = (off + bytes + 255) & ~(size_t)255;
    return p;
  };
  float*  hm    = (float*) alloc((size_t)RR2 * 4);
  float*  aux8  = (float*) alloc(256 * 4);
  float*  PSUMP = (float*) alloc((size_t)12 * 256 * 4);
  float2* A     = (float2*)alloc((size_t)3 * RR2 * 8);
  float2* HB    = (float2*)alloc((size_t)6 * RR2 * 8);
  float2* U     = (float2*)alloc((size_t)12 * RR2 * 8);
  float*  PSF   = (float*) alloc((size_t)12 * PP2 * 4);
  float2* OTF   = (float2*)alloc((size_t)12 * PP2 * 8);
  float2* Sb    = (float2*)alloc((size_t)12 * PP2 * 8);
  float2* X     = (float2*)alloc((size_t)12 * PP2 * 8);   // packed: 12 planes
  float2* Y     = (float2*)alloc((size_t)12 * PP2 * 8);   // packed: 12 planes

  // ---- merged setup: height map + transfer + aux ----
  k_setup<<<256 + 3072 + 1, 256, 0, stream>>>(zc, (const float4*)zv, (float4*)hm,
                                              mp, cf, aux8, HB);

  // ---- field rows-fwd -> A ----
  k_r512f_field<<<3*512/4, 256, 0, stream>>>(hm, A);

  // ---- mega (pm-split): cols-fwd + xH1 + freq-mask + xH2 + cols-inv -> U ----
  k_mega512<<<dim3(64, 3, 4), 256, 0, stream>>>(A, HB, aux8, U);

  // ---- rows-inv + |.|^2 + downsample -> PSF ----
  k_r512_inv_psf<<<12*256/4, 256, 0, stream>>>(U, PSF, PSUMP);

  // ---- OTFs + parity S build ----
  k_r256f_otf<<<12*256/4, 256, 0, stream>>>(PSF, PSUMP, OTF);
  k_c256w<<<dim3(64, 3), 256, 0, stream>>>(OTF, Sb);

  // ---- convolution (packed pairs: 12 planes) ----
  k_r256f_xp<<<12*256/4, 256, 0, stream>>>(inp, X);
  k_xyc<<<dim3(32, 12), 256, 0, stream>>>(X, Sb, Y);
  k_r256_inv_accum3<<<4*256/4, 256, 0, stream>>>(Y, out, cf);
}

// Round 13
// 113.450 us; speedup vs baseline: 2.0311x; 1.0345x over previous
//
#include <hip/hip_runtime.h>
#include <math.h>

#define RR 512
#define RR2 (RR*RR)
#define PP 256
#define PP2 (PP*PP)

__constant__ double d_wls[3] = {4.6e-7, 5.4e-7, 6.2e-7};
__constant__ double d_dn[3]  = {0.52, 0.515, 0.51};

__device__ __forceinline__ float2 cadd(float2 a, float2 b){ return make_float2(a.x+b.x, a.y+b.y); }
__device__ __forceinline__ float2 csub(float2 a, float2 b){ return make_float2(a.x-b.x, a.y-b.y); }
__device__ __forceinline__ float2 cmulf(float2 a, float2 b){ return make_float2(a.x*b.x-a.y*b.y, a.x*b.y+a.y*b.x); }

// ======================================================================
// Wave-level FFT: N = 64 lanes x R regs, element n = lane + 64*reg.
// storage: out[lane + 64*m] = v[brR(m)]  ->  f(s) = (s>>6) + R_hi*bitrev6(s&63)
// ======================================================================

template<int R>
__device__ __forceinline__ void xf64_fwd(float2* v, int lane) {
  #pragma unroll
  for (int h = 32; h >= 1; h >>= 1) {
    float ang = -6.2831853071795865f * (float)(lane & (h-1)) / (float)(2*h);
    float sn, cs;
    __sincosf(ang, &sn, &cs);
    bool odd = (lane & h) != 0;
    float wc = odd ? cs : 1.f;
    float ws = odd ? sn : 0.f;
    #pragma unroll
    for (int r = 0; r < R; ++r) {
      float2 t;
      t.x = __shfl_xor(v[r].x, h);
      t.y = __shfl_xor(v[r].y, h);
      float2 d = odd ? csub(t, v[r]) : cadd(v[r], t);
      v[r] = make_float2(d.x*wc - d.y*ws, d.x*ws + d.y*wc);
    }
  }
}

template<int R>
__device__ __forceinline__ void xf64_inv(float2* v, int lane) {
  #pragma unroll
  for (int h = 1; h <= 32; h <<= 1) {
    float ang = 6.2831853071795865f * (float)(lane & (h-1)) / (float)(2*h);
    float sn, cs;
    __sincosf(ang, &sn, &cs);
    bool odd = (lane & h) != 0;
    #pragma unroll
    for (int r = 0; r < R; ++r) {
      float2 t;
      t.x = __shfl_xor(v[r].x, h);
      t.y = __shfl_xor(v[r].y, h);
      float2 s = odd ? v[r] : t;
      float2 ws = make_float2(s.x*cs - s.y*sn, s.x*sn + s.y*cs);
      v[r] = odd ? csub(t, ws) : cadd(v[r], ws);
    }
  }
}

template<bool INV>
__device__ __forceinline__ void reg_fft8(float2* a) {
  const float C = 0.70710678118654752f;
  {
    float2 t0 = csub(a[0], a[4]); a[0] = cadd(a[0], a[4]); a[4] = t0;
    float2 t1 = csub(a[1], a[5]); a[1] = cadd(a[1], a[5]);
    a[5] = INV ? make_float2(C*(t1.x - t1.y), C*(t1.x + t1.y))
               : make_float2(C*(t1.x + t1.y), C*(t1.y - t1.x));
    float2 t2 = csub(a[2], a[6]); a[2] = cadd(a[2], a[6]);
    a[6] = INV ? make_float2(-t2.y, t2.x) : make_float2(t2.y, -t2.x);
    float2 t3 = csub(a[3], a[7]); a[3] = cadd(a[3], a[7]);
    a[7] = INV ? make_float2(-C*(t3.x + t3.y), C*(t3.x - t3.y))
               : make_float2(C*(t3.y - t3.x), -C*(t3.x + t3.y));
  }
  #pragma unroll
  for (int g = 0; g < 2; ++g) {
    int b = g*4;
    float2 t0 = csub(a[b], a[b+2]); a[b] = cadd(a[b], a[b+2]); a[b+2] = t0;
    float2 t1 = csub(a[b+1], a[b+3]); a[b+1] = cadd(a[b+1], a[b+3]);
    a[b+3] = INV ? make_float2(-t1.y, t1.x) : make_float2(t1.y, -t1.x);
  }
  #pragma unroll
  for (int g = 0; g < 4; ++g) {
    int b = g*2;
    float2 t = csub(a[b], a[b+1]); a[b] = cadd(a[b], a[b+1]); a[b+1] = t;
  }
}

template<bool INV>
__device__ __forceinline__ void reg_fft4(float2* a) {
  float2 t0 = csub(a[0], a[2]); a[0] = cadd(a[0], a[2]); a[2] = t0;
  float2 t1 = csub(a[1], a[3]); a[1] = cadd(a[1], a[3]);
  a[3] = INV ? make_float2(-t1.y, t1.x) : make_float2(t1.y, -t1.x);
  t0 = csub(a[0], a[1]); a[0] = cadd(a[0], a[1]); a[1] = t0;
  t1 = csub(a[2], a[3]); a[2] = cadd(a[2], a[3]); a[3] = t1;
}

__device__ __forceinline__ void wfft512_fwd(float2* v, int lane) {
  const int BR3[8] = {0,4,2,6,1,5,3,7};
  reg_fft8<false>(v);
  float ang = -6.2831853071795865f * (float)lane * (1.f/512.f);
  float sn, cs; __sincosf(ang, &sn, &cs);
  float2 w1 = make_float2(cs, sn), w = w1;
  #pragma unroll
  for (int m = 1; m < 8; ++m) {
    v[BR3[m]] = cmulf(v[BR3[m]], w);
    if (m < 7) w = cmulf(w, w1);
  }
  xf64_fwd<8>(v, lane);
}

__device__ __forceinline__ void wfft512_inv(float2* v, int lane) {
  xf64_inv<8>(v, lane);
  float ang = 6.2831853071795865f * (float)lane * (1.f/512.f);
  float sn, cs; __sincosf(ang, &sn, &cs);
  float2 w1 = make_float2(cs, sn), w = w1;
  #pragma unroll
  for (int m = 1; m < 8; ++m) {
    v[m] = cmulf(v[m], w);
    if (m < 7) w = cmulf(w, w1);
  }
  reg_fft8<true>(v);
}

__device__ __forceinline__ void wfft256_fwd(float2* v, int lane) {
  const int BR2[4] = {0,2,1,3};
  reg_fft4<false>(v);
  float ang = -6.2831853071795865f * (float)lane * (1.f/256.f);
  float sn, cs; __sincosf(ang, &sn, &cs);
  float2 w1 = make_float2(cs, sn), w = w1;
  #pragma unroll
  for (int m = 1; m < 4; ++m) {
    v[BR2[m]] = cmulf(v[BR2[m]], w);
    if (m < 3) w = cmulf(w, w1);
  }
  xf64_fwd<4>(v, lane);
}

__device__ __forceinline__ void wfft256_inv(float2* v, int lane) {
  xf64_inv<4>(v, lane);
  float ang = 6.2831853071795865f * (float)lane * (1.f/256.f);
  float sn, cs; __sincosf(ang, &sn, &cs);
  float2 w1 = make_float2(cs, sn), w = w1;
  #pragma unroll
  for (int m = 1; m < 4; ++m) {
    v[m] = cmulf(v[m], w);
    if (m < 3) w = cmulf(w, w1);
  }
  reg_fft4<true>(v);
}

// ------------- merged setup: height map + H phases + aux + packed X rows-fwd --
__global__ void k_setup(const float* __restrict__ zc, const float4* __restrict__ zv,
                        float4* __restrict__ hm, const float* __restrict__ mp,
                        const float* __restrict__ cf, float* __restrict__ aux8,
                        float* __restrict__ PH,
                        const float* __restrict__ inp, float2* __restrict__ X) {
  int bid = blockIdx.x;
  if (bid < 256) {
    int idx = bid * 256 + threadIdx.x;
    float4 s = make_float4(0.f,0.f,0.f,0.f);
    #pragma unroll 8
    for (int t = 0; t < 64; ++t) {
      float c = zc[t];
      float4 v = zv[(size_t)t * (RR2/4) + idx];
      s.x += c*v.x; s.y += c*v.y; s.z += c*v.z; s.w += c*v.w;
    }
    hm[idx] = s;
  } else if (bid < 256 + 3072) {
    // H phases (permuted both dims). argd >= 0.986 for all bands -> no cutoff.
    int gid = (bid - 256) * 256 + threadIdx.x;   // 3 * RR2
    int band = gid >> 18, idx = gid & (RR2 - 1);
    double wl = d_wls[band];
    int su = idx >> 9, sv = idx & 511;
    int fui = (su >> 6) + 8 * (__brev(su & 63) >> 26);
    int fvi = (sv >> 6) + 8 * (__brev(sv & 63) >> 26);
    double inv_nd = 1.0 / (512.0 * 3.69e-6);
    double fu = (double)((fui < 256) ? fui : fui - 512) * inv_nd;
    double fv = (double)((fvi < 256) ? fvi : fvi - 512) * inv_nd;
    double au = wl * fu, av = wl * fv;
    double argd = 1.0 - au*au - av*av;
    double kz = (6.283185307179586 / wl) * sqrt(argd);
    PH[(size_t)(band*2    ) * RR2 + idx] = (float)fmod(0.047 * kz, 6.283185307179586);
    PH[(size_t)(band*2 + 1) * RR2 + idx] = (float)fmod(0.003 * kz, 6.283185307179586);
  } else if (bid == 256 + 3072) {
    int idx = threadIdx.x;
    if (idx >= 192) return;
    int l = idx % 3, j = (idx / 3) & 7, i = idx / 24;
    int i4 = (i < 4) ? i : 7 - i;
    int j4 = (j < 4) ? j : 7 - j;
    float s = 0.f;
    for (int f = 0; f < 4; ++f) s += cf[f*3 + l] * mp[f*16 + i4*4 + j4];
    aux8[idx] = s;
  } else {
    // packed input rows-fwd: z = x_{2g} + i*x_{2g+1}
    const int BR2[4] = {0,2,1,3};
    int b2 = bid - (256 + 3072 + 1);              // 0..767
    int lane = threadIdx.x & 63;
    int wid = (b2 << 2) | (threadIdx.x >> 6);     // p*256 + i, p = band*4+g
    int p = wid >> 8, i = wid & 255;
    int band = p >> 2, g = p & 3;
    const float* s0 = inp + (((size_t)(2*g)     * 256 + i) * 256) * 3 + band;
    const float* s1 = inp + (((size_t)(2*g + 1) * 256 + i) * 256) * 3 + band;
    float2 v[4];
    #pragma unroll
    for (int m = 0; m < 4; ++m) {
      int col = (lane + (m << 6)) * 3;
      v[m] = make_float2(s0[col], s1[col]);
    }
    wfft256_fwd(v, lane);
    float2* row = X + (size_t)wid * 256;
    #pragma unroll
    for (int m = 0; m < 4; ++m) row[lane + (m << 6)] = v[BR2[m]];
  }
}

// ---------------- field build + wave rows-fwd ----------------
__global__ __launch_bounds__(256) void k_r512f_field(
    const float* __restrict__ hm, float2* __restrict__ A) {
  const int BR3[8] = {0,4,2,6,1,5,3,7};
  int lane = threadIdx.x & 63;
  int wid = (blockIdx.x << 2) | (threadIdx.x >> 6);   // band*512 + r
  int band = wid >> 9, r = wid & 511;
  float K = (float)(6.283185307179586 / d_wls[band] * d_dn[band]);
  const float* hrow = hm + (size_t)r * 512;
  int dx = r - 256;
  float2 v[8];
  #pragma unroll
  for (int m = 0; m < 8; ++m) {
    int col = lane + (m << 6);
    int dy = col - 256;
    float2 f = make_float2(0.f, 0.f);
    if (dx*dx + dy*dy < 65025) {
      float ph = K * hrow[col];
      float s, c;
      sincosf(ph, &s, &c);
      f = make_float2(c, s);
    }
    v[m] = f;
  }
  wfft512_fwd(v, lane);
  float2* row = A + (size_t)wid * 512;
  #pragma unroll
  for (int m = 0; m < 8; ++m) row[lane + (m << 6)] = v[BR3[m]];
}

// ===== mega (pm split across blockIdx.z, single in-place 36KB LDS buffer) =====
// cols-fwd + xH1(phase) + [DFT8x8 -> mask(dr,dc) -> IDFT8x8] + xH2(phase) + cols-inv
__global__ __launch_bounds__(256) void k_mega512(
    const float2* __restrict__ A, const float* __restrict__ PH,
    const float* __restrict__ aux8, float2* __restrict__ U) {
  const int BR3[8] = {0,4,2,6,1,5,3,7};
  __shared__ float2 buf[512*9];
  int tid = threadIdx.x;
  int c8 = tid & 7, w32 = tid >> 3;
  int lane = tid & 63, wv = tid >> 6;
  int band = blockIdx.y;
  int pm = blockIdx.z;
  int dr = pm >> 1, dc = pm & 1;
  int col0 = blockIdx.x * 8;
  const float2* img = A + ((size_t)band << 18) + col0;
  #pragma unroll
  for (int r = w32; r < 512; r += 32) buf[r*9 + c8] = img[(size_t)r * 512 + c8];
  __syncthreads();
  const float* PH1 = PH + (((size_t)(band*2)) << 18);
  #pragma unroll
  for (int q = 0; q < 2; ++q) {
    int cc = wv*2 + q, scol = col0 + cc;
    float2 v[8];
    #pragma unroll
    for (int m = 0; m < 8; ++m) v[m] = buf[(lane + (m << 6))*9 + cc];
    wfft512_fwd(v, lane);
    const float* Prow = PH1 + (size_t)scol * 512;   // symmetric: row == column
    #pragma unroll
    for (int m = 0; m < 8; ++m) {
      float sn, cs;
      __sincosf(Prow[lane + (m << 6)], &sn, &cs);
      buf[(lane + (m << 6))*9 + cc] = cmulf(v[BR3[m]], make_float2(cs, sn));
    }
  }
  __syncthreads();
  #pragma unroll
  for (int r = tid; r < 512; r += 256) {
    float2 a[8];
    #pragma unroll
    for (int b = 0; b < 8; ++b) a[b] = buf[r*9 + BR3[b]];
    reg_fft8<true>(a);
    #pragma unroll
    for (int p = 0; p < 8; ++p) buf[r*9 + p] = a[p];
  }
  __syncthreads();
  #pragma unroll
  for (int t2 = tid; t2 < 512; t2 += 256) {
    int g = t2 >> 3, c = t2 & 7;
    int tc = BR3[c];
    int jm = ((tc + dc) & 7) * 3 + band;
    float2 a[8];
    #pragma unroll
    for (int b = 0; b < 8; ++b) a[b] = buf[(8*g + BR3[b])*9 + c];
    reg_fft8<true>(a);
    float2 nat[8];
    #pragma unroll
    for (int t = 0; t < 8; ++t) {
      float2 z = a[BR3[t]];
      float mv = aux8[((t + dr) & 7) * 24 + jm];
      nat[t] = make_float2(z.x*mv, z.y*mv);
    }
    reg_fft8<false>(nat);
    #pragma unroll
    for (int p = 0; p < 8; ++p) buf[(8*g + p)*9 + c] = nat[p];
  }
  __syncthreads();
  #pragma unroll
  for (int r = tid; r < 512; r += 256) {
    float2 nat[8];
    #pragma unroll
    for (int t = 0; t < 8; ++t) nat[t] = buf[r*9 + BR3[t]];
    reg_fft8<false>(nat);
    const float s64 = 1.f/64.f;
    #pragma unroll
    for (int p = 0; p < 8; ++p)
      buf[r*9 + p] = make_float2(nat[p].x*s64, nat[p].y*s64);
  }
  __syncthreads();
  const float* PH2 = PH + (((size_t)(band*2 + 1)) << 18);
  #pragma unroll
  for (int q = 0; q < 2; ++q) {
    int cc = wv*2 + q, scol = col0 + cc;
    const float* P2row = PH2 + (size_t)scol * 512;
    float2 u[8];
    #pragma unroll
    for (int m = 0; m < 8; ++m) {
      float sn, cs;
      __sincosf(P2row[lane + (m << 6)], &sn, &cs);
      u[m] = cmulf(buf[(lane + (m << 6))*9 + cc], make_float2(cs, sn));
    }
    wfft512_inv(u, lane);
    const float sc = 1.f/512.f;
    #pragma unroll
    for (int m = 0; m < 8; ++m) {
      float2 t = u[BR3[m]];
      buf[(lane + (m << 6))*9 + cc] = make_float2(t.x*sc, t.y*sc);
    }
  }
  __syncthreads();
  float2* orow = U + (((size_t)(band*4 + pm)) << 18) + col0;
  #pragma unroll
  for (int r = w32; r < 512; r += 32) orow[(size_t)r * 512 + c8] = buf[r*9 + c8];
}

// ------- wave rows-inv (row pair) + |.|^2 + 2x2 down + partial sum --
__global__ __launch_bounds__(256) void k_r512_inv_psf(
    const float2* __restrict__ U, float* __restrict__ PSF, float* __restrict__ PSUMP) {
  const int BR3[8] = {0,4,2,6,1,5,3,7};
  int lane = threadIdx.x & 63;
  int wid = (blockIdx.x << 2) | (threadIdx.x >> 6);   // p*256 + i
  int p = wid >> 8, i = wid & 255;
  const float2* row0 = U + ((size_t)p << 18) + (size_t)(2*i) * 512;
  const float2* row1 = row0 + 512;
  float2 v0[8], v1[8];
  #pragma unroll
  for (int m = 0; m < 8; ++m) v0[m] = row0[lane + (m << 6)];
  #pragma unroll
  for (int m = 0; m < 8; ++m) v1[m] = row1[lane + (m << 6)];
  wfft512_inv(v0, lane);
  wfft512_inv(v1, lane);
  float colsum[8];
  float tot = 0.f;
  #pragma unroll
  for (int pos = 0; pos < 8; ++pos) {
    float sq = v0[pos].x*v0[pos].x + v0[pos].y*v0[pos].y
             + v1[pos].x*v1[pos].x + v1[pos].y*v1[pos].y;
    tot += sq;
    colsum[pos] = sq;
  }
  const float sc2 = 0.25f / (512.f * 512.f);
  #pragma unroll
  for (int pos = 0; pos < 8; ++pos) {
    float pairs = colsum[pos] + __shfl_xor(colsum[pos], 1);
    if (!(lane & 1)) {
      int col = (lane >> 1) + (BR3[pos] << 5);
      PSF[((size_t)p << 16) | (i << 8) | col] = sc2 * pairs;
    }
  }
  #pragma unroll
  for (int h = 1; h < 64; h <<= 1) tot += __shfl_xor(tot, h);
  if (lane == 0) PSUMP[(p << 8) | i] = tot * sc2;
}

// --- wave rows-fwd fused with OTF load (shift + in-wave psum reduce + norm) ---
__global__ __launch_bounds__(256) void k_r256f_otf(
    const float* __restrict__ PSF, const float* __restrict__ PSUMP,
    float2* __restrict__ OTF) {
  const int BR2[4] = {0,2,1,3};
  int lane = threadIdx.x & 63;
  int wid = (blockIdx.x << 2) | (threadIdx.x >> 6);   // p*256 + i
  int p = wid >> 8, i = wid & 255;
  const float4* pp = reinterpret_cast<const float4*>(PSUMP + (p << 8));
  float4 q = pp[lane];
  float tot = (q.x + q.y) + (q.z + q.w);
  #pragma unroll
  for (int h = 1; h < 64; h <<= 1) tot += __shfl_xor(tot, h);
  float inv = 1.0f / tot;
  int si = (i + 128) & 255;
  const float* prow = PSF + ((size_t)p << 16) + (si << 8);
  float2 v[4];
  #pragma unroll
  for (int m = 0; m < 4; ++m) {
    int col = lane + (((m + 2) & 3) << 6);
    v[m] = make_float2(prow[col] * inv, 0.f);
  }
  wfft256_fwd(v, lane);
  float2* row = OTF + (size_t)wid * 256;
  #pragma unroll
  for (int m = 0; m < 4; ++m) row[lane + (m << 6)] = v[BR2[m]];
}

// ------- OTF cols-fwd (wave FFT, 1 col/wave) + parity S build; S COL-MAJOR ----
__global__ __launch_bounds__(256) void k_c256w(
    const float2* __restrict__ OTF, float2* __restrict__ Sb) {
  const int BR2[4] = {0,2,1,3};
  __shared__ float2 tile[256*5];
  int tid = threadIdx.x;
  int c = tid & 3, w = tid >> 2;
  int lane = tid & 63, wv = tid >> 6;
  int band = blockIdx.y;
  int col = blockIdx.x * 4 + c;
  float2 S0[4], S1[4], S2[4], S3[4];
  #pragma unroll
  for (int m = 0; m < 4; ++m) {
    S0[m] = make_float2(0.f,0.f); S1[m] = make_float2(0.f,0.f);
    S2[m] = make_float2(0.f,0.f); S3[m] = make_float2(0.f,0.f);
  }
  for (int q = 0; q < 4; ++q) {
    __syncthreads();
    const float2* img = OTF + (((size_t)(band*4 + q)) << 16) + col;
    #pragma unroll
    for (int r = w; r < 256; r += 64) tile[r*5 + c] = img[(size_t)r * 256];
    __syncthreads();
    float2 v[4];
    #pragma unroll
    for (int m = 0; m < 4; ++m) v[m] = tile[(lane + (m << 6))*5 + wv];
    wfft256_fwd(v, lane);
    float sg1 = (q & 1) ? -1.f : 1.f;
    float sg2 = (q & 2) ? -1.f : 1.f;
    float sg3 = sg1 * sg2;
    #pragma unroll
    for (int m = 0; m < 4; ++m) {
      float2 z = v[BR2[m]];
      S0[m] = cadd(S0[m], z);
      S1[m] = make_float2(S1[m].x + sg1*z.x, S1[m].y + sg1*z.y);
      S2[m] = make_float2(S2[m].x + sg2*z.x, S2[m].y + sg2*z.y);
      S3[m] = make_float2(S3[m].x + sg3*z.x, S3[m].y + sg3*z.y);
    }
  }
  // COL-MAJOR: S[plane][col][row]
  float2* S = Sb + (((size_t)(band*4)) << 16);
  #define WRITE_S(idx, arr)                                               \
  {                                                                       \
    __syncthreads();                                                      \
    _Pragma("unroll")                                                     \
    for (int m = 0; m < 4; ++m) tile[(lane + (m << 6))*5 + wv] = arr[m];  \
    __syncthreads();                                                      \
    _Pragma("unroll")                                                     \
    for (int r = w; r < 256; r += 64)                                     \
      S[((size_t)(idx) << 16) + (col << 8) + r] = tile[r*5 + c];          \
  }
  WRITE_S(0, S0)
  WRITE_S(1, S1)
  WRITE_S(2, S2)
  WRITE_S(3, S3)
  #undef WRITE_S
}

// --- fused: X cols-fwd (wave) + 9-tap combine (S col-major) + cols-inv ------
__global__ __launch_bounds__(256) void k_xyc(
    const float2* __restrict__ X, const float2* __restrict__ Sb,
    float2* __restrict__ Y) {
  const int BR2[4] = {0,2,1,3};
  const int CAm[4] = {3,2,0,1};
  const int CBm[4] = {2,3,1,0};
  __shared__ float2 Xl[256*9];
  int tid = threadIdx.x;
  int c = tid & 7, w = tid >> 3;
  int lane = tid & 63, wv = tid >> 6;
  int n = blockIdx.y;                            // packed plane: band*4 + g
  int band = n >> 2;
  int col0 = blockIdx.x * 8;
  const float2* Xn = X + ((size_t)n << 16);
  #pragma unroll
  for (int r = w; r < 256; r += 32) Xl[r*9 + c] = Xn[(r << 8) | (col0 + c)];
  __syncthreads();
  #pragma unroll
  for (int q = 0; q < 2; ++q) {
    int cc = wv*2 + q;
    float2 v[4];
    #pragma unroll
    for (int m = 0; m < 4; ++m) v[m] = Xl[(lane + (m << 6))*9 + cc];
    wfft256_fwd(v, lane);
    #pragma unroll
    for (int m = 0; m < 4; ++m) Xl[(lane + (m << 6))*9 + cc] = v[BR2[m]];
  }
  __syncthreads();
  const float2* S = Sb + (((size_t)(band*4)) << 16);
  float2 pa0[4], pa1[4];
  #define COMBINE(pa, qq)                                                       \
  {                                                                             \
    int cc = wv*2 + (qq);                                                       \
    int cA = (cc & 4) | CAm[cc & 3];                                            \
    int cB = (cc & 4) | CBm[cc & 3];                                            \
    int scol = col0 + cc;                                                       \
    _Pragma("unroll")                                                           \
    for (int m = 0; m < 4; ++m) {                                               \
      int u  = lane + (m << 6);                                                 \
      int ua = (u & ~3) | CAm[u & 3];                                           \
      int ub = (u & ~3) | CBm[u & 3];                                           \
      float2 X00 = Xl[u*9 + cc];                                                \
      float2 X01 = Xl[u*9 + cA],  X03 = Xl[u*9 + cB];                           \
      float2 X10 = Xl[ua*9 + cc], X30 = Xl[ub*9 + cc];                          \
      float2 X11 = Xl[ua*9 + cA], X13 = Xl[ua*9 + cB];                          \
      float2 X31 = Xl[ub*9 + cA], X33 = Xl[ub*9 + cB];                          \
      float2 t00 = make_float2(0.25f*X00.x, 0.25f*X00.y);                       \
      float2 t01 = make_float2(0.125f*(X01.x + X03.x - (X03.y - X01.y)),        \
                               0.125f*(X01.y + X03.y + (X03.x - X01.x)));       \
      float2 t10 = make_float2(0.125f*(X10.x + X30.x - (X30.y - X10.y)),        \
                               0.125f*(X10.y + X30.y + (X30.x - X10.x)));       \
      float2 t11 = make_float2(0.125f*(X13.x + X31.x - (X33.y - X11.y)),        \
                               0.125f*(X13.y + X31.y + (X33.x - X11.x)));       \
      int uv = (scol << 8) | u;               /* col-major S index */           \
      float2 acc = cmulf(S[uv], t00);                                           \
      acc = cadd(acc, cmulf(S[(1<<16) | uv], t01));                             \
      acc = cadd(acc, cmulf(S[(2<<16) | uv], t10));                             \
      acc = cadd(acc, cmulf(S[(3<<16) | uv], t11));                             \
      pa[m] = acc;                                                              \
    }                                                                           \
  }
  COMBINE(pa0, 0)
  COMBINE(pa1, 1)
  #undef COMBINE
  __syncthreads();
  const float sc = 1.f/256.f;
  wfft256_inv(pa0, lane);
  wfft256_inv(pa1, lane);
  #pragma unroll
  for (int pos = 0; pos < 4; ++pos) {
    int rown = lane + (BR2[pos] << 6);
    float2 a = pa0[pos], b = pa1[pos];
    Xl[rown*9 + wv*2]     = make_float2(a.x*sc, a.y*sc);
    Xl[rown*9 + wv*2 + 1] = make_float2(b.x*sc, b.y*sc);
  }
  __syncthreads();
  float2* Yn = Y + ((size_t)n << 16);
  #pragma unroll
  for (int r = w; r < 256; r += 32) Yn[(r << 8) | (col0 + c)] = Xl[r*9 + c];
}

// ----- wave rows-inv over 3 bands + color accumulate; PACKED (Re/Im = 2 imgs) -
__global__ __launch_bounds__(256) void k_r256_inv_accum3(
    const float2* __restrict__ Y, float* __restrict__ out,
    const float* __restrict__ cf) {
  const int BR2[4] = {0,2,1,3};
  int lane = threadIdx.x & 63;
  int wid = (blockIdx.x << 2) | (threadIdx.x >> 6);   // g*256 + i, g in [0,4)
  int g = wid >> 8, i = wid & 255;
  float aR0[4] = {0.f,0.f,0.f,0.f}, aG0[4] = {0.f,0.f,0.f,0.f}, aB0[4] = {0.f,0.f,0.f,0.f};
  float aR1[4] = {0.f,0.f,0.f,0.f}, aG1[4] = {0.f,0.f,0.f,0.f}, aB1[4] = {0.f,0.f,0.f,0.f};
  const float sc = 1.f/256.f;
  for (int band = 0; band < 3; ++band) {
    const float2* row = Y + (((size_t)(band*4 + g)) << 16) + ((size_t)i << 8);
    float2 v[4];
    #pragma unroll
    for (int m = 0; m < 4; ++m) v[m] = row[lane + (m << 6)];
    wfft256_inv(v, lane);
    float c0 = cf[band], c1 = cf[3 + band], c2 = cf[9 + band];
    #pragma unroll
    for (int pos = 0; pos < 4; ++pos) {
      float re = v[pos].x * sc;    // image 2g
      float im = v[pos].y * sc;    // image 2g+1
      int n2 = BR2[pos];
      aR0[n2] += c0*re; aG0[n2] += c1*re; aB0[n2] += c2*re;
      aR1[n2] += c0*im; aG1[n2] += c1*im; aB1[n2] += c2*im;
    }
  }
  #pragma unroll
  for (int n2 = 0; n2 < 4; ++n2) {
    int col = lane + (n2 << 6);
    float* o0 = out + (((size_t)(2*g)     * 256 + i) * 256 + col) * 3;
    float* o1 = out + (((size_t)(2*g + 1) * 256 + i) * 256 + col) * 3;
    o0[0] = aR0[n2]; o0[1] = aG0[n2]; o0[2] = aB0[n2];
    o1[0] = aR1[n2]; o1[1] = aG1[n2]; o1[2] = aB1[n2];
  }
}

// ================= host-side dispatch =================

extern "C" void kernel_launch(void* const* d_in, const int* in_sizes, int n_in,
                              void* d_out, int out_size, void* d_ws, size_t ws_size,
                              hipStream_t stream) {
  const float* inp = (const float*)d_in[0];
  const float* zc  = (const float*)d_in[1];
  const float* zv  = (const float*)d_in[2];
  const float* mp  = (const float*)d_in[3];
  const float* cf  = (const float*)d_in[4];
  float* out = (float*)d_out;

  char* ws = (char*)d_ws;
  size_t off = 0;
  auto alloc = [&](size_t bytes) -> void* {
    void* p = ws + off;
    off = (off + bytes + 255) & ~(size_t)255;
    return p;
  };
  float*  hm    = (float*) alloc((size_t)RR2 * 4);
  float*  aux8  = (float*) alloc(256 * 4);
  float*  PSUMP = (float*) alloc((size_t)12 * 256 * 4);
  float2* A     = (float2*)alloc((size_t)3 * RR2 * 8);
  float*  PH    = (float*) alloc((size_t)6 * RR2 * 4);    // phases: 6 planes x 1MB
  float2* U     = (float2*)alloc((size_t)12 * RR2 * 8);
  float*  PSF   = (float*) alloc((size_t)12 * PP2 * 4);
  float2* OTF   = (float2*)alloc((size_t)12 * PP2 * 8);
  float2* Sb    = (float2*)alloc((size_t)12 * PP2 * 8);
  float2* X     = (float2*)alloc((size_t)12 * PP2 * 8);   // packed: 12 planes
  float2* Y     = (float2*)alloc((size_t)12 * PP2 * 8);   // packed: 12 planes

  // ---- merged setup: height map + H phases + aux + packed X rows-fwd ----
  k_setup<<<256 + 3072 + 1 + 768, 256, 0, stream>>>(zc, (const float4*)zv, (float4*)hm,
                                                    mp, cf, aux8, PH, inp, X);

  // ---- field rows-fwd -> A ----
  k_r512f_field<<<3*512/4, 256, 0, stream>>>(hm, A);

  // ---- mega (pm-split): cols-fwd + xH1 + freq-mask + xH2 + cols-inv -> U ----
  k_mega512<<<dim3(64, 3, 4), 256, 0, stream>>>(A, PH, aux8, U);

  // ---- rows-inv + |.|^2 + downsample -> PSF ----
  k_r512_inv_psf<<<12*256/4, 256, 0, stream>>>(U, PSF, PSUMP);

  // ---- OTFs + parity S build ----
  k_r256f_otf<<<12*256/4, 256, 0, stream>>>(PSF, PSUMP, OTF);
  k_c256w<<<dim3(64, 3), 256, 0, stream>>>(OTF, Sb);

  // ---- convolution (packed pairs) ----
  k_xyc<<<dim3(32, 12), 256, 0, stream>>>(X, Sb, Y);
  k_r256_inv_accum3<<<4*256/4, 256, 0, stream>>>(Y, out, cf);
}